// Round 3
// baseline (339.899 us; speedup 1.0000x reference)
//
#include <hip/hip_runtime.h>
#include <hip/hip_bf16.h>

typedef __hip_bfloat16 bf16;
typedef short short8v __attribute__((ext_vector_type(8)));
typedef short short4v __attribute__((ext_vector_type(4)));
typedef float float4v __attribute__((ext_vector_type(4)));
typedef float float2v __attribute__((ext_vector_type(2)));

static __device__ __forceinline__ float b2f(bf16 v){ return __bfloat162float(v); }
static __device__ __forceinline__ bf16 f2b(float v){ return __float2bfloat16(v); }
static __device__ __forceinline__ float bu2f(unsigned short u){ return __uint_as_float(((unsigned)u) << 16); }
static __device__ __forceinline__ short f2bs(float v){ bf16 t = __float2bfloat16(v); return *(short*)&t; }
static __device__ __forceinline__ float ftanh(float x){ return 1.f - 2.f / (1.f + __expf(2.f * x)); }
// bf16 pair -> float2 (low element = even channel)
static __device__ __forceinline__ float2v bfpair(unsigned u){
  float2v r; r.x = __uint_as_float(u << 16); r.y = __uint_as_float(u & 0xffff0000u); return r;
}
// exact-GELU via A&S 7.1.26 erf (|err|<=1.5e-7), no libm call
static __device__ __forceinline__ float gelu_f(float v){
  float x = v * 0.70710678118654752f;
  float ax = fabsf(x);
  float t = __builtin_amdgcn_rcpf(__builtin_fmaf(0.3275911f, ax, 1.f));
  float p = __builtin_fmaf(1.061405429f, t, -1.453152027f);
  p = __builtin_fmaf(p, t, 1.421413741f);
  p = __builtin_fmaf(p, t, -0.284496736f);
  p = __builtin_fmaf(p, t, 0.254829592f);
  p = p * t;
  float e = __expf(-ax * ax);
  float er = __builtin_fmaf(-p, e, 1.f);
  er = copysignf(er, x);
  return 0.5f * v * (1.f + er);
}

#define WT 128
#define HWT 16384

// ---- packed f32 weights (float offsets inside ws) ----
#define OFF_WINPB 1024     // bf16 fragment-order [nt:4][kc:2][ln:64][j:8] packed 2/float (2048 floats)
#define OFF_BZ    20544    // 32
#define OFF_BR    39008    // 32
#define OFF_BQ    57472    // 32
#define OFF_DWP   57504    // [tap][64]        576
#define OFF_DWB   58080    // 64
#define OFF_LNG   58144    // 64
#define OFF_LNB   58208    // 64
#define OFF_OMB   65184    // 108 (+4 zero pad)
#define OFF_WINP  65296    // [c][64]          4096
#define OFF_BINP  69392    // 64
#define OFF_BOUT  73552    // 64
#define NW_TOTAL  73616
#define NBF_ZR    36864    // bf16 fragment-order [t:4][kc:18][ln:64][j:8]
#define NBF_Q     18432    // bf16 fragment-order [t:2][kc:18][ln:64][j:8]
#define NBF_OM    7168     // bf16 fragment-order [wv:7][kc:2][ln:64][j:8]
#define NBF_OUT   4096     // bf16 fragment-order [nt:4][kc:2][ln:64][j:8]
#define NPREP     (NW_TOTAL + NBF_ZR + NBF_Q + NBF_OM + NBF_OUT)
#define NHALO     2064     // 4 imgs * 516 halo pixels
#define NTOT      (NPREP + NHALO)
#define NB_PREPB  556      // ceil(NTOT/256)

// ---- ws byte offsets (end = 21,928,448 B) ----
#define B_WZRB  294912
#define B_WQB   368640
#define B_WOMB  405504
#define B_WOUTB 419840
#define B_HXP   428544     // bf16 [4][130][130][64]  (dead after k_zr)
#define B_QINP  9081344    // bf16 [4][130][130][64]  (dead after stageB)
#define B_ZBUF  17734144   // bf16 [4][128][32][128]
#define B_XL    428544     // bf16 [4][HWT][64] overlays HXP (written in stageB, right before mega)

// ---------------- K1: stage1 = weight-prep blocks + encoder blocks (merged launch) ----------------
__global__ void __launch_bounds__(256) k_stage1(
    const float* __restrict__ enc_w, const float* __restrict__ enc_b,
    const float* __restrict__ bn_g, const float* __restrict__ bn_b,
    const float* __restrict__ bn_m, const float* __restrict__ bn_v,
    const float* __restrict__ gwz, const float* __restrict__ gbz,
    const float* __restrict__ gwr, const float* __restrict__ gbr,
    const float* __restrict__ gwq, const float* __restrict__ gbq,
    const float* __restrict__ dww, const float* __restrict__ dwb,
    const float* __restrict__ lng, const float* __restrict__ lnb,
    const float* __restrict__ offw, const float* __restrict__ offb,
    const float* __restrict__ maskw, const float* __restrict__ maskb,
    const float* __restrict__ inpw, const float* __restrict__ inpb,
    const float* __restrict__ outw, const float* __restrict__ outb,
    float* __restrict__ Wp, bf16* __restrict__ wzrb, bf16* __restrict__ wqb,
    bf16* __restrict__ womb, bf16* __restrict__ woutb,
    bf16* __restrict__ hxp, bf16* __restrict__ qinp,
    const float* __restrict__ X, const float* __restrict__ Y) {
  __shared__ float xls[4096];
  __shared__ float ewls[2048];
  __shared__ float escl[64];
  int tid = threadIdx.x;
  int b = blockIdx.x;

  if (b < NB_PREPB) {
    int i = b * 256 + tid;
    if (i >= NTOT) return;
    if (i >= NPREP) {
      int t = i - NPREP;
      int img = t / 516, r = t % 516;
      int ph, pw;
      if (r < 130) { ph = 0; pw = r; }
      else if (r < 260) { ph = 129; pw = r - 130; }
      else if (r < 388) { ph = r - 260 + 1; pw = 0; }
      else { ph = r - 388 + 1; pw = 129; }
      size_t pb = (((size_t)img * 130 + ph) * 130 + pw) * 64;
      uint4 zz = make_uint4(0, 0, 0, 0);
      #pragma unroll
      for (int k = 0; k < 8; ++k) {
        ((uint4*)(hxp + pb))[k] = zz;
        ((uint4*)(qinp + pb))[k] = zz;
      }
      return;
    }
    if (i >= NW_TOTAL) {
      int d = i - NW_TOTAL;
      if (d < NBF_ZR) {
        int t = d / 9216, rem = d % 9216;
        int kc = rem / 512, rem2 = rem % 512;
        int ln = rem2 >> 3, j = rem2 & 7;
        int n = t * 16 + (ln & 15);
        int cin = (kc & 1) * 32 + ((ln >> 4) << 3) + j;
        int tap = kc >> 1;
        float v = (n < 32) ? gwz[(n*64 + cin)*9 + tap] : gwr[((n-32)*64 + cin)*9 + tap];
        wzrb[d] = f2b(v);
      } else if (d < NBF_ZR + NBF_Q) {
        int d2 = d - NBF_ZR;
        int t = d2 / 9216, rem = d2 % 9216;
        int kc = rem / 512, rem2 = rem % 512;
        int ln = rem2 >> 3, j = rem2 & 7;
        int n = t * 16 + (ln & 15);
        int cin = (kc & 1) * 32 + ((ln >> 4) << 3) + j;
        int tap = kc >> 1;
        wqb[d2] = f2b(gwq[(n*64 + cin)*9 + tap]);
      } else if (d < NBF_ZR + NBF_Q + NBF_OM) {
        int d3 = d - NBF_ZR - NBF_Q;
        int wv = d3 / 1024, rem = d3 % 1024;
        int kc = rem / 512, rem2 = rem % 512;
        int ln = rem2 >> 3, j = rem2 & 7;
        int jcol = wv * 16 + (ln & 15);
        int c = kc * 32 + ((ln >> 4) << 3) + j;
        float v = (jcol < 72) ? offw[jcol*64 + c] : ((jcol < 108) ? maskw[(jcol-72)*64 + c] : 0.f);
        womb[d3] = f2b(v);
      } else {
        int d4 = d - NBF_ZR - NBF_Q - NBF_OM;
        int nt = d4 / 1024, rem = d4 % 1024;
        int kc = rem / 512, rem2 = rem % 512;
        int ln = rem2 >> 3, j = rem2 & 7;
        int o = nt * 16 + (ln & 15);
        int c = kc * 32 + ((ln >> 4) << 3) + j;
        woutb[d4] = f2b(outw[o*64 + c]);
      }
      return;
    }
    float v;
    if (i < 20544) {
      if (i >= OFF_WINPB && i < OFF_WINPB + 2048) {
        // bf16 fragment-order inp_w: d = ((nt*2+kc)*64+ln)*8+j, packed 2 bf16 per float
        int d0 = (i - OFF_WINPB) * 2;
        int nt = d0 >> 10, kc = (d0 >> 9) & 1, lnn = (d0 >> 3) & 63, j0 = d0 & 7;
        int o = nt * 16 + (lnn & 15);
        int c = kc * 32 + ((lnn >> 4) << 3) + j0;
        unsigned lo = (unsigned)(unsigned short)f2bs(inpw[o * 64 + c]);
        unsigned hi = (unsigned)(unsigned short)f2bs(inpw[o * 64 + c + 1]);
        v = __uint_as_float(lo | (hi << 16));
      } else v = 0.f;
    }
    else if (i < 20576) { v = gbz[i - OFF_BZ]; }
    else if (i < 39008) { v = 0.f; }
    else if (i < 39040) { v = gbr[i - OFF_BR]; }
    else if (i < 57472) { v = 0.f; }
    else if (i < 57504) { v = gbq[i - OFF_BQ]; }
    else if (i < 58080) { int d = i - OFF_DWP; int tap = d >> 6, o = d & 63; v = dww[o*9 + tap]; }
    else if (i < 58144) { v = dwb[i - OFF_DWB]; }
    else if (i < 58208) { v = lng[i - OFF_LNG]; }
    else if (i < 58272) { v = lnb[i - OFF_LNB]; }
    else if (i < 65184) { v = 0.f; }
    else if (i < 65292) { int j = i - OFF_OMB; v = (j < 72) ? offb[j] : maskb[j-72]; }
    else if (i < 65296) { v = 0.f; }
    else if (i < 69392) { int d = i - OFF_WINP; int c = d >> 6, o = d & 63; v = inpw[o*64 + c]; }
    else if (i < 69456) { v = inpb[i - OFF_BINP]; }
    else if (i < 73552) { v = 0.f; }
    else { v = outb[i - OFF_BOUT]; }
    Wp[i] = v;
    return;
  }

  // ===== encoder blocks =====
  int pb2 = b - NB_PREPB;
  int img = pb2 >> 8, h = (pb2 >> 1) & 127, w0 = (pb2 & 1) * 64;
  int px = tid & 63, sect = tid >> 6;
  #pragma unroll
  for (int k = 0; k < 8; ++k) {
    int i2 = k * 256 + tid;
    int c = i2 >> 5, o = i2 & 31;
    ewls[i2] = enc_w[o*64 + c];
  }
  if (tid < 32) {
    float sc = bn_g[tid] * rsqrtf(bn_v[tid] + 1e-5f);
    escl[tid] = sc;
    escl[32 + tid] = (enc_b[tid] - bn_m[tid]) * sc + bn_b[tid];
  }
  int hw = h * WT + w0 + px;
  const float* xp = X + (size_t)img * (64 * HWT) + hw;
  #pragma unroll
  for (int i2 = 0; i2 < 16; ++i2) {
    int c = sect * 16 + i2;
    xls[c * 64 + px] = xp[c * HWT];
  }
  const float* yp = Y + (size_t)img * (32 * HWT) + hw;
  bf16 yv[8];
  #pragma unroll
  for (int i2 = 0; i2 < 8; ++i2) yv[i2] = f2b(yp[(sect * 8 + i2) * HWT]);
  size_t pbb = (((size_t)img * 130 + h + 1) * 130 + (w0 + px + 1)) * 64;
  *(uint4*)(hxp + pbb + sect * 8) = *(const uint4*)yv;
  __syncthreads();
  float aen[8];
  #pragma unroll
  for (int o = 0; o < 8; ++o) aen[o] = 0.f;
  for (int k = 0; k < 64; ++k) {
    float a = xls[k * 64 + px];
    const float* we = ewls + k * 32 + sect * 8;
    #pragma unroll
    for (int o = 0; o < 8; ++o) aen[o] += a * we[o];
  }
  bf16 xe[8];
  #pragma unroll
  for (int o = 0; o < 8; ++o) {
    int oo = sect * 8 + o;
    float e = aen[o] * escl[oo] + escl[32 + oo];
    xe[o] = f2b(e / (1.f + __expf(-e)));
  }
  *(uint4*)(hxp + pbb + 32 + sect * 8) = *(const uint4*)xe;
  *(uint4*)(qinp + pbb + 32 + sect * 8) = *(const uint4*)xe;
}

// ---------------- K2: z+r implicit-GEMM, M=16/wave, 64-px blocks (2x occupancy vs R11) ----------------
__global__ void __launch_bounds__(256) k_zr(
    const float* __restrict__ Wp,
    const bf16* __restrict__ hxp, const bf16* __restrict__ wzrb,
    bf16* __restrict__ qinp, bf16* __restrict__ zbuf) {
  __shared__ short zt[32 * 72];
  __shared__ short ryt[64 * 40];
  int tid = threadIdx.x;
  int wv = tid >> 6, ln = tid & 63;
  int quad = ln >> 4, lm = ln & 15;
  int img = blockIdx.z, h = blockIdx.y;
  int x0 = blockIdx.x * 64;
  int p0 = x0 + wv * 16;
  const short* hs = (const short*)hxp;
  const short* ws = (const short*)wzrb;
  size_t rowb = ((size_t)img * 130 + h + 1) * 130;
  const short* ab = hs + (rowb + p0 + lm + 1) * 64 + quad * 8;
  short8v a[18];
  #pragma unroll
  for (int kc = 0; kc < 18; ++kc) {
    const int tap = kc >> 1, cin0 = (kc & 1) * 32;
    const int dd = (tap / 3 - 1) * 130 + (tap % 3 - 1);
    a[kc] = *(const short8v*)(ab + dd * 64 + cin0);
  }
  float4v acc[4];
  #pragma unroll
  for (int t = 0; t < 4; ++t) acc[t] = (float4v){0.f, 0.f, 0.f, 0.f};
  #pragma unroll
  for (int kc = 0; kc < 18; ++kc) {
    #pragma unroll
    for (int t = 0; t < 4; ++t) {
      short8v b = *(const short8v*)(ws + ((t * 18 + kc) * 64 + ln) * 8);
      acc[t] = __builtin_amdgcn_mfma_f32_16x16x32_bf16(a[kc], b, acc[t], 0, 0, 0);
    }
  }
  #pragma unroll
  for (int t = 0; t < 2; ++t) {
    int n = t * 16 + lm;
    float bz = Wp[OFF_BZ + n];
    short zp[4];
    #pragma unroll
    for (int ri = 0; ri < 4; ++ri)
      zp[ri] = f2bs(1.f / (1.f + __expf(-(acc[t][ri] + bz))));
    *(short4v*)(zt + n * 72 + wv * 16 + quad * 4) = *(const short4v*)zp;
  }
  #pragma unroll
  for (int t = 2; t < 4; ++t) {
    int c = (t - 2) * 16 + lm;
    float br = Wp[OFF_BR + c];
    #pragma unroll
    for (int ri = 0; ri < 4; ++ri) {
      int pxl = wv * 16 + quad * 4 + ri;
      float rv = 1.f / (1.f + __expf(-(acc[t][ri] + br)));
      float yy = b2f(hxp[(rowb + x0 + pxl + 1) * 64 + c]);
      ryt[pxl * 40 + c] = f2bs(rv * yy);
    }
  }
  __syncthreads();
  {
    int n2 = tid >> 3, pq = tid & 7;
    short8v z0 = *(const short8v*)(zt + n2 * 72 + pq * 8);
    short* zo = (short*)zbuf + (((size_t)img * 128 + h) * 32 + n2) * 128 + x0 + pq * 8;
    *(short8v*)zo = z0;
  }
  {
    int px = tid >> 2, cq = tid & 3;
    short8v r0 = *(const short8v*)(ryt + px * 40 + cq * 8);
    short* qo = (short*)qinp + (rowb + x0 + px + 1) * 64 + cq * 8;
    *(short8v*)qo = r0;
  }
}

// ---------------- K3: stageB v2 — 2048 uniform 64-px blocks, XCD h-band swizzle ----------------
__global__ void __launch_bounds__(256) k_stageB(
    const float* __restrict__ Y, const float* __restrict__ Wp,
    const bf16* __restrict__ qinp, const bf16* __restrict__ wqb,
    const bf16* __restrict__ zbuf, float* __restrict__ outh,
    const float* __restrict__ X, bf16* __restrict__ xl) {
  __shared__ short xs[64 * 72];
  int tid = threadIdx.x;
  int bid = blockIdx.x;
  int xcd = bid & 7, u = bid >> 3;           // u 0..255
  int part = u & 1, slot = u >> 1;           // slot 0..127
  int img = slot >> 5, rem = slot & 31;
  int hh = xcd * 16 + (rem & 15);
  int w0 = (rem >> 4) * 64;
  int wv = tid >> 6, ln = tid & 63, quad = ln >> 4, lm = ln & 15;

  if (part == 0) {
    // ===== q-GEMM: 64 px, N=32; wave wv owns 16-px M-tile =====
    int p0 = w0 + wv * 16;
    const short* qs = (const short*)qinp;
    const short* ws = (const short*)wqb;
    size_t rowb = ((size_t)img * 130 + hh + 1) * 130;
    const short* ab = qs + (rowb + p0 + lm + 1) * 64 + quad * 8;
    float4v acc0 = (float4v){0.f,0.f,0.f,0.f};
    float4v acc1 = (float4v){0.f,0.f,0.f,0.f};
    #pragma unroll
    for (int kc = 0; kc < 18; ++kc) {
      const int tap = kc >> 1, cin0 = (kc & 1) * 32;
      const int dd = (tap / 3 - 1) * 130 + (tap % 3 - 1);
      short8v a  = *(const short8v*)(ab + dd * 64 + cin0);
      short8v b0 = *(const short8v*)(ws + ((0 * 18 + kc) * 64 + ln) * 8);
      short8v b1 = *(const short8v*)(ws + ((1 * 18 + kc) * 64 + ln) * 8);
      acc0 = __builtin_amdgcn_mfma_f32_16x16x32_bf16(a, b0, acc0, 0, 0, 0);
      acc1 = __builtin_amdgcn_mfma_f32_16x16x32_bf16(a, b1, acc1, 0, 0, 0);
    }
    int px4 = p0 + quad * 4;
    #pragma unroll
    for (int t = 0; t < 2; ++t) {
      float4v acc = t ? acc1 : acc0;
      int n = t * 16 + lm;
      float bq = Wp[OFF_BQ + n];
      size_t gb = ((size_t)img * 32 + n) * HWT + hh * 128 + px4;
      uint2 zz = *(const uint2*)((const short*)zbuf + (((size_t)img * 128 + hh) * 32 + n) * 128 + px4);
      float4 yv = *(const float4*)(Y + gb);
      float z0 = bu2f((unsigned short)(zz.x & 0xFFFFu)), z1 = bu2f((unsigned short)(zz.x >> 16));
      float z2 = bu2f((unsigned short)(zz.y & 0xFFFFu)), z3 = bu2f((unsigned short)(zz.y >> 16));
      float4 o;
      o.x = (1.f - z0) * yv.x + z0 * ftanh(acc[0] + bq);
      o.y = (1.f - z1) * yv.y + z1 * ftanh(acc[1] + bq);
      o.z = (1.f - z2) * yv.z + z2 * ftanh(acc[2] + bq);
      o.w = (1.f - z3) * yv.w + z3 * ftanh(acc[3] + bq);
      *(float4*)(outh + gb) = o;
    }
    return;
  }

  // ===== input linear via MFMA =====
  {
    const float* xb = X + (size_t)img * (64 * HWT) + hh * 128 + w0 + wv * 16 + lm;
    short8v a[2];
    #pragma unroll
    for (int kc = 0; kc < 2; ++kc) {
      short tmp[8];
      #pragma unroll
      for (int j = 0; j < 8; ++j)
        tmp[j] = f2bs(xb[(size_t)(kc * 32 + quad * 8 + j) * HWT]);
      a[kc] = *(const short8v*)tmp;
    }
    const short* wib = (const short*)Wp + 2 * OFF_WINPB;
    float4v acc[4];
    #pragma unroll
    for (int nt = 0; nt < 4; ++nt) acc[nt] = (float4v){0.f,0.f,0.f,0.f};
    #pragma unroll
    for (int kc = 0; kc < 2; ++kc) {
      #pragma unroll
      for (int nt = 0; nt < 4; ++nt) {
        short8v b = *(const short8v*)(wib + ((nt * 2 + kc) * 64 + ln) * 8);
        acc[nt] = __builtin_amdgcn_mfma_f32_16x16x32_bf16(a[kc], b, acc[nt], 0, 0, 0);
      }
    }
    #pragma unroll
    for (int nt = 0; nt < 4; ++nt) {
      int o = nt * 16 + lm;
      float bias = Wp[OFF_BINP + o];
      #pragma unroll
      for (int ri = 0; ri < 4; ++ri)
        xs[(wv * 16 + quad * 4 + ri) * 72 + o] = f2bs(acc[nt][ri] + bias);
    }
    __syncthreads();
    int row = tid >> 2, c0 = (tid & 3) * 16;
    short8v v0 = *(const short8v*)(xs + row * 72 + c0);
    short8v v1 = *(const short8v*)(xs + row * 72 + c0 + 8);
    short* op = (short*)xl + ((size_t)img * HWT + hh * 128 + w0 + row) * 64 + c0;
    *(short8v*)op = v0;
    *(short8v*)(op + 8) = v1;
  }
}

// ---------------- K5 mega (512 thr, forced 8 waves/SIMD) with XCD h-band swizzle ----------------
#define LDS_PSA  0         // f32 [8][64]      2048
#define LDS_PSB  2048      // f32 [8][64]      2048
#define LDS_STAT 4096      // f32 [64][2]      512
#define LDS_Y    4608      // bf16 [64][72]    9216  (vls overlays after P2)
#define LDS_OM   13824     // bf16 [64][114]   14592
#define LDS_TOT  28416

__global__ void __launch_bounds__(512, 8) k_mega(
    const float* __restrict__ Wp, const float* __restrict__ hb,
    const bf16* __restrict__ xl, const bf16* __restrict__ womb,
    const bf16* __restrict__ woutb, float* __restrict__ out0) {
  __shared__ char smem[LDS_TOT];
  float* psa  = (float*)(smem + LDS_PSA);
  float* psb  = (float*)(smem + LDS_PSB);
  float* stat = (float*)(smem + LDS_STAT);
  short* yls  = (short*)(smem + LDS_Y);
  short* omls = (short*)(smem + LDS_OM);
  short* vls  = (short*)(smem + LDS_Y);

  int tid = threadIdx.x;
  int bid = blockIdx.x;
  int xcd = bid & 7, slot = bid >> 3;            // slot 0..127
  int img = slot >> 5;                           // 4 imgs
  int rem = slot & 31;                           // 2 w-tiles x 16 h
  int h = xcd * 16 + (rem & 15);
  int w0 = (rem >> 4) * 64;

  int wloc = tid & 63, part = tid >> 6;
  int w = w0 + wloc;
  float yv[8];
  {
    const float* hn = hb + (size_t)img * (32 * HWT);
    #pragma unroll
    for (int i = 0; i < 8; ++i) yv[i] = Wp[OFF_DWB + part*8 + i];
    #pragma unroll
    for (int tap = 0; tap < 9; ++tap) {
      int dy = tap / 3 - 1, dx = tap % 3 - 1;
      int hh = h + dy, ww = w + dx;
      bool ok = ((unsigned)hh < 128u) && ((unsigned)ww < 128u);
      int off = hh * WT + ww;
      #pragma unroll
      for (int j = 0; j < 4; ++j) {
        int cin = part * 4 + j;
        float a = ok ? hn[cin * HWT + off] : 0.f;
        yv[2*j]   += a * Wp[OFF_DWP + tap*64 + part*8 + 2*j];
        yv[2*j+1] += a * Wp[OFF_DWP + tap*64 + part*8 + 2*j+1];
      }
    }
  }
  float lsum = 0.f, lsq = 0.f;
  #pragma unroll
  for (int i = 0; i < 8; ++i) { lsum += yv[i]; lsq += yv[i]*yv[i]; }
  psa[part * 64 + wloc] = lsum;
  psb[part * 64 + wloc] = lsq;
  __syncthreads();
  if (tid < 64) {
    float s = 0.f, q = 0.f;
    #pragma unroll
    for (int p = 0; p < 8; ++p) { s += psa[p*64 + tid]; q += psb[p*64 + tid]; }
    float mu = s * (1.f/64.f);
    float var = q * (1.f/64.f) - mu * mu;
    stat[tid*2] = mu;
    stat[tid*2+1] = rsqrtf(var + 1e-6f);
  }
  __syncthreads();
  {
    float mu = stat[wloc*2], inv = stat[wloc*2+1];
    bf16 tmp[8];
    #pragma unroll
    for (int i = 0; i < 8; ++i) {
      int c = part*8 + i;
      float v = (yv[i] - mu) * inv * Wp[OFF_LNG + c] + Wp[OFF_LNB + c];
      tmp[i] = f2b(gelu_f(v));
    }
    *(short8v*)(yls + wloc*72 + part*8) = *(const short8v*)tmp;
  }
  __syncthreads();

  int wv = tid >> 6, ln = tid & 63, quad = ln >> 4, lm = ln & 15;
  if (wv < 7) {
    const short* wb = (const short*)womb;
    float4v acc[4];
    #pragma unroll
    for (int mt = 0; mt < 4; ++mt) acc[mt] = (float4v){0.f,0.f,0.f,0.f};
    #pragma unroll
    for (int kc = 0; kc < 2; ++kc) {
      short8v b = *(const short8v*)(wb + ((wv * 2 + kc) * 64 + ln) * 8);
      #pragma unroll
      for (int mt = 0; mt < 4; ++mt) {
        short8v a = *(const short8v*)(yls + (mt*16 + lm)*72 + kc*32 + quad*8);
        acc[mt] = __builtin_amdgcn_mfma_f32_16x16x32_bf16(a, b, acc[mt], 0, 0, 0);
      }
    }
    float bias = Wp[OFF_OMB + wv*16 + lm];
    #pragma unroll
    for (int mt = 0; mt < 4; ++mt) {
      #pragma unroll
      for (int ri = 0; ri < 4; ++ri)
        omls[(mt*16 + quad*4 + ri)*114 + wv*16 + lm] = f2bs(acc[mt][ri] + bias);
    }
  }
  __syncthreads();

  {
    int px = tid >> 3, g = (tid >> 1) & 3, half = tid & 1;
    const short* oml = omls + px*114;
    float m[9];
    #pragma unroll
    for (int p = 0; p < 9; ++p) m[p] = bu2f((unsigned short)oml[72 + g*9 + p]);
    float mx = m[0];
    #pragma unroll
    for (int p = 1; p < 9; ++p) mx = fmaxf(mx, m[p]);
    float sum = 0.f;
    #pragma unroll
    for (int p = 0; p < 9; ++p) { m[p] = __expf(m[p] - mx); sum += m[p]; }
    float rs = 1.f / sum;
    int wg = w0 + px;
    const short* xn = (const short*)xl + (size_t)img * (HWT * 64) + g * 16 + half * 8;
    float2v acc2[4];
    #pragma unroll
    for (int q = 0; q < 4; ++q) acc2[q] = (float2v){0.f, 0.f};
    for (int p = 0; p < 9; ++p) {
      float ox = bu2f((unsigned short)oml[g*18 + p*2]);
      float oy = bu2f((unsigned short)oml[g*18 + p*2 + 1]);
      float pxx = (float)(wg + p / 3 - 1) + ox;
      float pyy = (float)(h + p % 3 - 1) + oy;
      float fx = floorf(pxx), fy = floorf(pyy);
      int jx0 = (int)fx, jy0 = (int)fy;
      int jx1 = jx0 + 1, jy1 = jy0 + 1;
      float wx1 = pxx - fx, wy1 = pyy - fy;
      float wx0 = 1.f - wx1, wy0 = 1.f - wy1;
      float mk = m[p];  // softmax denom applied once after the loop
      // factorized validity folded into axis weights (zeros-padding semantics)
      wx0 = ((unsigned)jx0 < 128u) ? wx0 : 0.f;
      wx1 = ((unsigned)jx1 < 128u) ? wx1 : 0.f;
      wy0 = ((unsigned)jy0 < 128u) ? wy0 * mk : 0.f;
      wy1 = ((unsigned)jy1 < 128u) ? wy1 * mk : 0.f;
      int ax0 = min(max(jx0, 0), 127), ax1 = min(max(jx1, 0), 127);
      int ay0 = min(max(jy0, 0), 127), ay1 = min(max(jy1, 0), 127);
      // pair 1: row ay0 (2 uint4 in flight)
      {
        const short* r0 = xn + (size_t)(ay0 * WT) * 64;
        uint4 u00 = *(const uint4*)(r0 + ax0 * 64);
        uint4 u10 = *(const uint4*)(r0 + ax1 * 64);
        float c00 = wx0 * wy0, c10 = wx1 * wy0;
        float2v cc;
        cc = (float2v){c00, c00};
        acc2[0] += cc * bfpair(u00.x); acc2[1] += cc * bfpair(u00.y);
        acc2[2] += cc * bfpair(u00.z); acc2[3] += cc * bfpair(u00.w);
        cc = (float2v){c10, c10};
        acc2[0] += cc * bfpair(u10.x); acc2[1] += cc * bfpair(u10.y);
        acc2[2] += cc * bfpair(u10.z); acc2[3] += cc * bfpair(u10.w);
      }
      // pair 2: row ay1
      {
        const short* r1 = xn + (size_t)(ay1 * WT) * 64;
        uint4 u01 = *(const uint4*)(r1 + ax0 * 64);
        uint4 u11 = *(const uint4*)(r1 + ax1 * 64);
        float c01 = wx0 * wy1, c11 = wx1 * wy1;
        float2v cc;
        cc = (float2v){c01, c01};
        acc2[0] += cc * bfpair(u01.x); acc2[1] += cc * bfpair(u01.y);
        acc2[2] += cc * bfpair(u01.z); acc2[3] += cc * bfpair(u01.w);
        cc = (float2v){c11, c11};
        acc2[0] += cc * bfpair(u11.x); acc2[1] += cc * bfpair(u11.y);
        acc2[2] += cc * bfpair(u11.z); acc2[3] += cc * bfpair(u11.w);
      }
    }
    bf16 tmp[8];
    #pragma unroll
    for (int q = 0; q < 4; ++q) {
      tmp[2*q]   = f2b(acc2[q].x * rs);
      tmp[2*q+1] = f2b(acc2[q].y * rs);
    }
    *(short8v*)(vls + px*72 + g*16 + half*8) = *(const short8v*)tmp;
  }
  __syncthreads();

  {
    const short* wb = (const short*)woutb;
    #pragma unroll
    for (int s = 0; s < 2; ++s) {
      int tile = wv * 2 + s;
      int nt = tile >> 2, mt = tile & 3;
      float4v acc = (float4v){0.f,0.f,0.f,0.f};
      #pragma unroll
      for (int kc = 0; kc < 2; ++kc) {
        short8v b = *(const short8v*)(wb + ((nt * 2 + kc) * 64 + ln) * 8);
        short8v a = *(const short8v*)(vls + (mt*16 + lm)*72 + kc*32 + quad*8);
        acc = __builtin_amdgcn_mfma_f32_16x16x32_bf16(a, b, acc, 0, 0, 0);
      }
      int ch = nt*16 + lm;
      float bias = Wp[OFF_BOUT + ch];
      float4 v;
      float s0 = acc[0] + bias; v.x = s0 / (1.f + __expf(-s0));
      float s1 = acc[1] + bias; v.y = s1 / (1.f + __expf(-s1));
      float s2 = acc[2] + bias; v.z = s2 / (1.f + __expf(-s2));
      float s3 = acc[3] + bias; v.w = s3 / (1.f + __expf(-s3));
      *(float4*)(out0 + ((size_t)img*64 + ch)*HWT + h*128 + w0 + mt*16 + quad*4) = v;
    }
  }
}

extern "C" void kernel_launch(void* const* d_in, const int* in_sizes, int n_in,
                              void* d_out, int out_size, void* d_ws, size_t ws_size,
                              hipStream_t stream) {
  const float* input_x = (const float*)d_in[0];
  const float* input_y = (const float*)d_in[1];

  float* Wp = (float*)d_ws;
  bf16* WZRB  = (bf16*)((char*)d_ws + B_WZRB);
  bf16* WQB   = (bf16*)((char*)d_ws + B_WQB);
  bf16* WOMB  = (bf16*)((char*)d_ws + B_WOMB);
  bf16* WOUTB = (bf16*)((char*)d_ws + B_WOUTB);
  bf16* HXP   = (bf16*)((char*)d_ws + B_HXP);
  bf16* QINP  = (bf16*)((char*)d_ws + B_QINP);
  bf16* ZBUF  = (bf16*)((char*)d_ws + B_ZBUF);
  bf16* XL    = (bf16*)((char*)d_ws + B_XL);
  float* out0 = (float*)d_out;
  float* outh = (float*)d_out + 4194304;

  k_stage1<<<dim3(NB_PREPB + 1024), dim3(256), 0, stream>>>(
      (const float*)d_in[2], (const float*)d_in[3], (const float*)d_in[4], (const float*)d_in[5],
      (const float*)d_in[6], (const float*)d_in[7], (const float*)d_in[8], (const float*)d_in[9],
      (const float*)d_in[10], (const float*)d_in[11], (const float*)d_in[12], (const float*)d_in[13],
      (const float*)d_in[14], (const float*)d_in[15], (const float*)d_in[16], (const float*)d_in[17],
      (const float*)d_in[18], (const float*)d_in[19], (const float*)d_in[20], (const float*)d_in[21],
      (const float*)d_in[22], (const float*)d_in[23], (const float*)d_in[24], (const float*)d_in[25],
      Wp, WZRB, WQB, WOMB, WOUTB, HXP, QINP, input_x, input_y);
  k_zr<<<dim3(2, 128, 4), dim3(256), 0, stream>>>(Wp, HXP, WZRB, QINP, ZBUF);
  k_stageB<<<dim3(2048), dim3(256), 0, stream>>>(input_y, Wp, QINP, WQB, ZBUF, outh, input_x, XL);
  k_mega<<<dim3(1024), dim3(512), 0, stream>>>(Wp, outh, XL, WOMB, WOUTB, out0);
}

// Round 4
// 241.019 us; speedup vs baseline: 1.4103x; 1.4103x over previous
//
#include <hip/hip_runtime.h>
#include <hip/hip_bf16.h>

typedef __hip_bfloat16 bf16;
typedef short short8v __attribute__((ext_vector_type(8)));
typedef short short4v __attribute__((ext_vector_type(4)));
typedef float float4v __attribute__((ext_vector_type(4)));
typedef float float2v __attribute__((ext_vector_type(2)));

static __device__ __forceinline__ float b2f(bf16 v){ return __bfloat162float(v); }
static __device__ __forceinline__ bf16 f2b(float v){ return __float2bfloat16(v); }
static __device__ __forceinline__ float bu2f(unsigned short u){ return __uint_as_float(((unsigned)u) << 16); }
static __device__ __forceinline__ short f2bs(float v){ bf16 t = __float2bfloat16(v); return *(short*)&t; }
static __device__ __forceinline__ float ftanh(float x){ return 1.f - 2.f / (1.f + __expf(2.f * x)); }
// bf16 pair -> float2 (low element = even channel)
static __device__ __forceinline__ float2v bfpair(unsigned u){
  float2v r; r.x = __uint_as_float(u << 16); r.y = __uint_as_float(u & 0xffff0000u); return r;
}
// exact-GELU via A&S 7.1.26 erf (|err|<=1.5e-7), no libm call
static __device__ __forceinline__ float gelu_f(float v){
  float x = v * 0.70710678118654752f;
  float ax = fabsf(x);
  float t = __builtin_amdgcn_rcpf(__builtin_fmaf(0.3275911f, ax, 1.f));
  float p = __builtin_fmaf(1.061405429f, t, -1.453152027f);
  p = __builtin_fmaf(p, t, 1.421413741f);
  p = __builtin_fmaf(p, t, -0.284496736f);
  p = __builtin_fmaf(p, t, 0.254829592f);
  p = p * t;
  float e = __expf(-ax * ax);
  float er = __builtin_fmaf(-p, e, 1.f);
  er = copysignf(er, x);
  return 0.5f * v * (1.f + er);
}

#define WT 128
#define HWT 16384

// ---- packed f32 weights (float offsets inside ws) ----
#define OFF_WINPB 1024     // bf16 fragment-order [nt:4][kc:2][ln:64][j:8] packed 2/float (2048 floats)
#define OFF_BZ    20544    // 32
#define OFF_BR    39008    // 32
#define OFF_BQ    57472    // 32
#define OFF_DWP   57504    // [tap][64]        576
#define OFF_DWB   58080    // 64
#define OFF_LNG   58144    // 64
#define OFF_LNB   58208    // 64
#define OFF_OMB   65184    // 108 (+4 zero pad)
#define OFF_WINP  65296    // [c][64]          4096
#define OFF_BINP  69392    // 64
#define OFF_BOUT  73552    // 64
#define NW_TOTAL  73616
#define NBF_ZR    36864    // bf16 fragment-order [t:4][kc:18][ln:64][j:8]
#define NBF_Q     18432    // bf16 fragment-order [t:2][kc:18][ln:64][j:8]
#define NBF_OM    7168     // bf16 fragment-order [wv:7][kc:2][ln:64][j:8]
#define NBF_OUT   4096     // bf16 fragment-order [nt:4][kc:2][ln:64][j:8]
#define NPREP     (NW_TOTAL + NBF_ZR + NBF_Q + NBF_OM + NBF_OUT)
#define NHALO     2064     // 4 imgs * 516 halo pixels
#define NTOT      (NPREP + NHALO)
#define NB_PREPB  556      // ceil(NTOT/256)

// ---- ws byte offsets (end = 21,928,448 B) ----
#define B_WZRB  294912
#define B_WQB   368640
#define B_WOMB  405504
#define B_WOUTB 419840
#define B_HXP   428544     // bf16 [4][130][130][64]  (dead after k_zr)
#define B_QINP  9081344    // bf16 [4][130][130][64]  (dead after stageB)
#define B_ZBUF  17734144   // bf16 [4][128][32][128]
#define B_XL    428544     // bf16 [4][HWT][64] overlays HXP (written in stageB, right before mega)

// ---------------- K1: stage1 = weight-prep blocks + encoder blocks (merged launch) ----------------
__global__ void __launch_bounds__(256) k_stage1(
    const float* __restrict__ enc_w, const float* __restrict__ enc_b,
    const float* __restrict__ bn_g, const float* __restrict__ bn_b,
    const float* __restrict__ bn_m, const float* __restrict__ bn_v,
    const float* __restrict__ gwz, const float* __restrict__ gbz,
    const float* __restrict__ gwr, const float* __restrict__ gbr,
    const float* __restrict__ gwq, const float* __restrict__ gbq,
    const float* __restrict__ dww, const float* __restrict__ dwb,
    const float* __restrict__ lng, const float* __restrict__ lnb,
    const float* __restrict__ offw, const float* __restrict__ offb,
    const float* __restrict__ maskw, const float* __restrict__ maskb,
    const float* __restrict__ inpw, const float* __restrict__ inpb,
    const float* __restrict__ outw, const float* __restrict__ outb,
    float* __restrict__ Wp, bf16* __restrict__ wzrb, bf16* __restrict__ wqb,
    bf16* __restrict__ womb, bf16* __restrict__ woutb,
    bf16* __restrict__ hxp, bf16* __restrict__ qinp,
    const float* __restrict__ X, const float* __restrict__ Y) {
  __shared__ float xls[4096];
  __shared__ float ewls[2048];
  __shared__ float escl[64];
  int tid = threadIdx.x;
  int b = blockIdx.x;

  if (b < NB_PREPB) {
    int i = b * 256 + tid;
    if (i >= NTOT) return;
    if (i >= NPREP) {
      int t = i - NPREP;
      int img = t / 516, r = t % 516;
      int ph, pw;
      if (r < 130) { ph = 0; pw = r; }
      else if (r < 260) { ph = 129; pw = r - 130; }
      else if (r < 388) { ph = r - 260 + 1; pw = 0; }
      else { ph = r - 388 + 1; pw = 129; }
      size_t pb = (((size_t)img * 130 + ph) * 130 + pw) * 64;
      uint4 zz = make_uint4(0, 0, 0, 0);
      #pragma unroll
      for (int k = 0; k < 8; ++k) {
        ((uint4*)(hxp + pb))[k] = zz;
        ((uint4*)(qinp + pb))[k] = zz;
      }
      return;
    }
    if (i >= NW_TOTAL) {
      int d = i - NW_TOTAL;
      if (d < NBF_ZR) {
        int t = d / 9216, rem = d % 9216;
        int kc = rem / 512, rem2 = rem % 512;
        int ln = rem2 >> 3, j = rem2 & 7;
        int n = t * 16 + (ln & 15);
        int cin = (kc & 1) * 32 + ((ln >> 4) << 3) + j;
        int tap = kc >> 1;
        float v = (n < 32) ? gwz[(n*64 + cin)*9 + tap] : gwr[((n-32)*64 + cin)*9 + tap];
        wzrb[d] = f2b(v);
      } else if (d < NBF_ZR + NBF_Q) {
        int d2 = d - NBF_ZR;
        int t = d2 / 9216, rem = d2 % 9216;
        int kc = rem / 512, rem2 = rem % 512;
        int ln = rem2 >> 3, j = rem2 & 7;
        int n = t * 16 + (ln & 15);
        int cin = (kc & 1) * 32 + ((ln >> 4) << 3) + j;
        int tap = kc >> 1;
        wqb[d2] = f2b(gwq[(n*64 + cin)*9 + tap]);
      } else if (d < NBF_ZR + NBF_Q + NBF_OM) {
        int d3 = d - NBF_ZR - NBF_Q;
        int wv = d3 / 1024, rem = d3 % 1024;
        int kc = rem / 512, rem2 = rem % 512;
        int ln = rem2 >> 3, j = rem2 & 7;
        int jcol = wv * 16 + (ln & 15);
        int c = kc * 32 + ((ln >> 4) << 3) + j;
        float v = (jcol < 72) ? offw[jcol*64 + c] : ((jcol < 108) ? maskw[(jcol-72)*64 + c] : 0.f);
        womb[d3] = f2b(v);
      } else {
        int d4 = d - NBF_ZR - NBF_Q - NBF_OM;
        int nt = d4 / 1024, rem = d4 % 1024;
        int kc = rem / 512, rem2 = rem % 512;
        int ln = rem2 >> 3, j = rem2 & 7;
        int o = nt * 16 + (ln & 15);
        int c = kc * 32 + ((ln >> 4) << 3) + j;
        woutb[d4] = f2b(outw[o*64 + c]);
      }
      return;
    }
    float v;
    if (i < 20544) {
      if (i >= OFF_WINPB && i < OFF_WINPB + 2048) {
        // bf16 fragment-order inp_w: d = ((nt*2+kc)*64+ln)*8+j, packed 2 bf16 per float
        int d0 = (i - OFF_WINPB) * 2;
        int nt = d0 >> 10, kc = (d0 >> 9) & 1, lnn = (d0 >> 3) & 63, j0 = d0 & 7;
        int o = nt * 16 + (lnn & 15);
        int c = kc * 32 + ((lnn >> 4) << 3) + j0;
        unsigned lo = (unsigned)(unsigned short)f2bs(inpw[o * 64 + c]);
        unsigned hi = (unsigned)(unsigned short)f2bs(inpw[o * 64 + c + 1]);
        v = __uint_as_float(lo | (hi << 16));
      } else v = 0.f;
    }
    else if (i < 20576) { v = gbz[i - OFF_BZ]; }
    else if (i < 39008) { v = 0.f; }
    else if (i < 39040) { v = gbr[i - OFF_BR]; }
    else if (i < 57472) { v = 0.f; }
    else if (i < 57504) { v = gbq[i - OFF_BQ]; }
    else if (i < 58080) { int d = i - OFF_DWP; int tap = d >> 6, o = d & 63; v = dww[o*9 + tap]; }
    else if (i < 58144) { v = dwb[i - OFF_DWB]; }
    else if (i < 58208) { v = lng[i - OFF_LNG]; }
    else if (i < 58272) { v = lnb[i - OFF_LNB]; }
    else if (i < 65184) { v = 0.f; }
    else if (i < 65292) { int j = i - OFF_OMB; v = (j < 72) ? offb[j] : maskb[j-72]; }
    else if (i < 65296) { v = 0.f; }
    else if (i < 69392) { int d = i - OFF_WINP; int c = d >> 6, o = d & 63; v = inpw[o*64 + c]; }
    else if (i < 69456) { v = inpb[i - OFF_BINP]; }
    else if (i < 73552) { v = 0.f; }
    else { v = outb[i - OFF_BOUT]; }
    Wp[i] = v;
    return;
  }

  // ===== encoder blocks =====
  int pb2 = b - NB_PREPB;
  int img = pb2 >> 8, h = (pb2 >> 1) & 127, w0 = (pb2 & 1) * 64;
  int px = tid & 63, sect = tid >> 6;
  #pragma unroll
  for (int k = 0; k < 8; ++k) {
    int i2 = k * 256 + tid;
    int c = i2 >> 5, o = i2 & 31;
    ewls[i2] = enc_w[o*64 + c];
  }
  if (tid < 32) {
    float sc = bn_g[tid] * rsqrtf(bn_v[tid] + 1e-5f);
    escl[tid] = sc;
    escl[32 + tid] = (enc_b[tid] - bn_m[tid]) * sc + bn_b[tid];
  }
  int hw = h * WT + w0 + px;
  const float* xp = X + (size_t)img * (64 * HWT) + hw;
  #pragma unroll
  for (int i2 = 0; i2 < 16; ++i2) {
    int c = sect * 16 + i2;
    xls[c * 64 + px] = xp[c * HWT];
  }
  const float* yp = Y + (size_t)img * (32 * HWT) + hw;
  bf16 yv[8];
  #pragma unroll
  for (int i2 = 0; i2 < 8; ++i2) yv[i2] = f2b(yp[(sect * 8 + i2) * HWT]);
  size_t pbb = (((size_t)img * 130 + h + 1) * 130 + (w0 + px + 1)) * 64;
  *(uint4*)(hxp + pbb + sect * 8) = *(const uint4*)yv;
  __syncthreads();
  float aen[8];
  #pragma unroll
  for (int o = 0; o < 8; ++o) aen[o] = 0.f;
  for (int k = 0; k < 64; ++k) {
    float a = xls[k * 64 + px];
    const float* we = ewls + k * 32 + sect * 8;
    #pragma unroll
    for (int o = 0; o < 8; ++o) aen[o] += a * we[o];
  }
  bf16 xe[8];
  #pragma unroll
  for (int o = 0; o < 8; ++o) {
    int oo = sect * 8 + o;
    float e = aen[o] * escl[oo] + escl[32 + oo];
    xe[o] = f2b(e / (1.f + __expf(-e)));
  }
  *(uint4*)(hxp + pbb + 32 + sect * 8) = *(const uint4*)xe;
  *(uint4*)(qinp + pbb + 32 + sect * 8) = *(const uint4*)xe;
}

// ---------------- K2: z+r implicit-GEMM, M=16/wave, 64-px blocks (2x occupancy vs R11) ----------------
__global__ void __launch_bounds__(256) k_zr(
    const float* __restrict__ Wp,
    const bf16* __restrict__ hxp, const bf16* __restrict__ wzrb,
    bf16* __restrict__ qinp, bf16* __restrict__ zbuf) {
  __shared__ short zt[32 * 72];
  __shared__ short ryt[64 * 40];
  int tid = threadIdx.x;
  int wv = tid >> 6, ln = tid & 63;
  int quad = ln >> 4, lm = ln & 15;
  int img = blockIdx.z, h = blockIdx.y;
  int x0 = blockIdx.x * 64;
  int p0 = x0 + wv * 16;
  const short* hs = (const short*)hxp;
  const short* ws = (const short*)wzrb;
  size_t rowb = ((size_t)img * 130 + h + 1) * 130;
  const short* ab = hs + (rowb + p0 + lm + 1) * 64 + quad * 8;
  short8v a[18];
  #pragma unroll
  for (int kc = 0; kc < 18; ++kc) {
    const int tap = kc >> 1, cin0 = (kc & 1) * 32;
    const int dd = (tap / 3 - 1) * 130 + (tap % 3 - 1);
    a[kc] = *(const short8v*)(ab + dd * 64 + cin0);
  }
  float4v acc[4];
  #pragma unroll
  for (int t = 0; t < 4; ++t) acc[t] = (float4v){0.f, 0.f, 0.f, 0.f};
  #pragma unroll
  for (int kc = 0; kc < 18; ++kc) {
    #pragma unroll
    for (int t = 0; t < 4; ++t) {
      short8v b = *(const short8v*)(ws + ((t * 18 + kc) * 64 + ln) * 8);
      acc[t] = __builtin_amdgcn_mfma_f32_16x16x32_bf16(a[kc], b, acc[t], 0, 0, 0);
    }
  }
  #pragma unroll
  for (int t = 0; t < 2; ++t) {
    int n = t * 16 + lm;
    float bz = Wp[OFF_BZ + n];
    short zp[4];
    #pragma unroll
    for (int ri = 0; ri < 4; ++ri)
      zp[ri] = f2bs(1.f / (1.f + __expf(-(acc[t][ri] + bz))));
    *(short4v*)(zt + n * 72 + wv * 16 + quad * 4) = *(const short4v*)zp;
  }
  #pragma unroll
  for (int t = 2; t < 4; ++t) {
    int c = (t - 2) * 16 + lm;
    float br = Wp[OFF_BR + c];
    #pragma unroll
    for (int ri = 0; ri < 4; ++ri) {
      int pxl = wv * 16 + quad * 4 + ri;
      float rv = 1.f / (1.f + __expf(-(acc[t][ri] + br)));
      float yy = b2f(hxp[(rowb + x0 + pxl + 1) * 64 + c]);
      ryt[pxl * 40 + c] = f2bs(rv * yy);
    }
  }
  __syncthreads();
  {
    int n2 = tid >> 3, pq = tid & 7;
    short8v z0 = *(const short8v*)(zt + n2 * 72 + pq * 8);
    short* zo = (short*)zbuf + (((size_t)img * 128 + h) * 32 + n2) * 128 + x0 + pq * 8;
    *(short8v*)zo = z0;
  }
  {
    int px = tid >> 2, cq = tid & 3;
    short8v r0 = *(const short8v*)(ryt + px * 40 + cq * 8);
    short* qo = (short*)qinp + (rowb + x0 + px + 1) * 64 + cq * 8;
    *(short8v*)qo = r0;
  }
}

// ---------------- K3: stageB v2 — 2048 uniform 64-px blocks, XCD h-band swizzle ----------------
__global__ void __launch_bounds__(256) k_stageB(
    const float* __restrict__ Y, const float* __restrict__ Wp,
    const bf16* __restrict__ qinp, const bf16* __restrict__ wqb,
    const bf16* __restrict__ zbuf, float* __restrict__ outh,
    const float* __restrict__ X, bf16* __restrict__ xl) {
  __shared__ short xs[64 * 72];
  int tid = threadIdx.x;
  int bid = blockIdx.x;
  int xcd = bid & 7, u = bid >> 3;           // u 0..255
  int part = u & 1, slot = u >> 1;           // slot 0..127
  int img = slot >> 5, rem = slot & 31;
  int hh = xcd * 16 + (rem & 15);
  int w0 = (rem >> 4) * 64;
  int wv = tid >> 6, ln = tid & 63, quad = ln >> 4, lm = ln & 15;

  if (part == 0) {
    // ===== q-GEMM: 64 px, N=32; wave wv owns 16-px M-tile =====
    int p0 = w0 + wv * 16;
    const short* qs = (const short*)qinp;
    const short* ws = (const short*)wqb;
    size_t rowb = ((size_t)img * 130 + hh + 1) * 130;
    const short* ab = qs + (rowb + p0 + lm + 1) * 64 + quad * 8;
    float4v acc0 = (float4v){0.f,0.f,0.f,0.f};
    float4v acc1 = (float4v){0.f,0.f,0.f,0.f};
    #pragma unroll
    for (int kc = 0; kc < 18; ++kc) {
      const int tap = kc >> 1, cin0 = (kc & 1) * 32;
      const int dd = (tap / 3 - 1) * 130 + (tap % 3 - 1);
      short8v a  = *(const short8v*)(ab + dd * 64 + cin0);
      short8v b0 = *(const short8v*)(ws + ((0 * 18 + kc) * 64 + ln) * 8);
      short8v b1 = *(const short8v*)(ws + ((1 * 18 + kc) * 64 + ln) * 8);
      acc0 = __builtin_amdgcn_mfma_f32_16x16x32_bf16(a, b0, acc0, 0, 0, 0);
      acc1 = __builtin_amdgcn_mfma_f32_16x16x32_bf16(a, b1, acc1, 0, 0, 0);
    }
    int px4 = p0 + quad * 4;
    #pragma unroll
    for (int t = 0; t < 2; ++t) {
      float4v acc = t ? acc1 : acc0;
      int n = t * 16 + lm;
      float bq = Wp[OFF_BQ + n];
      size_t gb = ((size_t)img * 32 + n) * HWT + hh * 128 + px4;
      uint2 zz = *(const uint2*)((const short*)zbuf + (((size_t)img * 128 + hh) * 32 + n) * 128 + px4);
      float4 yv = *(const float4*)(Y + gb);
      float z0 = bu2f((unsigned short)(zz.x & 0xFFFFu)), z1 = bu2f((unsigned short)(zz.x >> 16));
      float z2 = bu2f((unsigned short)(zz.y & 0xFFFFu)), z3 = bu2f((unsigned short)(zz.y >> 16));
      float4 o;
      o.x = (1.f - z0) * yv.x + z0 * ftanh(acc[0] + bq);
      o.y = (1.f - z1) * yv.y + z1 * ftanh(acc[1] + bq);
      o.z = (1.f - z2) * yv.z + z2 * ftanh(acc[2] + bq);
      o.w = (1.f - z3) * yv.w + z3 * ftanh(acc[3] + bq);
      *(float4*)(outh + gb) = o;
    }
    return;
  }

  // ===== input linear via MFMA =====
  {
    const float* xb = X + (size_t)img * (64 * HWT) + hh * 128 + w0 + wv * 16 + lm;
    short8v a[2];
    #pragma unroll
    for (int kc = 0; kc < 2; ++kc) {
      short tmp[8];
      #pragma unroll
      for (int j = 0; j < 8; ++j)
        tmp[j] = f2bs(xb[(size_t)(kc * 32 + quad * 8 + j) * HWT]);
      a[kc] = *(const short8v*)tmp;
    }
    const short* wib = (const short*)Wp + 2 * OFF_WINPB;
    float4v acc[4];
    #pragma unroll
    for (int nt = 0; nt < 4; ++nt) acc[nt] = (float4v){0.f,0.f,0.f,0.f};
    #pragma unroll
    for (int kc = 0; kc < 2; ++kc) {
      #pragma unroll
      for (int nt = 0; nt < 4; ++nt) {
        short8v b = *(const short8v*)(wib + ((nt * 2 + kc) * 64 + ln) * 8);
        acc[nt] = __builtin_amdgcn_mfma_f32_16x16x32_bf16(a[kc], b, acc[nt], 0, 0, 0);
      }
    }
    #pragma unroll
    for (int nt = 0; nt < 4; ++nt) {
      int o = nt * 16 + lm;
      float bias = Wp[OFF_BINP + o];
      #pragma unroll
      for (int ri = 0; ri < 4; ++ri)
        xs[(wv * 16 + quad * 4 + ri) * 72 + o] = f2bs(acc[nt][ri] + bias);
    }
    __syncthreads();
    int row = tid >> 2, c0 = (tid & 3) * 16;
    short8v v0 = *(const short8v*)(xs + row * 72 + c0);
    short8v v1 = *(const short8v*)(xs + row * 72 + c0 + 8);
    short* op = (short*)xl + ((size_t)img * HWT + hh * 128 + w0 + row) * 64 + c0;
    *(short8v*)op = v0;
    *(short8v*)(op + 8) = v1;
  }
}

// ---------------- K5 mega (512 thr, R1 gather structure + pk-FMA) with XCD h-band swizzle ----------------
#define LDS_PSA  0         // f32 [8][64]      2048
#define LDS_PSB  2048      // f32 [8][64]      2048
#define LDS_STAT 4096      // f32 [64][2]      512
#define LDS_Y    4608      // bf16 [64][72]    9216  (vls overlays after P2)
#define LDS_OM   13824     // bf16 [64][114]   14592
#define LDS_TOT  28416

__global__ void __launch_bounds__(512) k_mega(
    const float* __restrict__ Wp, const float* __restrict__ hb,
    const bf16* __restrict__ xl, const bf16* __restrict__ womb,
    const bf16* __restrict__ woutb, float* __restrict__ out0) {
  __shared__ char smem[LDS_TOT];
  float* psa  = (float*)(smem + LDS_PSA);
  float* psb  = (float*)(smem + LDS_PSB);
  float* stat = (float*)(smem + LDS_STAT);
  short* yls  = (short*)(smem + LDS_Y);
  short* omls = (short*)(smem + LDS_OM);
  short* vls  = (short*)(smem + LDS_Y);

  int tid = threadIdx.x;
  int bid = blockIdx.x;
  int xcd = bid & 7, slot = bid >> 3;            // slot 0..127
  int img = slot >> 5;                           // 4 imgs
  int rem = slot & 31;                           // 2 w-tiles x 16 h
  int h = xcd * 16 + (rem & 15);
  int w0 = (rem >> 4) * 64;

  int wloc = tid & 63, part = tid >> 6;
  int w = w0 + wloc;
  float yv[8];
  {
    const float* hn = hb + (size_t)img * (32 * HWT);
    #pragma unroll
    for (int i = 0; i < 8; ++i) yv[i] = Wp[OFF_DWB + part*8 + i];
    #pragma unroll
    for (int tap = 0; tap < 9; ++tap) {
      int dy = tap / 3 - 1, dx = tap % 3 - 1;
      int hh = h + dy, ww = w + dx;
      bool ok = ((unsigned)hh < 128u) && ((unsigned)ww < 128u);
      int off = hh * WT + ww;
      #pragma unroll
      for (int j = 0; j < 4; ++j) {
        int cin = part * 4 + j;
        float a = ok ? hn[cin * HWT + off] : 0.f;
        yv[2*j]   += a * Wp[OFF_DWP + tap*64 + part*8 + 2*j];
        yv[2*j+1] += a * Wp[OFF_DWP + tap*64 + part*8 + 2*j+1];
      }
    }
  }
  float lsum = 0.f, lsq = 0.f;
  #pragma unroll
  for (int i = 0; i < 8; ++i) { lsum += yv[i]; lsq += yv[i]*yv[i]; }
  psa[part * 64 + wloc] = lsum;
  psb[part * 64 + wloc] = lsq;
  __syncthreads();
  if (tid < 64) {
    float s = 0.f, q = 0.f;
    #pragma unroll
    for (int p = 0; p < 8; ++p) { s += psa[p*64 + tid]; q += psb[p*64 + tid]; }
    float mu = s * (1.f/64.f);
    float var = q * (1.f/64.f) - mu * mu;
    stat[tid*2] = mu;
    stat[tid*2+1] = rsqrtf(var + 1e-6f);
  }
  __syncthreads();
  {
    float mu = stat[wloc*2], inv = stat[wloc*2+1];
    bf16 tmp[8];
    #pragma unroll
    for (int i = 0; i < 8; ++i) {
      int c = part*8 + i;
      float v = (yv[i] - mu) * inv * Wp[OFF_LNG + c] + Wp[OFF_LNB + c];
      tmp[i] = f2b(gelu_f(v));
    }
    *(short8v*)(yls + wloc*72 + part*8) = *(const short8v*)tmp;
  }
  __syncthreads();

  int wv = tid >> 6, ln = tid & 63, quad = ln >> 4, lm = ln & 15;
  if (wv < 7) {
    const short* wb = (const short*)womb;
    float4v acc[4];
    #pragma unroll
    for (int mt = 0; mt < 4; ++mt) acc[mt] = (float4v){0.f,0.f,0.f,0.f};
    #pragma unroll
    for (int kc = 0; kc < 2; ++kc) {
      short8v b = *(const short8v*)(wb + ((wv * 2 + kc) * 64 + ln) * 8);
      #pragma unroll
      for (int mt = 0; mt < 4; ++mt) {
        short8v a = *(const short8v*)(yls + (mt*16 + lm)*72 + kc*32 + quad*8);
        acc[mt] = __builtin_amdgcn_mfma_f32_16x16x32_bf16(a, b, acc[mt], 0, 0, 0);
      }
    }
    float bias = Wp[OFF_OMB + wv*16 + lm];
    #pragma unroll
    for (int mt = 0; mt < 4; ++mt) {
      #pragma unroll
      for (int ri = 0; ri < 4; ++ri)
        omls[(mt*16 + quad*4 + ri)*114 + wv*16 + lm] = f2bs(acc[mt][ri] + bias);
    }
  }
  __syncthreads();

  {
    int px = tid >> 3, g = (tid >> 1) & 3, half = tid & 1;
    const short* oml = omls + px*114;
    float m[9];
    #pragma unroll
    for (int p = 0; p < 9; ++p) m[p] = bu2f((unsigned short)oml[72 + g*9 + p]);
    float mx = m[0];
    #pragma unroll
    for (int p = 1; p < 9; ++p) mx = fmaxf(mx, m[p]);
    float sum = 0.f;
    #pragma unroll
    for (int p = 0; p < 9; ++p) { m[p] = __expf(m[p] - mx); sum += m[p]; }
    float rs = 1.f / sum;
    int wg = w0 + px;
    const short* xn = (const short*)xl + (size_t)img * (HWT * 64) + g * 16 + half * 8;
    float2v acc2[4];
    #pragma unroll
    for (int q = 0; q < 4; ++q) acc2[q] = (float2v){0.f, 0.f};
    for (int p = 0; p < 9; ++p) {
      float ox = bu2f((unsigned short)oml[g*18 + p*2]);
      float oy = bu2f((unsigned short)oml[g*18 + p*2 + 1]);
      float pxx = (float)(wg + p / 3 - 1) + ox;
      float pyy = (float)(h + p % 3 - 1) + oy;
      float fx = floorf(pxx), fy = floorf(pyy);
      int jx0 = (int)fx, jy0 = (int)fy;
      float wx1 = pxx - fx, wy1 = pyy - fy;
      float wx0 = 1.f - wx1, wy0 = 1.f - wy1;
      float mk = m[p];  // softmax denom applied once after the loop
      int cjx[4] = { jx0, jx0 + 1, jx0, jx0 + 1 };
      int cjy[4] = { jy0, jy0, jy0 + 1, jy0 + 1 };
      float cw[4] = { wx0*wy0, wx1*wy0, wx0*wy1, wx1*wy1 };
      #pragma unroll
      for (int k = 0; k < 4; ++k) {
        if ((unsigned)cjx[k] < 128u && (unsigned)cjy[k] < 128u) {
          float cf = mk * cw[k];
          const short* s = xn + (size_t)(cjy[k] * WT + cjx[k]) * 64;
          uint4 u0 = *(const uint4*)s;
          float2v cc = (float2v){cf, cf};
          acc2[0] += cc * bfpair(u0.x);
          acc2[1] += cc * bfpair(u0.y);
          acc2[2] += cc * bfpair(u0.z);
          acc2[3] += cc * bfpair(u0.w);
        }
      }
    }
    bf16 tmp[8];
    #pragma unroll
    for (int q = 0; q < 4; ++q) {
      tmp[2*q]   = f2b(acc2[q].x * rs);
      tmp[2*q+1] = f2b(acc2[q].y * rs);
    }
    *(short8v*)(vls + px*72 + g*16 + half*8) = *(const short8v*)tmp;
  }
  __syncthreads();

  {
    const short* wb = (const short*)woutb;
    #pragma unroll
    for (int s = 0; s < 2; ++s) {
      int tile = wv * 2 + s;
      int nt = tile >> 2, mt = tile & 3;
      float4v acc = (float4v){0.f,0.f,0.f,0.f};
      #pragma unroll
      for (int kc = 0; kc < 2; ++kc) {
        short8v b = *(const short8v*)(wb + ((nt * 2 + kc) * 64 + ln) * 8);
        short8v a = *(const short8v*)(vls + (mt*16 + lm)*72 + kc*32 + quad*8);
        acc = __builtin_amdgcn_mfma_f32_16x16x32_bf16(a, b, acc, 0, 0, 0);
      }
      int ch = nt*16 + lm;
      float bias = Wp[OFF_BOUT + ch];
      float4 v;
      float s0 = acc[0] + bias; v.x = s0 / (1.f + __expf(-s0));
      float s1 = acc[1] + bias; v.y = s1 / (1.f + __expf(-s1));
      float s2 = acc[2] + bias; v.z = s2 / (1.f + __expf(-s2));
      float s3 = acc[3] + bias; v.w = s3 / (1.f + __expf(-s3));
      *(float4*)(out0 + ((size_t)img*64 + ch)*HWT + h*128 + w0 + mt*16 + quad*4) = v;
    }
  }
}

extern "C" void kernel_launch(void* const* d_in, const int* in_sizes, int n_in,
                              void* d_out, int out_size, void* d_ws, size_t ws_size,
                              hipStream_t stream) {
  const float* input_x = (const float*)d_in[0];
  const float* input_y = (const float*)d_in[1];

  float* Wp = (float*)d_ws;
  bf16* WZRB  = (bf16*)((char*)d_ws + B_WZRB);
  bf16* WQB   = (bf16*)((char*)d_ws + B_WQB);
  bf16* WOMB  = (bf16*)((char*)d_ws + B_WOMB);
  bf16* WOUTB = (bf16*)((char*)d_ws + B_WOUTB);
  bf16* HXP   = (bf16*)((char*)d_ws + B_HXP);
  bf16* QINP  = (bf16*)((char*)d_ws + B_QINP);
  bf16* ZBUF  = (bf16*)((char*)d_ws + B_ZBUF);
  bf16* XL    = (bf16*)((char*)d_ws + B_XL);
  float* out0 = (float*)d_out;
  float* outh = (float*)d_out + 4194304;

  k_stage1<<<dim3(NB_PREPB + 1024), dim3(256), 0, stream>>>(
      (const float*)d_in[2], (const float*)d_in[3], (const float*)d_in[4], (const float*)d_in[5],
      (const float*)d_in[6], (const float*)d_in[7], (const float*)d_in[8], (const float*)d_in[9],
      (const float*)d_in[10], (const float*)d_in[11], (const float*)d_in[12], (const float*)d_in[13],
      (const float*)d_in[14], (const float*)d_in[15], (const float*)d_in[16], (const float*)d_in[17],
      (const float*)d_in[18], (const float*)d_in[19], (const float*)d_in[20], (const float*)d_in[21],
      (const float*)d_in[22], (const float*)d_in[23], (const float*)d_in[24], (const float*)d_in[25],
      Wp, WZRB, WQB, WOMB, WOUTB, HXP, QINP, input_x, input_y);
  k_zr<<<dim3(2, 128, 4), dim3(256), 0, stream>>>(Wp, HXP, WZRB, QINP, ZBUF);
  k_stageB<<<dim3(2048), dim3(256), 0, stream>>>(input_y, Wp, QINP, WQB, ZBUF, outh, input_x, XL);
  k_mega<<<dim3(1024), dim3(512), 0, stream>>>(Wp, outh, XL, WOMB, WOUTB, out0);
}

// Round 5
// 240.860 us; speedup vs baseline: 1.4112x; 1.0007x over previous
//
#include <hip/hip_runtime.h>
#include <hip/hip_bf16.h>

typedef __hip_bfloat16 bf16;
typedef short short8v __attribute__((ext_vector_type(8)));
typedef short short4v __attribute__((ext_vector_type(4)));
typedef float float4v __attribute__((ext_vector_type(4)));

static __device__ __forceinline__ float b2f(bf16 v){ return __bfloat162float(v); }
static __device__ __forceinline__ bf16 f2b(float v){ return __float2bfloat16(v); }
static __device__ __forceinline__ float bu2f(unsigned short u){ return __uint_as_float(((unsigned)u) << 16); }
static __device__ __forceinline__ short f2bs(float v){ bf16 t = __float2bfloat16(v); return *(short*)&t; }
static __device__ __forceinline__ float ftanh(float x){ return 1.f - 2.f / (1.f + __expf(2.f * x)); }
// exact-GELU via A&S 7.1.26 erf (|err|<=1.5e-7), no libm call
static __device__ __forceinline__ float gelu_f(float v){
  float x = v * 0.70710678118654752f;
  float ax = fabsf(x);
  float t = __builtin_amdgcn_rcpf(__builtin_fmaf(0.3275911f, ax, 1.f));
  float p = __builtin_fmaf(1.061405429f, t, -1.453152027f);
  p = __builtin_fmaf(p, t, 1.421413741f);
  p = __builtin_fmaf(p, t, -0.284496736f);
  p = __builtin_fmaf(p, t, 0.254829592f);
  p = p * t;
  float e = __expf(-ax * ax);
  float er = __builtin_fmaf(-p, e, 1.f);
  er = copysignf(er, x);
  return 0.5f * v * (1.f + er);
}

#define WT 128
#define HWT 16384

// ---- packed f32 weights (float offsets inside ws) ----
#define OFF_WINPB 1024     // bf16 fragment-order [nt:4][kc:2][ln:64][j:8] packed 2/float (2048 floats)
#define OFF_BZ    20544    // 32
#define OFF_BR    39008    // 32
#define OFF_BQ    57472    // 32
#define OFF_DWP   57504    // [tap][64]        576
#define OFF_DWB   58080    // 64
#define OFF_LNG   58144    // 64
#define OFF_LNB   58208    // 64
#define OFF_OMB   65184    // 108 (+4 zero pad)
#define OFF_WINP  65296    // [c][64]          4096
#define OFF_BINP  69392    // 64
#define OFF_BOUT  73552    // 64
#define NW_TOTAL  73616
#define NBF_ZR    36864    // bf16 fragment-order [t:4][kc:18][ln:64][j:8]
#define NBF_Q     18432    // bf16 fragment-order [t:2][kc:18][ln:64][j:8]
#define NBF_OM    7168     // bf16 fragment-order [wv:7][kc:2][ln:64][j:8]
#define NBF_OUT   4096     // bf16 fragment-order [nt:4][kc:2][ln:64][j:8]
#define NPREP     (NW_TOTAL + NBF_ZR + NBF_Q + NBF_OM + NBF_OUT)
#define NHALO     2064     // 4 imgs * 516 halo pixels
#define NTOT      (NPREP + NHALO)
#define NB_PREPB  556      // ceil(NTOT/256)

// ---- ws byte offsets (end = 21,928,448 B) ----
#define B_WZRB  294912
#define B_WQB   368640
#define B_WOMB  405504
#define B_WOUTB 419840
#define B_HXP   428544     // bf16 [4][130][130][64]  (dead after k_zr)
#define B_QINP  9081344    // bf16 [4][130][130][64]  (dead after stageB)
#define B_ZBUF  17734144   // bf16 [4][128][32][128]
#define B_XL    428544     // bf16 [4][HWT][64] overlays HXP (written in stageB, right before mega)

// ---------------- K1: stage1 = weight-prep blocks + encoder blocks (merged launch) ----------------
__global__ void __launch_bounds__(256) k_stage1(
    const float* __restrict__ enc_w, const float* __restrict__ enc_b,
    const float* __restrict__ bn_g, const float* __restrict__ bn_b,
    const float* __restrict__ bn_m, const float* __restrict__ bn_v,
    const float* __restrict__ gwz, const float* __restrict__ gbz,
    const float* __restrict__ gwr, const float* __restrict__ gbr,
    const float* __restrict__ gwq, const float* __restrict__ gbq,
    const float* __restrict__ dww, const float* __restrict__ dwb,
    const float* __restrict__ lng, const float* __restrict__ lnb,
    const float* __restrict__ offw, const float* __restrict__ offb,
    const float* __restrict__ maskw, const float* __restrict__ maskb,
    const float* __restrict__ inpw, const float* __restrict__ inpb,
    const float* __restrict__ outw, const float* __restrict__ outb,
    float* __restrict__ Wp, bf16* __restrict__ wzrb, bf16* __restrict__ wqb,
    bf16* __restrict__ womb, bf16* __restrict__ woutb,
    bf16* __restrict__ hxp, bf16* __restrict__ qinp,
    const float* __restrict__ X, const float* __restrict__ Y) {
  __shared__ float xls[4096];
  __shared__ float ewls[2048];
  __shared__ float escl[64];
  int tid = threadIdx.x;
  int b = blockIdx.x;

  if (b < NB_PREPB) {
    int i = b * 256 + tid;
    if (i >= NTOT) return;
    if (i >= NPREP) {
      int t = i - NPREP;
      int img = t / 516, r = t % 516;
      int ph, pw;
      if (r < 130) { ph = 0; pw = r; }
      else if (r < 260) { ph = 129; pw = r - 130; }
      else if (r < 388) { ph = r - 260 + 1; pw = 0; }
      else { ph = r - 388 + 1; pw = 129; }
      size_t pb = (((size_t)img * 130 + ph) * 130 + pw) * 64;
      uint4 zz = make_uint4(0, 0, 0, 0);
      #pragma unroll
      for (int k = 0; k < 8; ++k) {
        ((uint4*)(hxp + pb))[k] = zz;
        ((uint4*)(qinp + pb))[k] = zz;
      }
      return;
    }
    if (i >= NW_TOTAL) {
      int d = i - NW_TOTAL;
      if (d < NBF_ZR) {
        int t = d / 9216, rem = d % 9216;
        int kc = rem / 512, rem2 = rem % 512;
        int ln = rem2 >> 3, j = rem2 & 7;
        int n = t * 16 + (ln & 15);
        int cin = (kc & 1) * 32 + ((ln >> 4) << 3) + j;
        int tap = kc >> 1;
        float v = (n < 32) ? gwz[(n*64 + cin)*9 + tap] : gwr[((n-32)*64 + cin)*9 + tap];
        wzrb[d] = f2b(v);
      } else if (d < NBF_ZR + NBF_Q) {
        int d2 = d - NBF_ZR;
        int t = d2 / 9216, rem = d2 % 9216;
        int kc = rem / 512, rem2 = rem % 512;
        int ln = rem2 >> 3, j = rem2 & 7;
        int n = t * 16 + (ln & 15);
        int cin = (kc & 1) * 32 + ((ln >> 4) << 3) + j;
        int tap = kc >> 1;
        wqb[d2] = f2b(gwq[(n*64 + cin)*9 + tap]);
      } else if (d < NBF_ZR + NBF_Q + NBF_OM) {
        int d3 = d - NBF_ZR - NBF_Q;
        int wv = d3 / 1024, rem = d3 % 1024;
        int kc = rem / 512, rem2 = rem % 512;
        int ln = rem2 >> 3, j = rem2 & 7;
        int jcol = wv * 16 + (ln & 15);
        int c = kc * 32 + ((ln >> 4) << 3) + j;
        float v = (jcol < 72) ? offw[jcol*64 + c] : ((jcol < 108) ? maskw[(jcol-72)*64 + c] : 0.f);
        womb[d3] = f2b(v);
      } else {
        int d4 = d - NBF_ZR - NBF_Q - NBF_OM;
        int nt = d4 / 1024, rem = d4 % 1024;
        int kc = rem / 512, rem2 = rem % 512;
        int ln = rem2 >> 3, j = rem2 & 7;
        int o = nt * 16 + (ln & 15);
        int c = kc * 32 + ((ln >> 4) << 3) + j;
        woutb[d4] = f2b(outw[o*64 + c]);
      }
      return;
    }
    float v;
    if (i < 20544) {
      if (i >= OFF_WINPB && i < OFF_WINPB + 2048) {
        // bf16 fragment-order inp_w: d = ((nt*2+kc)*64+ln)*8+j, packed 2 bf16 per float
        int d0 = (i - OFF_WINPB) * 2;
        int nt = d0 >> 10, kc = (d0 >> 9) & 1, lnn = (d0 >> 3) & 63, j0 = d0 & 7;
        int o = nt * 16 + (lnn & 15);
        int c = kc * 32 + ((lnn >> 4) << 3) + j0;
        unsigned lo = (unsigned)(unsigned short)f2bs(inpw[o * 64 + c]);
        unsigned hi = (unsigned)(unsigned short)f2bs(inpw[o * 64 + c + 1]);
        v = __uint_as_float(lo | (hi << 16));
      } else v = 0.f;
    }
    else if (i < 20576) { v = gbz[i - OFF_BZ]; }
    else if (i < 39008) { v = 0.f; }
    else if (i < 39040) { v = gbr[i - OFF_BR]; }
    else if (i < 57472) { v = 0.f; }
    else if (i < 57504) { v = gbq[i - OFF_BQ]; }
    else if (i < 58080) { int d = i - OFF_DWP; int tap = d >> 6, o = d & 63; v = dww[o*9 + tap]; }
    else if (i < 58144) { v = dwb[i - OFF_DWB]; }
    else if (i < 58208) { v = lng[i - OFF_LNG]; }
    else if (i < 58272) { v = lnb[i - OFF_LNB]; }
    else if (i < 65184) { v = 0.f; }
    else if (i < 65292) { int j = i - OFF_OMB; v = (j < 72) ? offb[j] : maskb[j-72]; }
    else if (i < 65296) { v = 0.f; }
    else if (i < 69392) { int d = i - OFF_WINP; int c = d >> 6, o = d & 63; v = inpw[o*64 + c]; }
    else if (i < 69456) { v = inpb[i - OFF_BINP]; }
    else if (i < 73552) { v = 0.f; }
    else { v = outb[i - OFF_BOUT]; }
    Wp[i] = v;
    return;
  }

  // ===== encoder blocks =====
  int pb2 = b - NB_PREPB;
  int img = pb2 >> 8, h = (pb2 >> 1) & 127, w0 = (pb2 & 1) * 64;
  int px = tid & 63, sect = tid >> 6;
  #pragma unroll
  for (int k = 0; k < 8; ++k) {
    int i2 = k * 256 + tid;
    int c = i2 >> 5, o = i2 & 31;
    ewls[i2] = enc_w[o*64 + c];
  }
  if (tid < 32) {
    float sc = bn_g[tid] * rsqrtf(bn_v[tid] + 1e-5f);
    escl[tid] = sc;
    escl[32 + tid] = (enc_b[tid] - bn_m[tid]) * sc + bn_b[tid];
  }
  int hw = h * WT + w0 + px;
  const float* xp = X + (size_t)img * (64 * HWT) + hw;
  #pragma unroll
  for (int i2 = 0; i2 < 16; ++i2) {
    int c = sect * 16 + i2;
    xls[c * 64 + px] = xp[c * HWT];
  }
  const float* yp = Y + (size_t)img * (32 * HWT) + hw;
  bf16 yv[8];
  #pragma unroll
  for (int i2 = 0; i2 < 8; ++i2) yv[i2] = f2b(yp[(sect * 8 + i2) * HWT]);
  size_t pbb = (((size_t)img * 130 + h + 1) * 130 + (w0 + px + 1)) * 64;
  *(uint4*)(hxp + pbb + sect * 8) = *(const uint4*)yv;
  __syncthreads();
  float aen[8];
  #pragma unroll
  for (int o = 0; o < 8; ++o) aen[o] = 0.f;
  for (int k = 0; k < 64; ++k) {
    float a = xls[k * 64 + px];
    const float* we = ewls + k * 32 + sect * 8;
    #pragma unroll
    for (int o = 0; o < 8; ++o) aen[o] += a * we[o];
  }
  bf16 xe[8];
  #pragma unroll
  for (int o = 0; o < 8; ++o) {
    int oo = sect * 8 + o;
    float e = aen[o] * escl[oo] + escl[32 + oo];
    xe[o] = f2b(e / (1.f + __expf(-e)));
  }
  *(uint4*)(hxp + pbb + 32 + sect * 8) = *(const uint4*)xe;
  *(uint4*)(qinp + pbb + 32 + sect * 8) = *(const uint4*)xe;
}

// ---------------- K2: z+r implicit-GEMM, M=16/wave, 64-px blocks (2x occupancy vs R11) ----------------
__global__ void __launch_bounds__(256) k_zr(
    const float* __restrict__ Wp,
    const bf16* __restrict__ hxp, const bf16* __restrict__ wzrb,
    bf16* __restrict__ qinp, bf16* __restrict__ zbuf) {
  __shared__ short zt[32 * 72];
  __shared__ short ryt[64 * 40];
  int tid = threadIdx.x;
  int wv = tid >> 6, ln = tid & 63;
  int quad = ln >> 4, lm = ln & 15;
  int img = blockIdx.z, h = blockIdx.y;
  int x0 = blockIdx.x * 64;
  int p0 = x0 + wv * 16;
  const short* hs = (const short*)hxp;
  const short* ws = (const short*)wzrb;
  size_t rowb = ((size_t)img * 130 + h + 1) * 130;
  const short* ab = hs + (rowb + p0 + lm + 1) * 64 + quad * 8;
  short8v a[18];
  #pragma unroll
  for (int kc = 0; kc < 18; ++kc) {
    const int tap = kc >> 1, cin0 = (kc & 1) * 32;
    const int dd = (tap / 3 - 1) * 130 + (tap % 3 - 1);
    a[kc] = *(const short8v*)(ab + dd * 64 + cin0);
  }
  float4v acc[4];
  #pragma unroll
  for (int t = 0; t < 4; ++t) acc[t] = (float4v){0.f, 0.f, 0.f, 0.f};
  #pragma unroll
  for (int kc = 0; kc < 18; ++kc) {
    #pragma unroll
    for (int t = 0; t < 4; ++t) {
      short8v b = *(const short8v*)(ws + ((t * 18 + kc) * 64 + ln) * 8);
      acc[t] = __builtin_amdgcn_mfma_f32_16x16x32_bf16(a[kc], b, acc[t], 0, 0, 0);
    }
  }
  #pragma unroll
  for (int t = 0; t < 2; ++t) {
    int n = t * 16 + lm;
    float bz = Wp[OFF_BZ + n];
    short zp[4];
    #pragma unroll
    for (int ri = 0; ri < 4; ++ri)
      zp[ri] = f2bs(1.f / (1.f + __expf(-(acc[t][ri] + bz))));
    *(short4v*)(zt + n * 72 + wv * 16 + quad * 4) = *(const short4v*)zp;
  }
  #pragma unroll
  for (int t = 2; t < 4; ++t) {
    int c = (t - 2) * 16 + lm;
    float br = Wp[OFF_BR + c];
    #pragma unroll
    for (int ri = 0; ri < 4; ++ri) {
      int pxl = wv * 16 + quad * 4 + ri;
      float rv = 1.f / (1.f + __expf(-(acc[t][ri] + br)));
      float yy = b2f(hxp[(rowb + x0 + pxl + 1) * 64 + c]);
      ryt[pxl * 40 + c] = f2bs(rv * yy);
    }
  }
  __syncthreads();
  {
    int n2 = tid >> 3, pq = tid & 7;
    short8v z0 = *(const short8v*)(zt + n2 * 72 + pq * 8);
    short* zo = (short*)zbuf + (((size_t)img * 128 + h) * 32 + n2) * 128 + x0 + pq * 8;
    *(short8v*)zo = z0;
  }
  {
    int px = tid >> 2, cq = tid & 3;
    short8v r0 = *(const short8v*)(ryt + px * 40 + cq * 8);
    short* qo = (short*)qinp + (rowb + x0 + px + 1) * 64 + cq * 8;
    *(short8v*)qo = r0;
  }
}

// ---------------- K3: stageB v2 — 2048 uniform 64-px blocks, XCD h-band swizzle ----------------
__global__ void __launch_bounds__(256) k_stageB(
    const float* __restrict__ Y, const float* __restrict__ Wp,
    const bf16* __restrict__ qinp, const bf16* __restrict__ wqb,
    const bf16* __restrict__ zbuf, float* __restrict__ outh,
    const float* __restrict__ X, bf16* __restrict__ xl) {
  __shared__ short xs[64 * 72];
  int tid = threadIdx.x;
  int bid = blockIdx.x;
  int xcd = bid & 7, u = bid >> 3;           // u 0..255
  int part = u & 1, slot = u >> 1;           // slot 0..127
  int img = slot >> 5, rem = slot & 31;
  int hh = xcd * 16 + (rem & 15);
  int w0 = (rem >> 4) * 64;
  int wv = tid >> 6, ln = tid & 63, quad = ln >> 4, lm = ln & 15;

  if (part == 0) {
    // ===== q-GEMM: 64 px, N=32; wave wv owns 16-px M-tile =====
    int p0 = w0 + wv * 16;
    const short* qs = (const short*)qinp;
    const short* ws = (const short*)wqb;
    size_t rowb = ((size_t)img * 130 + hh + 1) * 130;
    const short* ab = qs + (rowb + p0 + lm + 1) * 64 + quad * 8;
    float4v acc0 = (float4v){0.f,0.f,0.f,0.f};
    float4v acc1 = (float4v){0.f,0.f,0.f,0.f};
    #pragma unroll
    for (int kc = 0; kc < 18; ++kc) {
      const int tap = kc >> 1, cin0 = (kc & 1) * 32;
      const int dd = (tap / 3 - 1) * 130 + (tap % 3 - 1);
      short8v a  = *(const short8v*)(ab + dd * 64 + cin0);
      short8v b0 = *(const short8v*)(ws + ((0 * 18 + kc) * 64 + ln) * 8);
      short8v b1 = *(const short8v*)(ws + ((1 * 18 + kc) * 64 + ln) * 8);
      acc0 = __builtin_amdgcn_mfma_f32_16x16x32_bf16(a, b0, acc0, 0, 0, 0);
      acc1 = __builtin_amdgcn_mfma_f32_16x16x32_bf16(a, b1, acc1, 0, 0, 0);
    }
    int px4 = p0 + quad * 4;
    #pragma unroll
    for (int t = 0; t < 2; ++t) {
      float4v acc = t ? acc1 : acc0;
      int n = t * 16 + lm;
      float bq = Wp[OFF_BQ + n];
      size_t gb = ((size_t)img * 32 + n) * HWT + hh * 128 + px4;
      uint2 zz = *(const uint2*)((const short*)zbuf + (((size_t)img * 128 + hh) * 32 + n) * 128 + px4);
      float4 yv = *(const float4*)(Y + gb);
      float z0 = bu2f((unsigned short)(zz.x & 0xFFFFu)), z1 = bu2f((unsigned short)(zz.x >> 16));
      float z2 = bu2f((unsigned short)(zz.y & 0xFFFFu)), z3 = bu2f((unsigned short)(zz.y >> 16));
      float4 o;
      o.x = (1.f - z0) * yv.x + z0 * ftanh(acc[0] + bq);
      o.y = (1.f - z1) * yv.y + z1 * ftanh(acc[1] + bq);
      o.z = (1.f - z2) * yv.z + z2 * ftanh(acc[2] + bq);
      o.w = (1.f - z3) * yv.w + z3 * ftanh(acc[3] + bq);
      *(float4*)(outh + gb) = o;
    }
    return;
  }

  // ===== input linear via MFMA =====
  {
    const float* xb = X + (size_t)img * (64 * HWT) + hh * 128 + w0 + wv * 16 + lm;
    short8v a[2];
    #pragma unroll
    for (int kc = 0; kc < 2; ++kc) {
      short tmp[8];
      #pragma unroll
      for (int j = 0; j < 8; ++j)
        tmp[j] = f2bs(xb[(size_t)(kc * 32 + quad * 8 + j) * HWT]);
      a[kc] = *(const short8v*)tmp;
    }
    const short* wib = (const short*)Wp + 2 * OFF_WINPB;
    float4v acc[4];
    #pragma unroll
    for (int nt = 0; nt < 4; ++nt) acc[nt] = (float4v){0.f,0.f,0.f,0.f};
    #pragma unroll
    for (int kc = 0; kc < 2; ++kc) {
      #pragma unroll
      for (int nt = 0; nt < 4; ++nt) {
        short8v b = *(const short8v*)(wib + ((nt * 2 + kc) * 64 + ln) * 8);
        acc[nt] = __builtin_amdgcn_mfma_f32_16x16x32_bf16(a[kc], b, acc[nt], 0, 0, 0);
      }
    }
    #pragma unroll
    for (int nt = 0; nt < 4; ++nt) {
      int o = nt * 16 + lm;
      float bias = Wp[OFF_BINP + o];
      #pragma unroll
      for (int ri = 0; ri < 4; ++ri)
        xs[(wv * 16 + quad * 4 + ri) * 72 + o] = f2bs(acc[nt][ri] + bias);
    }
    __syncthreads();
    int row = tid >> 2, c0 = (tid & 3) * 16;
    short8v v0 = *(const short8v*)(xs + row * 72 + c0);
    short8v v1 = *(const short8v*)(xs + row * 72 + c0 + 8);
    short* op = (short*)xl + ((size_t)img * HWT + hh * 128 + w0 + row) * 64 + c0;
    *(short8v*)op = v0;
    *(short8v*)(op + 8) = v1;
  }
}

// ---------------- K5 mega (512 thr, R1 gather regime: 64-VGPR, branchy scalar corners) ----------------
#define LDS_PSA  0         // f32 [8][64]      2048
#define LDS_PSB  2048      // f32 [8][64]      2048
#define LDS_STAT 4096      // f32 [64][2]      512
#define LDS_Y    4608      // bf16 [64][72]    9216  (vls overlays after P2)
#define LDS_OM   13824     // bf16 [64][114]   14592
#define LDS_TOT  28416

__global__ void __launch_bounds__(512) k_mega(
    const float* __restrict__ Wp, const float* __restrict__ hb,
    const bf16* __restrict__ xl, const bf16* __restrict__ womb,
    const bf16* __restrict__ woutb, float* __restrict__ out0) {
  __shared__ char smem[LDS_TOT];
  float* psa  = (float*)(smem + LDS_PSA);
  float* psb  = (float*)(smem + LDS_PSB);
  float* stat = (float*)(smem + LDS_STAT);
  short* yls  = (short*)(smem + LDS_Y);
  short* omls = (short*)(smem + LDS_OM);
  short* vls  = (short*)(smem + LDS_Y);

  int tid = threadIdx.x;
  int bid = blockIdx.x;
  int xcd = bid & 7, slot = bid >> 3;            // slot 0..127
  int img = slot >> 5;                           // 4 imgs
  int rem = slot & 31;                           // 2 w-tiles x 16 h
  int h = xcd * 16 + (rem & 15);
  int w0 = (rem >> 4) * 64;

  int wloc = tid & 63, part = tid >> 6;
  int w = w0 + wloc;
  float yv[8];
  {
    const float* hn = hb + (size_t)img * (32 * HWT);
    #pragma unroll
    for (int i = 0; i < 8; ++i) yv[i] = Wp[OFF_DWB + part*8 + i];
    #pragma unroll
    for (int tap = 0; tap < 9; ++tap) {
      int dy = tap / 3 - 1, dx = tap % 3 - 1;
      int hh = h + dy, ww = w + dx;
      bool ok = ((unsigned)hh < 128u) && ((unsigned)ww < 128u);
      int off = hh * WT + ww;
      #pragma unroll
      for (int j = 0; j < 4; ++j) {
        int cin = part * 4 + j;
        float a = ok ? hn[cin * HWT + off] : 0.f;
        yv[2*j]   += a * Wp[OFF_DWP + tap*64 + part*8 + 2*j];
        yv[2*j+1] += a * Wp[OFF_DWP + tap*64 + part*8 + 2*j+1];
      }
    }
  }
  float lsum = 0.f, lsq = 0.f;
  #pragma unroll
  for (int i = 0; i < 8; ++i) { lsum += yv[i]; lsq += yv[i]*yv[i]; }
  psa[part * 64 + wloc] = lsum;
  psb[part * 64 + wloc] = lsq;
  __syncthreads();
  if (tid < 64) {
    float s = 0.f, q = 0.f;
    #pragma unroll
    for (int p = 0; p < 8; ++p) { s += psa[p*64 + tid]; q += psb[p*64 + tid]; }
    float mu = s * (1.f/64.f);
    float var = q * (1.f/64.f) - mu * mu;
    stat[tid*2] = mu;
    stat[tid*2+1] = rsqrtf(var + 1e-6f);
  }
  __syncthreads();
  {
    float mu = stat[wloc*2], inv = stat[wloc*2+1];
    bf16 tmp[8];
    #pragma unroll
    for (int i = 0; i < 8; ++i) {
      int c = part*8 + i;
      float v = (yv[i] - mu) * inv * Wp[OFF_LNG + c] + Wp[OFF_LNB + c];
      tmp[i] = f2b(gelu_f(v));
    }
    *(short8v*)(yls + wloc*72 + part*8) = *(const short8v*)tmp;
  }
  __syncthreads();

  int wv = tid >> 6, ln = tid & 63, quad = ln >> 4, lm = ln & 15;
  if (wv < 7) {
    const short* wb = (const short*)womb;
    float4v acc[4];
    #pragma unroll
    for (int mt = 0; mt < 4; ++mt) acc[mt] = (float4v){0.f,0.f,0.f,0.f};
    #pragma unroll
    for (int kc = 0; kc < 2; ++kc) {
      short8v b = *(const short8v*)(wb + ((wv * 2 + kc) * 64 + ln) * 8);
      #pragma unroll
      for (int mt = 0; mt < 4; ++mt) {
        short8v a = *(const short8v*)(yls + (mt*16 + lm)*72 + kc*32 + quad*8);
        acc[mt] = __builtin_amdgcn_mfma_f32_16x16x32_bf16(a, b, acc[mt], 0, 0, 0);
      }
    }
    float bias = Wp[OFF_OMB + wv*16 + lm];
    #pragma unroll
    for (int mt = 0; mt < 4; ++mt) {
      #pragma unroll
      for (int ri = 0; ri < 4; ++ri)
        omls[(mt*16 + quad*4 + ri)*114 + wv*16 + lm] = f2bs(acc[mt][ri] + bias);
    }
  }
  __syncthreads();

  {
    int px = tid >> 3, g = (tid >> 1) & 3, half = tid & 1;
    const short* oml = omls + px*114;
    float m[9];
    #pragma unroll
    for (int p = 0; p < 9; ++p) m[p] = bu2f((unsigned short)oml[72 + g*9 + p]);
    float mx = m[0];
    #pragma unroll
    for (int p = 1; p < 9; ++p) mx = fmaxf(mx, m[p]);
    float sum = 0.f;
    #pragma unroll
    for (int p = 0; p < 9; ++p) { m[p] = __expf(m[p] - mx); sum += m[p]; }
    float rs = 1.f / sum;
    int wg = w0 + px;
    const bf16* xn = xl + (size_t)img * (HWT * 64);
    float acc[8];
    #pragma unroll
    for (int i = 0; i < 8; ++i) acc[i] = 0.f;
    for (int p = 0; p < 9; ++p) {
      float bx = (float)(wg + p / 3 - 1);
      float by = (float)(h + p % 3 - 1);
      float ox = bu2f((unsigned short)oml[g*18 + p*2]);
      float oy = bu2f((unsigned short)oml[g*18 + p*2 + 1]);
      float mk = m[p] * rs;
      float pxx = bx + ox, pyy = by + oy;
      float fx = floorf(pxx), fy = floorf(pyy);
      int jx0 = (int)fx, jy0 = (int)fy;
      float wx1 = pxx - fx, wy1 = pyy - fy;
      float wx0 = 1.f - wx1, wy0 = 1.f - wy1;
      int cjx[4] = { jx0, jx0 + 1, jx0, jx0 + 1 };
      int cjy[4] = { jy0, jy0, jy0 + 1, jy0 + 1 };
      float cw[4] = { wx0*wy0, wx1*wy0, wx0*wy1, wx1*wy1 };
      #pragma unroll
      for (int k = 0; k < 4; ++k) {
        if ((unsigned)cjx[k] < 128u && (unsigned)cjy[k] < 128u) {
          float cf = mk * cw[k];
          const bf16* s = xn + (size_t)(cjy[k] * WT + cjx[k]) * 64 + g * 16 + half * 8;
          uint4 u0 = *(const uint4*)(s);
          const unsigned uu[4] = {u0.x,u0.y,u0.z,u0.w};
          #pragma unroll
          for (int q = 0; q < 4; ++q) {
            acc[2*q]     += cf * bu2f((unsigned short)(uu[q] & 0xFFFFu));
            acc[2*q + 1] += cf * bu2f((unsigned short)(uu[q] >> 16));
          }
        }
      }
    }
    bf16 tmp[8];
    #pragma unroll
    for (int i = 0; i < 8; ++i) tmp[i] = f2b(acc[i]);
    *(short8v*)(vls + px*72 + g*16 + half*8) = *(const short8v*)tmp;
  }
  __syncthreads();

  {
    const short* wb = (const short*)woutb;
    #pragma unroll
    for (int s = 0; s < 2; ++s) {
      int tile = wv * 2 + s;
      int nt = tile >> 2, mt = tile & 3;
      float4v acc = (float4v){0.f,0.f,0.f,0.f};
      #pragma unroll
      for (int kc = 0; kc < 2; ++kc) {
        short8v b = *(const short8v*)(wb + ((nt * 2 + kc) * 64 + ln) * 8);
        short8v a = *(const short8v*)(vls + (mt*16 + lm)*72 + kc*32 + quad*8);
        acc = __builtin_amdgcn_mfma_f32_16x16x32_bf16(a, b, acc, 0, 0, 0);
      }
      int ch = nt*16 + lm;
      float bias = Wp[OFF_BOUT + ch];
      float4 v;
      float s0 = acc[0] + bias; v.x = s0 / (1.f + __expf(-s0));
      float s1 = acc[1] + bias; v.y = s1 / (1.f + __expf(-s1));
      float s2 = acc[2] + bias; v.z = s2 / (1.f + __expf(-s2));
      float s3 = acc[3] + bias; v.w = s3 / (1.f + __expf(-s3));
      *(float4*)(out0 + ((size_t)img*64 + ch)*HWT + h*128 + w0 + mt*16 + quad*4) = v;
    }
  }
}

extern "C" void kernel_launch(void* const* d_in, const int* in_sizes, int n_in,
                              void* d_out, int out_size, void* d_ws, size_t ws_size,
                              hipStream_t stream) {
  const float* input_x = (const float*)d_in[0];
  const float* input_y = (const float*)d_in[1];

  float* Wp = (float*)d_ws;
  bf16* WZRB  = (bf16*)((char*)d_ws + B_WZRB);
  bf16* WQB   = (bf16*)((char*)d_ws + B_WQB);
  bf16* WOMB  = (bf16*)((char*)d_ws + B_WOMB);
  bf16* WOUTB = (bf16*)((char*)d_ws + B_WOUTB);
  bf16* HXP   = (bf16*)((char*)d_ws + B_HXP);
  bf16* QINP  = (bf16*)((char*)d_ws + B_QINP);
  bf16* ZBUF  = (bf16*)((char*)d_ws + B_ZBUF);
  bf16* XL    = (bf16*)((char*)d_ws + B_XL);
  float* out0 = (float*)d_out;
  float* outh = (float*)d_out + 4194304;

  k_stage1<<<dim3(NB_PREPB + 1024), dim3(256), 0, stream>>>(
      (const float*)d_in[2], (const float*)d_in[3], (const float*)d_in[4], (const float*)d_in[5],
      (const float*)d_in[6], (const float*)d_in[7], (const float*)d_in[8], (const float*)d_in[9],
      (const float*)d_in[10], (const float*)d_in[11], (const float*)d_in[12], (const float*)d_in[13],
      (const float*)d_in[14], (const float*)d_in[15], (const float*)d_in[16], (const float*)d_in[17],
      (const float*)d_in[18], (const float*)d_in[19], (const float*)d_in[20], (const float*)d_in[21],
      (const float*)d_in[22], (const float*)d_in[23], (const float*)d_in[24], (const float*)d_in[25],
      Wp, WZRB, WQB, WOMB, WOUTB, HXP, QINP, input_x, input_y);
  k_zr<<<dim3(2, 128, 4), dim3(256), 0, stream>>>(Wp, HXP, WZRB, QINP, ZBUF);
  k_stageB<<<dim3(2048), dim3(256), 0, stream>>>(input_y, Wp, QINP, WQB, ZBUF, outh, input_x, XL);
  k_mega<<<dim3(1024), dim3(512), 0, stream>>>(Wp, outh, XL, WOMB, WOUTB, out0);
}

// Round 6
// 224.223 us; speedup vs baseline: 1.5159x; 1.0742x over previous
//
#include <hip/hip_runtime.h>
#include <hip/hip_bf16.h>

typedef __hip_bfloat16 bf16;
typedef short short8v __attribute__((ext_vector_type(8)));
typedef short short4v __attribute__((ext_vector_type(4)));
typedef float float4v __attribute__((ext_vector_type(4)));

static __device__ __forceinline__ float b2f(bf16 v){ return __bfloat162float(v); }
static __device__ __forceinline__ bf16 f2b(float v){ return __float2bfloat16(v); }
static __device__ __forceinline__ float bu2f(unsigned short u){ return __uint_as_float(((unsigned)u) << 16); }
static __device__ __forceinline__ short f2bs(float v){ bf16 t = __float2bfloat16(v); return *(short*)&t; }
static __device__ __forceinline__ float ftanh(float x){ return 1.f - 2.f / (1.f + __expf(2.f * x)); }

#define WT 128
#define HWT 16384

// ---- packed f32 weights (float offsets inside ws) ----
#define OFF_WINPB 1024     // bf16 fragment-order [nt:4][kc:2][ln:64][j:8] packed 2/float (2048 floats)
#define OFF_BZ    20544    // 32
#define OFF_BR    39008    // 32
#define OFF_BQ    57472    // 32
#define OFF_DWP   57504    // [tap][64]        576
#define OFF_DWB   58080    // 64
#define OFF_LNG   58144    // 64
#define OFF_LNB   58208    // 64
#define OFF_OMB   65184    // 108 (+4 zero pad)
#define OFF_WINP  65296    // [c][64]          4096
#define OFF_BINP  69392    // 64
#define OFF_BOUT  73552    // 64
#define NW_TOTAL  73616
#define NBF_ZR    36864    // bf16 fragment-order [t:4][kc:18][ln:64][j:8]
#define NBF_Q     18432    // bf16 fragment-order [t:2][kc:18][ln:64][j:8]
#define NBF_OM    7168     // bf16 fragment-order [wv:7][kc:2][ln:64][j:8]
#define NBF_OUT   4096     // bf16 fragment-order [nt:4][kc:2][ln:64][j:8]
#define NPREP     (NW_TOTAL + NBF_ZR + NBF_Q + NBF_OM + NBF_OUT)
#define NHALO     2064     // 4 imgs * 516 halo pixels
#define NTOT      (NPREP + NHALO)
#define NB_PREPB  556      // ceil(NTOT/256)

// ---- ws byte offsets (end = 21,928,448 B) ----
#define B_WZRB  294912
#define B_WQB   368640
#define B_WOMB  405504
#define B_WOUTB 419840
#define B_HXP   428544     // bf16 [4][130][130][64]  (dead after k_zr)
#define B_QINP  9081344    // bf16 [4][130][130][64]  (dead after stageB)
#define B_ZBUF  17734144   // bf16 [4][128][32][128]
#define B_XL    428544     // bf16 [4][HWT][64] overlays HXP (written in stageB, right before mega)

// ---------------- K1: stage1 = weight-prep blocks + encoder blocks (merged launch) ----------------
__global__ void __launch_bounds__(256) k_stage1(
    const float* __restrict__ enc_w, const float* __restrict__ enc_b,
    const float* __restrict__ bn_g, const float* __restrict__ bn_b,
    const float* __restrict__ bn_m, const float* __restrict__ bn_v,
    const float* __restrict__ gwz, const float* __restrict__ gbz,
    const float* __restrict__ gwr, const float* __restrict__ gbr,
    const float* __restrict__ gwq, const float* __restrict__ gbq,
    const float* __restrict__ dww, const float* __restrict__ dwb,
    const float* __restrict__ lng, const float* __restrict__ lnb,
    const float* __restrict__ offw, const float* __restrict__ offb,
    const float* __restrict__ maskw, const float* __restrict__ maskb,
    const float* __restrict__ inpw, const float* __restrict__ inpb,
    const float* __restrict__ outw, const float* __restrict__ outb,
    float* __restrict__ Wp, bf16* __restrict__ wzrb, bf16* __restrict__ wqb,
    bf16* __restrict__ womb, bf16* __restrict__ woutb,
    bf16* __restrict__ hxp, bf16* __restrict__ qinp,
    const float* __restrict__ X, const float* __restrict__ Y) {
  __shared__ float xls[4096];
  __shared__ float ewls[2048];
  __shared__ float escl[64];
  int tid = threadIdx.x;
  int b = blockIdx.x;

  if (b < NB_PREPB) {
    int i = b * 256 + tid;
    if (i >= NTOT) return;
    if (i >= NPREP) {
      int t = i - NPREP;
      int img = t / 516, r = t % 516;
      int ph, pw;
      if (r < 130) { ph = 0; pw = r; }
      else if (r < 260) { ph = 129; pw = r - 130; }
      else if (r < 388) { ph = r - 260 + 1; pw = 0; }
      else { ph = r - 388 + 1; pw = 129; }
      size_t pb = (((size_t)img * 130 + ph) * 130 + pw) * 64;
      uint4 zz = make_uint4(0, 0, 0, 0);
      #pragma unroll
      for (int k = 0; k < 8; ++k) {
        ((uint4*)(hxp + pb))[k] = zz;
        ((uint4*)(qinp + pb))[k] = zz;
      }
      return;
    }
    if (i >= NW_TOTAL) {
      int d = i - NW_TOTAL;
      if (d < NBF_ZR) {
        int t = d / 9216, rem = d % 9216;
        int kc = rem / 512, rem2 = rem % 512;
        int ln = rem2 >> 3, j = rem2 & 7;
        int n = t * 16 + (ln & 15);
        int cin = (kc & 1) * 32 + ((ln >> 4) << 3) + j;
        int tap = kc >> 1;
        float v = (n < 32) ? gwz[(n*64 + cin)*9 + tap] : gwr[((n-32)*64 + cin)*9 + tap];
        wzrb[d] = f2b(v);
      } else if (d < NBF_ZR + NBF_Q) {
        int d2 = d - NBF_ZR;
        int t = d2 / 9216, rem = d2 % 9216;
        int kc = rem / 512, rem2 = rem % 512;
        int ln = rem2 >> 3, j = rem2 & 7;
        int n = t * 16 + (ln & 15);
        int cin = (kc & 1) * 32 + ((ln >> 4) << 3) + j;
        int tap = kc >> 1;
        wqb[d2] = f2b(gwq[(n*64 + cin)*9 + tap]);
      } else if (d < NBF_ZR + NBF_Q + NBF_OM) {
        int d3 = d - NBF_ZR - NBF_Q;
        int wv = d3 / 1024, rem = d3 % 1024;
        int kc = rem / 512, rem2 = rem % 512;
        int ln = rem2 >> 3, j = rem2 & 7;
        int jcol = wv * 16 + (ln & 15);
        int c = kc * 32 + ((ln >> 4) << 3) + j;
        float v = (jcol < 72) ? offw[jcol*64 + c] : ((jcol < 108) ? maskw[(jcol-72)*64 + c] : 0.f);
        womb[d3] = f2b(v);
      } else {
        int d4 = d - NBF_ZR - NBF_Q - NBF_OM;
        int nt = d4 / 1024, rem = d4 % 1024;
        int kc = rem / 512, rem2 = rem % 512;
        int ln = rem2 >> 3, j = rem2 & 7;
        int o = nt * 16 + (ln & 15);
        int c = kc * 32 + ((ln >> 4) << 3) + j;
        woutb[d4] = f2b(outw[o*64 + c]);
      }
      return;
    }
    float v;
    if (i < 20544) {
      if (i >= OFF_WINPB && i < OFF_WINPB + 2048) {
        // bf16 fragment-order inp_w: d = ((nt*2+kc)*64+ln)*8+j, packed 2 bf16 per float
        int d0 = (i - OFF_WINPB) * 2;
        int nt = d0 >> 10, kc = (d0 >> 9) & 1, lnn = (d0 >> 3) & 63, j0 = d0 & 7;
        int o = nt * 16 + (lnn & 15);
        int c = kc * 32 + ((lnn >> 4) << 3) + j0;
        unsigned lo = (unsigned)(unsigned short)f2bs(inpw[o * 64 + c]);
        unsigned hi = (unsigned)(unsigned short)f2bs(inpw[o * 64 + c + 1]);
        v = __uint_as_float(lo | (hi << 16));
      } else v = 0.f;
    }
    else if (i < 20576) { v = gbz[i - OFF_BZ]; }
    else if (i < 39008) { v = 0.f; }
    else if (i < 39040) { v = gbr[i - OFF_BR]; }
    else if (i < 57472) { v = 0.f; }
    else if (i < 57504) { v = gbq[i - OFF_BQ]; }
    else if (i < 58080) { int d = i - OFF_DWP; int tap = d >> 6, o = d & 63; v = dww[o*9 + tap]; }
    else if (i < 58144) { v = dwb[i - OFF_DWB]; }
    else if (i < 58208) { v = lng[i - OFF_LNG]; }
    else if (i < 58272) { v = lnb[i - OFF_LNB]; }
    else if (i < 65184) { v = 0.f; }
    else if (i < 65292) { int j = i - OFF_OMB; v = (j < 72) ? offb[j] : maskb[j-72]; }
    else if (i < 65296) { v = 0.f; }
    else if (i < 69392) { int d = i - OFF_WINP; int c = d >> 6, o = d & 63; v = inpw[o*64 + c]; }
    else if (i < 69456) { v = inpb[i - OFF_BINP]; }
    else if (i < 73552) { v = 0.f; }
    else { v = outb[i - OFF_BOUT]; }
    Wp[i] = v;
    return;
  }

  // ===== encoder blocks =====
  int pb2 = b - NB_PREPB;
  int img = pb2 >> 8, h = (pb2 >> 1) & 127, w0 = (pb2 & 1) * 64;
  int px = tid & 63, sect = tid >> 6;
  #pragma unroll
  for (int k = 0; k < 8; ++k) {
    int i2 = k * 256 + tid;
    int c = i2 >> 5, o = i2 & 31;
    ewls[i2] = enc_w[o*64 + c];
  }
  if (tid < 32) {
    float sc = bn_g[tid] * rsqrtf(bn_v[tid] + 1e-5f);
    escl[tid] = sc;
    escl[32 + tid] = (enc_b[tid] - bn_m[tid]) * sc + bn_b[tid];
  }
  int hw = h * WT + w0 + px;
  const float* xp = X + (size_t)img * (64 * HWT) + hw;
  #pragma unroll
  for (int i2 = 0; i2 < 16; ++i2) {
    int c = sect * 16 + i2;
    xls[c * 64 + px] = xp[c * HWT];
  }
  const float* yp = Y + (size_t)img * (32 * HWT) + hw;
  bf16 yv[8];
  #pragma unroll
  for (int i2 = 0; i2 < 8; ++i2) yv[i2] = f2b(yp[(sect * 8 + i2) * HWT]);
  size_t pbb = (((size_t)img * 130 + h + 1) * 130 + (w0 + px + 1)) * 64;
  *(uint4*)(hxp + pbb + sect * 8) = *(const uint4*)yv;
  __syncthreads();
  float aen[8];
  #pragma unroll
  for (int o = 0; o < 8; ++o) aen[o] = 0.f;
  for (int k = 0; k < 64; ++k) {
    float a = xls[k * 64 + px];
    const float* we = ewls + k * 32 + sect * 8;
    #pragma unroll
    for (int o = 0; o < 8; ++o) aen[o] += a * we[o];
  }
  bf16 xe[8];
  #pragma unroll
  for (int o = 0; o < 8; ++o) {
    int oo = sect * 8 + o;
    float e = aen[o] * escl[oo] + escl[32 + oo];
    xe[o] = f2b(e / (1.f + __expf(-e)));
  }
  *(uint4*)(hxp + pbb + 32 + sect * 8) = *(const uint4*)xe;
  *(uint4*)(qinp + pbb + 32 + sect * 8) = *(const uint4*)xe;
}

// ---------------- K2: z+r implicit-GEMM, M=16/wave, 64-px blocks (2x occupancy vs R11) ----------------
__global__ void __launch_bounds__(256) k_zr(
    const float* __restrict__ Wp,
    const bf16* __restrict__ hxp, const bf16* __restrict__ wzrb,
    bf16* __restrict__ qinp, bf16* __restrict__ zbuf) {
  __shared__ short zt[32 * 72];
  __shared__ short ryt[64 * 40];
  int tid = threadIdx.x;
  int wv = tid >> 6, ln = tid & 63;
  int quad = ln >> 4, lm = ln & 15;
  int img = blockIdx.z, h = blockIdx.y;
  int x0 = blockIdx.x * 64;
  int p0 = x0 + wv * 16;
  const short* hs = (const short*)hxp;
  const short* ws = (const short*)wzrb;
  size_t rowb = ((size_t)img * 130 + h + 1) * 130;
  const short* ab = hs + (rowb + p0 + lm + 1) * 64 + quad * 8;
  short8v a[18];
  #pragma unroll
  for (int kc = 0; kc < 18; ++kc) {
    const int tap = kc >> 1, cin0 = (kc & 1) * 32;
    const int dd = (tap / 3 - 1) * 130 + (tap % 3 - 1);
    a[kc] = *(const short8v*)(ab + dd * 64 + cin0);
  }
  float4v acc[4];
  #pragma unroll
  for (int t = 0; t < 4; ++t) acc[t] = (float4v){0.f, 0.f, 0.f, 0.f};
  #pragma unroll
  for (int kc = 0; kc < 18; ++kc) {
    #pragma unroll
    for (int t = 0; t < 4; ++t) {
      short8v b = *(const short8v*)(ws + ((t * 18 + kc) * 64 + ln) * 8);
      acc[t] = __builtin_amdgcn_mfma_f32_16x16x32_bf16(a[kc], b, acc[t], 0, 0, 0);
    }
  }
  #pragma unroll
  for (int t = 0; t < 2; ++t) {
    int n = t * 16 + lm;
    float bz = Wp[OFF_BZ + n];
    short zp[4];
    #pragma unroll
    for (int ri = 0; ri < 4; ++ri)
      zp[ri] = f2bs(1.f / (1.f + __expf(-(acc[t][ri] + bz))));
    *(short4v*)(zt + n * 72 + wv * 16 + quad * 4) = *(const short4v*)zp;
  }
  #pragma unroll
  for (int t = 2; t < 4; ++t) {
    int c = (t - 2) * 16 + lm;
    float br = Wp[OFF_BR + c];
    #pragma unroll
    for (int ri = 0; ri < 4; ++ri) {
      int pxl = wv * 16 + quad * 4 + ri;
      float rv = 1.f / (1.f + __expf(-(acc[t][ri] + br)));
      float yy = b2f(hxp[(rowb + x0 + pxl + 1) * 64 + c]);
      ryt[pxl * 40 + c] = f2bs(rv * yy);
    }
  }
  __syncthreads();
  {
    int n2 = tid >> 3, pq = tid & 7;
    short8v z0 = *(const short8v*)(zt + n2 * 72 + pq * 8);
    short* zo = (short*)zbuf + (((size_t)img * 128 + h) * 32 + n2) * 128 + x0 + pq * 8;
    *(short8v*)zo = z0;
  }
  {
    int px = tid >> 2, cq = tid & 3;
    short8v r0 = *(const short8v*)(ryt + px * 40 + cq * 8);
    short* qo = (short*)qinp + (rowb + x0 + px + 1) * 64 + cq * 8;
    *(short8v*)qo = r0;
  }
}

// ---------------- K3: stageB v2 — 2048 uniform 64-px blocks, XCD h-band swizzle ----------------
__global__ void __launch_bounds__(256) k_stageB(
    const float* __restrict__ Y, const float* __restrict__ Wp,
    const bf16* __restrict__ qinp, const bf16* __restrict__ wqb,
    const bf16* __restrict__ zbuf, float* __restrict__ outh,
    const float* __restrict__ X, bf16* __restrict__ xl) {
  __shared__ short xs[64 * 72];
  int tid = threadIdx.x;
  int bid = blockIdx.x;
  int xcd = bid & 7, u = bid >> 3;           // u 0..255
  int part = u & 1, slot = u >> 1;           // slot 0..127
  int img = slot >> 5, rem = slot & 31;
  int hh = xcd * 16 + (rem & 15);
  int w0 = (rem >> 4) * 64;
  int wv = tid >> 6, ln = tid & 63, quad = ln >> 4, lm = ln & 15;

  if (part == 0) {
    // ===== q-GEMM: 64 px, N=32; wave wv owns 16-px M-tile =====
    int p0 = w0 + wv * 16;
    const short* qs = (const short*)qinp;
    const short* ws = (const short*)wqb;
    size_t rowb = ((size_t)img * 130 + hh + 1) * 130;
    const short* ab = qs + (rowb + p0 + lm + 1) * 64 + quad * 8;
    float4v acc0 = (float4v){0.f,0.f,0.f,0.f};
    float4v acc1 = (float4v){0.f,0.f,0.f,0.f};
    #pragma unroll
    for (int kc = 0; kc < 18; ++kc) {
      const int tap = kc >> 1, cin0 = (kc & 1) * 32;
      const int dd = (tap / 3 - 1) * 130 + (tap % 3 - 1);
      short8v a  = *(const short8v*)(ab + dd * 64 + cin0);
      short8v b0 = *(const short8v*)(ws + ((0 * 18 + kc) * 64 + ln) * 8);
      short8v b1 = *(const short8v*)(ws + ((1 * 18 + kc) * 64 + ln) * 8);
      acc0 = __builtin_amdgcn_mfma_f32_16x16x32_bf16(a, b0, acc0, 0, 0, 0);
      acc1 = __builtin_amdgcn_mfma_f32_16x16x32_bf16(a, b1, acc1, 0, 0, 0);
    }
    int px4 = p0 + quad * 4;
    #pragma unroll
    for (int t = 0; t < 2; ++t) {
      float4v acc = t ? acc1 : acc0;
      int n = t * 16 + lm;
      float bq = Wp[OFF_BQ + n];
      size_t gb = ((size_t)img * 32 + n) * HWT + hh * 128 + px4;
      uint2 zz = *(const uint2*)((const short*)zbuf + (((size_t)img * 128 + hh) * 32 + n) * 128 + px4);
      float4 yv = *(const float4*)(Y + gb);
      float z0 = bu2f((unsigned short)(zz.x & 0xFFFFu)), z1 = bu2f((unsigned short)(zz.x >> 16));
      float z2 = bu2f((unsigned short)(zz.y & 0xFFFFu)), z3 = bu2f((unsigned short)(zz.y >> 16));
      float4 o;
      o.x = (1.f - z0) * yv.x + z0 * ftanh(acc[0] + bq);
      o.y = (1.f - z1) * yv.y + z1 * ftanh(acc[1] + bq);
      o.z = (1.f - z2) * yv.z + z2 * ftanh(acc[2] + bq);
      o.w = (1.f - z3) * yv.w + z3 * ftanh(acc[3] + bq);
      *(float4*)(outh + gb) = o;
    }
    return;
  }

  // ===== input linear via MFMA =====
  {
    const float* xb = X + (size_t)img * (64 * HWT) + hh * 128 + w0 + wv * 16 + lm;
    short8v a[2];
    #pragma unroll
    for (int kc = 0; kc < 2; ++kc) {
      short tmp[8];
      #pragma unroll
      for (int j = 0; j < 8; ++j)
        tmp[j] = f2bs(xb[(size_t)(kc * 32 + quad * 8 + j) * HWT]);
      a[kc] = *(const short8v*)tmp;
    }
    const short* wib = (const short*)Wp + 2 * OFF_WINPB;
    float4v acc[4];
    #pragma unroll
    for (int nt = 0; nt < 4; ++nt) acc[nt] = (float4v){0.f,0.f,0.f,0.f};
    #pragma unroll
    for (int kc = 0; kc < 2; ++kc) {
      #pragma unroll
      for (int nt = 0; nt < 4; ++nt) {
        short8v b = *(const short8v*)(wib + ((nt * 2 + kc) * 64 + ln) * 8);
        acc[nt] = __builtin_amdgcn_mfma_f32_16x16x32_bf16(a[kc], b, acc[nt], 0, 0, 0);
      }
    }
    #pragma unroll
    for (int nt = 0; nt < 4; ++nt) {
      int o = nt * 16 + lm;
      float bias = Wp[OFF_BINP + o];
      #pragma unroll
      for (int ri = 0; ri < 4; ++ri)
        xs[(wv * 16 + quad * 4 + ri) * 72 + o] = f2bs(acc[nt][ri] + bias);
    }
    __syncthreads();
    int row = tid >> 2, c0 = (tid & 3) * 16;
    short8v v0 = *(const short8v*)(xs + row * 72 + c0);
    short8v v1 = *(const short8v*)(xs + row * 72 + c0 + 8);
    short* op = (short*)xl + ((size_t)img * HWT + hh * 128 + w0 + row) * 64 + c0;
    *(short8v*)op = v0;
    *(short8v*)(op + 8) = v1;
  }
}

// ---------------- K5 mega (512 thr, R1-verbatim: erff GELU, branchy scalar gather, 64 VGPR) ----------------
#define LDS_PSA  0         // f32 [8][64]      2048
#define LDS_PSB  2048      // f32 [8][64]      2048
#define LDS_STAT 4096      // f32 [64][2]      512
#define LDS_Y    4608      // bf16 [64][72]    9216  (vls overlays after P2)
#define LDS_OM   13824     // bf16 [64][114]   14592
#define LDS_TOT  28416

__global__ void __launch_bounds__(512) k_mega(
    const float* __restrict__ Wp, const float* __restrict__ hb,
    const bf16* __restrict__ xl, const bf16* __restrict__ womb,
    const bf16* __restrict__ woutb, float* __restrict__ out0) {
  __shared__ char smem[LDS_TOT];
  float* psa  = (float*)(smem + LDS_PSA);
  float* psb  = (float*)(smem + LDS_PSB);
  float* stat = (float*)(smem + LDS_STAT);
  short* yls  = (short*)(smem + LDS_Y);
  short* omls = (short*)(smem + LDS_OM);
  short* vls  = (short*)(smem + LDS_Y);

  int tid = threadIdx.x;
  int bid = blockIdx.x;
  int xcd = bid & 7, slot = bid >> 3;            // slot 0..127
  int img = slot >> 5;                           // 4 imgs
  int rem = slot & 31;                           // 2 w-tiles x 16 h
  int h = xcd * 16 + (rem & 15);
  int w0 = (rem >> 4) * 64;

  int wloc = tid & 63, part = tid >> 6;
  int w = w0 + wloc;
  float yv[8];
  {
    const float* hn = hb + (size_t)img * (32 * HWT);
    #pragma unroll
    for (int i = 0; i < 8; ++i) yv[i] = Wp[OFF_DWB + part*8 + i];
    #pragma unroll
    for (int tap = 0; tap < 9; ++tap) {
      int dy = tap / 3 - 1, dx = tap % 3 - 1;
      int hh = h + dy, ww = w + dx;
      bool ok = ((unsigned)hh < 128u) && ((unsigned)ww < 128u);
      int off = hh * WT + ww;
      #pragma unroll
      for (int j = 0; j < 4; ++j) {
        int cin = part * 4 + j;
        float a = ok ? hn[cin * HWT + off] : 0.f;
        yv[2*j]   += a * Wp[OFF_DWP + tap*64 + part*8 + 2*j];
        yv[2*j+1] += a * Wp[OFF_DWP + tap*64 + part*8 + 2*j+1];
      }
    }
  }
  float lsum = 0.f, lsq = 0.f;
  #pragma unroll
  for (int i = 0; i < 8; ++i) { lsum += yv[i]; lsq += yv[i]*yv[i]; }
  psa[part * 64 + wloc] = lsum;
  psb[part * 64 + wloc] = lsq;
  __syncthreads();
  if (tid < 64) {
    float s = 0.f, q = 0.f;
    #pragma unroll
    for (int p = 0; p < 8; ++p) { s += psa[p*64 + tid]; q += psb[p*64 + tid]; }
    float mu = s * (1.f/64.f);
    float var = q * (1.f/64.f) - mu * mu;
    stat[tid*2] = mu;
    stat[tid*2+1] = rsqrtf(var + 1e-6f);
  }
  __syncthreads();
  {
    float mu = stat[wloc*2], inv = stat[wloc*2+1];
    bf16 tmp[8];
    #pragma unroll
    for (int i = 0; i < 8; ++i) {
      int c = part*8 + i;
      float v = (yv[i] - mu) * inv * Wp[OFF_LNG + c] + Wp[OFF_LNB + c];
      tmp[i] = f2b(0.5f * v * (1.f + erff(v * 0.70710678118654752f)));
    }
    *(short8v*)(yls + wloc*72 + part*8) = *(const short8v*)tmp;
  }
  __syncthreads();

  int wv = tid >> 6, ln = tid & 63, quad = ln >> 4, lm = ln & 15;
  if (wv < 7) {
    const short* wb = (const short*)womb;
    float4v acc[4];
    #pragma unroll
    for (int mt = 0; mt < 4; ++mt) acc[mt] = (float4v){0.f,0.f,0.f,0.f};
    #pragma unroll
    for (int kc = 0; kc < 2; ++kc) {
      short8v b = *(const short8v*)(wb + ((wv * 2 + kc) * 64 + ln) * 8);
      #pragma unroll
      for (int mt = 0; mt < 4; ++mt) {
        short8v a = *(const short8v*)(yls + (mt*16 + lm)*72 + kc*32 + quad*8);
        acc[mt] = __builtin_amdgcn_mfma_f32_16x16x32_bf16(a, b, acc[mt], 0, 0, 0);
      }
    }
    float bias = Wp[OFF_OMB + wv*16 + lm];
    #pragma unroll
    for (int mt = 0; mt < 4; ++mt) {
      #pragma unroll
      for (int ri = 0; ri < 4; ++ri)
        omls[(mt*16 + quad*4 + ri)*114 + wv*16 + lm] = f2bs(acc[mt][ri] + bias);
    }
  }
  __syncthreads();

  {
    int px = tid >> 3, g = (tid >> 1) & 3, half = tid & 1;
    const short* oml = omls + px*114;
    float m[9];
    #pragma unroll
    for (int p = 0; p < 9; ++p) m[p] = bu2f((unsigned short)oml[72 + g*9 + p]);
    float mx = m[0];
    #pragma unroll
    for (int p = 1; p < 9; ++p) mx = fmaxf(mx, m[p]);
    float sum = 0.f;
    #pragma unroll
    for (int p = 0; p < 9; ++p) { m[p] = __expf(m[p] - mx); sum += m[p]; }
    float rs = 1.f / sum;
    int wg = w0 + px;
    const bf16* xn = xl + (size_t)img * (HWT * 64);
    float acc[8];
    #pragma unroll
    for (int i = 0; i < 8; ++i) acc[i] = 0.f;
    for (int p = 0; p < 9; ++p) {
      float bx = (float)(wg + p / 3 - 1);
      float by = (float)(h + p % 3 - 1);
      float ox = bu2f((unsigned short)oml[g*18 + p*2]);
      float oy = bu2f((unsigned short)oml[g*18 + p*2 + 1]);
      float mk = m[p] * rs;
      float pxx = bx + ox, pyy = by + oy;
      float fx = floorf(pxx), fy = floorf(pyy);
      int jx0 = (int)fx, jy0 = (int)fy;
      float wx1 = pxx - fx, wy1 = pyy - fy;
      float wx0 = 1.f - wx1, wy0 = 1.f - wy1;
      int cjx[4] = { jx0, jx0 + 1, jx0, jx0 + 1 };
      int cjy[4] = { jy0, jy0, jy0 + 1, jy0 + 1 };
      float cw[4] = { wx0*wy0, wx1*wy0, wx0*wy1, wx1*wy1 };
      #pragma unroll
      for (int k = 0; k < 4; ++k) {
        if ((unsigned)cjx[k] < 128u && (unsigned)cjy[k] < 128u) {
          float cf = mk * cw[k];
          const bf16* s = xn + (size_t)(cjy[k] * WT + cjx[k]) * 64 + g * 16 + half * 8;
          uint4 u0 = *(const uint4*)(s);
          const unsigned uu[4] = {u0.x,u0.y,u0.z,u0.w};
          #pragma unroll
          for (int q = 0; q < 4; ++q) {
            acc[2*q]     += cf * bu2f((unsigned short)(uu[q] & 0xFFFFu));
            acc[2*q + 1] += cf * bu2f((unsigned short)(uu[q] >> 16));
          }
        }
      }
    }
    bf16 tmp[8];
    #pragma unroll
    for (int i = 0; i < 8; ++i) tmp[i] = f2b(acc[i]);
    *(short8v*)(vls + px*72 + g*16 + half*8) = *(const short8v*)tmp;
  }
  __syncthreads();

  {
    const short* wb = (const short*)woutb;
    #pragma unroll
    for (int s = 0; s < 2; ++s) {
      int tile = wv * 2 + s;
      int nt = tile >> 2, mt = tile & 3;
      float4v acc = (float4v){0.f,0.f,0.f,0.f};
      #pragma unroll
      for (int kc = 0; kc < 2; ++kc) {
        short8v b = *(const short8v*)(wb + ((nt * 2 + kc) * 64 + ln) * 8);
        short8v a = *(const short8v*)(vls + (mt*16 + lm)*72 + kc*32 + quad*8);
        acc = __builtin_amdgcn_mfma_f32_16x16x32_bf16(a, b, acc, 0, 0, 0);
      }
      int ch = nt*16 + lm;
      float bias = Wp[OFF_BOUT + ch];
      float4 v;
      float s0 = acc[0] + bias; v.x = s0 / (1.f + __expf(-s0));
      float s1 = acc[1] + bias; v.y = s1 / (1.f + __expf(-s1));
      float s2 = acc[2] + bias; v.z = s2 / (1.f + __expf(-s2));
      float s3 = acc[3] + bias; v.w = s3 / (1.f + __expf(-s3));
      *(float4*)(out0 + ((size_t)img*64 + ch)*HWT + h*128 + w0 + mt*16 + quad*4) = v;
    }
  }
}

extern "C" void kernel_launch(void* const* d_in, const int* in_sizes, int n_in,
                              void* d_out, int out_size, void* d_ws, size_t ws_size,
                              hipStream_t stream) {
  const float* input_x = (const float*)d_in[0];
  const float* input_y = (const float*)d_in[1];

  float* Wp = (float*)d_ws;
  bf16* WZRB  = (bf16*)((char*)d_ws + B_WZRB);
  bf16* WQB   = (bf16*)((char*)d_ws + B_WQB);
  bf16* WOMB  = (bf16*)((char*)d_ws + B_WOMB);
  bf16* WOUTB = (bf16*)((char*)d_ws + B_WOUTB);
  bf16* HXP   = (bf16*)((char*)d_ws + B_HXP);
  bf16* QINP  = (bf16*)((char*)d_ws + B_QINP);
  bf16* ZBUF  = (bf16*)((char*)d_ws + B_ZBUF);
  bf16* XL    = (bf16*)((char*)d_ws + B_XL);
  float* out0 = (float*)d_out;
  float* outh = (float*)d_out + 4194304;

  k_stage1<<<dim3(NB_PREPB + 1024), dim3(256), 0, stream>>>(
      (const float*)d_in[2], (const float*)d_in[3], (const float*)d_in[4], (const float*)d_in[5],
      (const float*)d_in[6], (const float*)d_in[7], (const float*)d_in[8], (const float*)d_in[9],
      (const float*)d_in[10], (const float*)d_in[11], (const float*)d_in[12], (const float*)d_in[13],
      (const float*)d_in[14], (const float*)d_in[15], (const float*)d_in[16], (const float*)d_in[17],
      (const float*)d_in[18], (const float*)d_in[19], (const float*)d_in[20], (const float*)d_in[21],
      (const float*)d_in[22], (const float*)d_in[23], (const float*)d_in[24], (const float*)d_in[25],
      Wp, WZRB, WQB, WOMB, WOUTB, HXP, QINP, input_x, input_y);
  k_zr<<<dim3(2, 128, 4), dim3(256), 0, stream>>>(Wp, HXP, WZRB, QINP, ZBUF);
  k_stageB<<<dim3(2048), dim3(256), 0, stream>>>(input_y, Wp, QINP, WQB, ZBUF, outh, input_x, XL);
  k_mega<<<dim3(1024), dim3(512), 0, stream>>>(Wp, outh, XL, WOMB, WOUTB, out0);
}

// Round 8
// 222.546 us; speedup vs baseline: 1.5273x; 1.0075x over previous
//
#include <hip/hip_runtime.h>
#include <hip/hip_bf16.h>

typedef __hip_bfloat16 bf16;
typedef short short8v __attribute__((ext_vector_type(8)));
typedef short short4v __attribute__((ext_vector_type(4)));
typedef float float4v __attribute__((ext_vector_type(4)));

static __device__ __forceinline__ float b2f(bf16 v){ return __bfloat162float(v); }
static __device__ __forceinline__ bf16 f2b(float v){ return __float2bfloat16(v); }
static __device__ __forceinline__ float bu2f(unsigned short u){ return __uint_as_float(((unsigned)u) << 16); }
static __device__ __forceinline__ short f2bs(float v){ bf16 t = __float2bfloat16(v); return *(short*)&t; }
static __device__ __forceinline__ float ftanh(float x){ return 1.f - 2.f / (1.f + __expf(2.f * x)); }

#define WT 128
#define HWT 16384

// ---- packed f32 weights (float offsets inside ws) ----
#define OFF_WINPB 1024     // bf16 fragment-order [nt:4][kc:2][ln:64][j:8] packed 2/float (2048 floats)
#define OFF_BZ    20544    // 32
#define OFF_BR    39008    // 32
#define OFF_BQ    57472    // 32
#define OFF_DWP   57504    // [tap][64]        576
#define OFF_DWB   58080    // 64
#define OFF_LNG   58144    // 64
#define OFF_LNB   58208    // 64
#define OFF_OMB   65184    // 108 (+4 zero pad)
#define OFF_WINP  65296    // [c][64]          4096
#define OFF_BINP  69392    // 64
#define OFF_BOUT  73552    // 64
#define NW_TOTAL  73616
#define NBF_ZR    36864    // bf16 fragment-order [t:4][kc:18][ln:64][j:8]
#define NBF_Q     18432    // bf16 fragment-order [t:2][kc:18][ln:64][j:8]
#define NBF_OM    7168     // bf16 fragment-order [wv:7][kc:2][ln:64][j:8]
#define NBF_OUT   4096     // bf16 fragment-order [nt:4][kc:2][ln:64][j:8]
#define NPREP     (NW_TOTAL + NBF_ZR + NBF_Q + NBF_OM + NBF_OUT)
#define NHALO     2064     // 4 imgs * 516 halo pixels
#define NTOT      (NPREP + NHALO)
#define NB_PREPB  556      // ceil(NTOT/256)

// ---- ws byte offsets (end = 21,928,448 B) ----
#define B_WZRB  294912
#define B_WQB   368640
#define B_WOMB  405504
#define B_WOUTB 419840
#define B_HXP   428544     // bf16 [4][130][130][64]  (dead after k_zr)
#define B_QINP  9081344    // bf16 [4][130][130][64]  (dead after stageB)
#define B_ZBUF  17734144   // bf16 [4][128][32][128]
#define B_XL    428544     // bf16 [4][HWT][64] overlays HXP (written in stageB, right before mega)

// ---------------- K1: stage1 = weight-prep blocks + MFMA encoder blocks ----------------
// NOTE: encoder blocks must read ONLY kernel inputs (enc_w etc.), never Wp —
// prep blocks run in the SAME launch and dispatch order is undefined (R7 race).
__global__ void __launch_bounds__(256) k_stage1(
    const float* __restrict__ enc_w, const float* __restrict__ enc_b,
    const float* __restrict__ bn_g, const float* __restrict__ bn_b,
    const float* __restrict__ bn_m, const float* __restrict__ bn_v,
    const float* __restrict__ gwz, const float* __restrict__ gbz,
    const float* __restrict__ gwr, const float* __restrict__ gbr,
    const float* __restrict__ gwq, const float* __restrict__ gbq,
    const float* __restrict__ dww, const float* __restrict__ dwb,
    const float* __restrict__ lng, const float* __restrict__ lnb,
    const float* __restrict__ offw, const float* __restrict__ offb,
    const float* __restrict__ maskw, const float* __restrict__ maskb,
    const float* __restrict__ inpw, const float* __restrict__ inpb,
    const float* __restrict__ outw, const float* __restrict__ outb,
    float* __restrict__ Wp, bf16* __restrict__ wzrb, bf16* __restrict__ wqb,
    bf16* __restrict__ womb, bf16* __restrict__ woutb,
    bf16* __restrict__ hxp, bf16* __restrict__ qinp,
    const float* __restrict__ X, const float* __restrict__ Y) {
  __shared__ float escl[64];
  __shared__ short ews[2048];   // enc_w in B-fragment order [frag:4][ln:64][j:8]
  __shared__ short es[64 * 40];
  int tid = threadIdx.x;
  int b = blockIdx.x;

  if (b < NB_PREPB) {
    int i = b * 256 + tid;
    if (i >= NTOT) return;
    if (i >= NPREP) {
      int t = i - NPREP;
      int img = t / 516, r = t % 516;
      int ph, pw;
      if (r < 130) { ph = 0; pw = r; }
      else if (r < 260) { ph = 129; pw = r - 130; }
      else if (r < 388) { ph = r - 260 + 1; pw = 0; }
      else { ph = r - 388 + 1; pw = 129; }
      size_t pb = (((size_t)img * 130 + ph) * 130 + pw) * 64;
      uint4 zz = make_uint4(0, 0, 0, 0);
      #pragma unroll
      for (int k = 0; k < 8; ++k) {
        ((uint4*)(hxp + pb))[k] = zz;
        ((uint4*)(qinp + pb))[k] = zz;
      }
      return;
    }
    if (i >= NW_TOTAL) {
      int d = i - NW_TOTAL;
      if (d < NBF_ZR) {
        int t = d / 9216, rem = d % 9216;
        int kc = rem / 512, rem2 = rem % 512;
        int ln = rem2 >> 3, j = rem2 & 7;
        int n = t * 16 + (ln & 15);
        int cin = (kc & 1) * 32 + ((ln >> 4) << 3) + j;
        int tap = kc >> 1;
        float v = (n < 32) ? gwz[(n*64 + cin)*9 + tap] : gwr[((n-32)*64 + cin)*9 + tap];
        wzrb[d] = f2b(v);
      } else if (d < NBF_ZR + NBF_Q) {
        int d2 = d - NBF_ZR;
        int t = d2 / 9216, rem = d2 % 9216;
        int kc = rem / 512, rem2 = rem % 512;
        int ln = rem2 >> 3, j = rem2 & 7;
        int n = t * 16 + (ln & 15);
        int cin = (kc & 1) * 32 + ((ln >> 4) << 3) + j;
        int tap = kc >> 1;
        wqb[d2] = f2b(gwq[(n*64 + cin)*9 + tap]);
      } else if (d < NBF_ZR + NBF_Q + NBF_OM) {
        int d3 = d - NBF_ZR - NBF_Q;
        int wv = d3 / 1024, rem = d3 % 1024;
        int kc = rem / 512, rem2 = rem % 512;
        int ln = rem2 >> 3, j = rem2 & 7;
        int jcol = wv * 16 + (ln & 15);
        int c = kc * 32 + ((ln >> 4) << 3) + j;
        float v = (jcol < 72) ? offw[jcol*64 + c] : ((jcol < 108) ? maskw[(jcol-72)*64 + c] : 0.f);
        womb[d3] = f2b(v);
      } else {
        int d4 = d - NBF_ZR - NBF_Q - NBF_OM;
        int nt = d4 / 1024, rem = d4 % 1024;
        int kc = rem / 512, rem2 = rem % 512;
        int ln = rem2 >> 3, j = rem2 & 7;
        int o = nt * 16 + (ln & 15);
        int c = kc * 32 + ((ln >> 4) << 3) + j;
        woutb[d4] = f2b(outw[o*64 + c]);
      }
      return;
    }
    float v;
    if (i < 20544) {
      if (i >= OFF_WINPB && i < OFF_WINPB + 2048) {
        // bf16 fragment-order inp_w: d = ((nt*2+kc)*64+ln)*8+j, packed 2 bf16 per float
        int d0 = (i - OFF_WINPB) * 2;
        int nt = d0 >> 10, kc = (d0 >> 9) & 1, lnn = (d0 >> 3) & 63, j0 = d0 & 7;
        int o = nt * 16 + (lnn & 15);
        int c = kc * 32 + ((lnn >> 4) << 3) + j0;
        unsigned lo = (unsigned)(unsigned short)f2bs(inpw[o * 64 + c]);
        unsigned hi = (unsigned)(unsigned short)f2bs(inpw[o * 64 + c + 1]);
        v = __uint_as_float(lo | (hi << 16));
      } else v = 0.f;
    }
    else if (i < 20576) { v = gbz[i - OFF_BZ]; }
    else if (i < 39008) { v = 0.f; }
    else if (i < 39040) { v = gbr[i - OFF_BR]; }
    else if (i < 57472) { v = 0.f; }
    else if (i < 57504) { v = gbq[i - OFF_BQ]; }
    else if (i < 58080) { int d = i - OFF_DWP; int tap = d >> 6, o = d & 63; v = dww[o*9 + tap]; }
    else if (i < 58144) { v = dwb[i - OFF_DWB]; }
    else if (i < 58208) { v = lng[i - OFF_LNG]; }
    else if (i < 58272) { v = lnb[i - OFF_LNB]; }
    else if (i < 65184) { v = 0.f; }
    else if (i < 65292) { int j = i - OFF_OMB; v = (j < 72) ? offb[j] : maskb[j-72]; }
    else if (i < 65296) { v = 0.f; }
    else if (i < 69392) { int d = i - OFF_WINP; int c = d >> 6, o = d & 63; v = inpw[o*64 + c]; }
    else if (i < 69456) { v = inpb[i - OFF_BINP]; }
    else if (i < 73552) { v = 0.f; }
    else { v = outb[i - OFF_BOUT]; }
    Wp[i] = v;
    return;
  }

  // ===== encoder blocks (MFMA, XCD h-band aligned with k_zr/stageB/k_mega) =====
  int pb2 = b - NB_PREPB;
  int xcd2 = pb2 & 7, slot2 = pb2 >> 3;
  int img = slot2 >> 5, rem2 = slot2 & 31;
  int h = xcd2 * 16 + (rem2 & 15);
  int w0 = (rem2 >> 4) * 64;
  int px = tid & 63, sect = tid >> 6;
  if (tid < 32) {
    float sc = bn_g[tid] * rsqrtf(bn_v[tid] + 1e-5f);
    escl[tid] = sc;
    escl[32 + tid] = (enc_b[tid] - bn_m[tid]) * sc + bn_b[tid];
  }
  // stage enc_w -> LDS in B-fragment order (from kernel input: no cross-block dep)
  {
    int frag = tid >> 6, lnx = tid & 63;
    int ntw = frag >> 1, kcw = frag & 1;
    int o = ntw * 16 + (lnx & 15);
    int cb = kcw * 32 + ((lnx >> 4) << 3);
    short tmpw[8];
    #pragma unroll
    for (int j = 0; j < 8; ++j) tmpw[j] = f2bs(enc_w[o * 64 + cb + j]);
    *(short8v*)(ews + tid * 8) = *(const short8v*)tmpw;
  }
  int hw = h * WT + w0 + px;
  const float* yp = Y + (size_t)img * (32 * HWT) + hw;
  bf16 yv[8];
  #pragma unroll
  for (int i2 = 0; i2 < 8; ++i2) yv[i2] = f2b(yp[(sect * 8 + i2) * HWT]);
  size_t pbb = (((size_t)img * 130 + h + 1) * 130 + (w0 + px + 1)) * 64;
  *(uint4*)(hxp + pbb + sect * 8) = *(const uint4*)yv;
  // MFMA encoder: M=64px (16/wave), N=32, K=64
  int quad = px >> 4, lm = px & 15;
  const float* xb = X + (size_t)img * (64 * HWT) + h * WT + w0 + sect * 16 + lm;
  short8v af[2];
  #pragma unroll
  for (int kc = 0; kc < 2; ++kc) {
    short tmp[8];
    #pragma unroll
    for (int j = 0; j < 8; ++j)
      tmp[j] = f2bs(xb[(size_t)(kc * 32 + quad * 8 + j) * HWT]);
    af[kc] = *(const short8v*)tmp;
  }
  __syncthreads();
  float4v eacc[2];
  eacc[0] = (float4v){0.f,0.f,0.f,0.f};
  eacc[1] = (float4v){0.f,0.f,0.f,0.f};
  #pragma unroll
  for (int kc = 0; kc < 2; ++kc) {
    #pragma unroll
    for (int nt = 0; nt < 2; ++nt) {
      short8v bb = *(const short8v*)(ews + ((nt * 2 + kc) * 64 + px) * 8);
      eacc[nt] = __builtin_amdgcn_mfma_f32_16x16x32_bf16(af[kc], bb, eacc[nt], 0, 0, 0);
    }
  }
  #pragma unroll
  for (int nt = 0; nt < 2; ++nt) {
    int o = nt * 16 + lm;
    float sc = escl[o], bi = escl[32 + o];
    #pragma unroll
    for (int ri = 0; ri < 4; ++ri) {
      float e = eacc[nt][ri] * sc + bi;
      es[(sect * 16 + quad * 4 + ri) * 40 + o] = f2bs(e / (1.f + __expf(-e)));
    }
  }
  __syncthreads();
  {
    int row = tid >> 2, c0 = (tid & 3) * 8;
    short8v v0 = *(const short8v*)(es + row * 40 + c0);
    size_t ob = (((size_t)img * 130 + h + 1) * 130 + (w0 + row + 1)) * 64 + 32 + c0;
    *(short8v*)((short*)hxp + ob) = v0;
    *(short8v*)((short*)qinp + ob) = v0;
  }
}

// ---------------- K2: z+r implicit-GEMM, in-loop A-loads, XCD h-band swizzle ----------------
__global__ void __launch_bounds__(256) k_zr(
    const float* __restrict__ Wp,
    const bf16* __restrict__ hxp, const bf16* __restrict__ wzrb,
    bf16* __restrict__ qinp, bf16* __restrict__ zbuf) {
  __shared__ short zt[32 * 72];
  __shared__ short ryt[64 * 40];
  int tid = threadIdx.x;
  int wv = tid >> 6, ln = tid & 63;
  int quad = ln >> 4, lm = ln & 15;
  int bid = blockIdx.x;
  int xcd = bid & 7, slot = bid >> 3;
  int img = slot >> 5, rem = slot & 31;
  int h = xcd * 16 + (rem & 15);
  int x0 = (rem >> 4) * 64;
  int p0 = x0 + wv * 16;
  const short* hs = (const short*)hxp;
  const short* ws = (const short*)wzrb;
  size_t rowb = ((size_t)img * 130 + h + 1) * 130;
  const short* ab = hs + (rowb + p0 + lm + 1) * 64 + quad * 8;
  float4v acc[4];
  #pragma unroll
  for (int t = 0; t < 4; ++t) acc[t] = (float4v){0.f, 0.f, 0.f, 0.f};
  #pragma unroll
  for (int kc = 0; kc < 18; ++kc) {
    const int tap = kc >> 1, cin0 = (kc & 1) * 32;
    const int dd = (tap / 3 - 1) * 130 + (tap % 3 - 1);
    short8v a = *(const short8v*)(ab + dd * 64 + cin0);
    #pragma unroll
    for (int t = 0; t < 4; ++t) {
      short8v b = *(const short8v*)(ws + ((t * 18 + kc) * 64 + ln) * 8);
      acc[t] = __builtin_amdgcn_mfma_f32_16x16x32_bf16(a, b, acc[t], 0, 0, 0);
    }
  }
  #pragma unroll
  for (int t = 0; t < 2; ++t) {
    int n = t * 16 + lm;
    float bz = Wp[OFF_BZ + n];
    short zp[4];
    #pragma unroll
    for (int ri = 0; ri < 4; ++ri)
      zp[ri] = f2bs(1.f / (1.f + __expf(-(acc[t][ri] + bz))));
    *(short4v*)(zt + n * 72 + wv * 16 + quad * 4) = *(const short4v*)zp;
  }
  #pragma unroll
  for (int t = 2; t < 4; ++t) {
    int c = (t - 2) * 16 + lm;
    float br = Wp[OFF_BR + c];
    #pragma unroll
    for (int ri = 0; ri < 4; ++ri) {
      int pxl = wv * 16 + quad * 4 + ri;
      float rv = 1.f / (1.f + __expf(-(acc[t][ri] + br)));
      float yy = b2f(hxp[(rowb + x0 + pxl + 1) * 64 + c]);
      ryt[pxl * 40 + c] = f2bs(rv * yy);
    }
  }
  __syncthreads();
  {
    int n2 = tid >> 3, pq = tid & 7;
    short8v z0 = *(const short8v*)(zt + n2 * 72 + pq * 8);
    short* zo = (short*)zbuf + (((size_t)img * 128 + h) * 32 + n2) * 128 + x0 + pq * 8;
    *(short8v*)zo = z0;
  }
  {
    int px = tid >> 2, cq = tid & 3;
    short8v r0 = *(const short8v*)(ryt + px * 40 + cq * 8);
    short* qo = (short*)qinp + (rowb + x0 + px + 1) * 64 + cq * 8;
    *(short8v*)qo = r0;
  }
}

// ---------------- K3: stageB v2 — 2048 uniform 64-px blocks, XCD h-band swizzle ----------------
__global__ void __launch_bounds__(256) k_stageB(
    const float* __restrict__ Y, const float* __restrict__ Wp,
    const bf16* __restrict__ qinp, const bf16* __restrict__ wqb,
    const bf16* __restrict__ zbuf, float* __restrict__ outh,
    const float* __restrict__ X, bf16* __restrict__ xl) {
  __shared__ short xs[64 * 72];
  int tid = threadIdx.x;
  int bid = blockIdx.x;
  int xcd = bid & 7, u = bid >> 3;           // u 0..255
  int part = u & 1, slot = u >> 1;           // slot 0..127
  int img = slot >> 5, rem = slot & 31;
  int hh = xcd * 16 + (rem & 15);
  int w0 = (rem >> 4) * 64;
  int wv = tid >> 6, ln = tid & 63, quad = ln >> 4, lm = ln & 15;

  if (part == 0) {
    // ===== q-GEMM: 64 px, N=32; wave wv owns 16-px M-tile =====
    int p0 = w0 + wv * 16;
    const short* qs = (const short*)qinp;
    const short* ws = (const short*)wqb;
    size_t rowb = ((size_t)img * 130 + hh + 1) * 130;
    const short* ab = qs + (rowb + p0 + lm + 1) * 64 + quad * 8;
    float4v acc0 = (float4v){0.f,0.f,0.f,0.f};
    float4v acc1 = (float4v){0.f,0.f,0.f,0.f};
    #pragma unroll
    for (int kc = 0; kc < 18; ++kc) {
      const int tap = kc >> 1, cin0 = (kc & 1) * 32;
      const int dd = (tap / 3 - 1) * 130 + (tap % 3 - 1);
      short8v a  = *(const short8v*)(ab + dd * 64 + cin0);
      short8v b0 = *(const short8v*)(ws + ((0 * 18 + kc) * 64 + ln) * 8);
      short8v b1 = *(const short8v*)(ws + ((1 * 18 + kc) * 64 + ln) * 8);
      acc0 = __builtin_amdgcn_mfma_f32_16x16x32_bf16(a, b0, acc0, 0, 0, 0);
      acc1 = __builtin_amdgcn_mfma_f32_16x16x32_bf16(a, b1, acc1, 0, 0, 0);
    }
    int px4 = p0 + quad * 4;
    #pragma unroll
    for (int t = 0; t < 2; ++t) {
      float4v acc = t ? acc1 : acc0;
      int n = t * 16 + lm;
      float bq = Wp[OFF_BQ + n];
      size_t gb = ((size_t)img * 32 + n) * HWT + hh * 128 + px4;
      uint2 zz = *(const uint2*)((const short*)zbuf + (((size_t)img * 128 + hh) * 32 + n) * 128 + px4);
      float4 yv = *(const float4*)(Y + gb);
      float z0 = bu2f((unsigned short)(zz.x & 0xFFFFu)), z1 = bu2f((unsigned short)(zz.x >> 16));
      float z2 = bu2f((unsigned short)(zz.y & 0xFFFFu)), z3 = bu2f((unsigned short)(zz.y >> 16));
      float4 o;
      o.x = (1.f - z0) * yv.x + z0 * ftanh(acc[0] + bq);
      o.y = (1.f - z1) * yv.y + z1 * ftanh(acc[1] + bq);
      o.z = (1.f - z2) * yv.z + z2 * ftanh(acc[2] + bq);
      o.w = (1.f - z3) * yv.w + z3 * ftanh(acc[3] + bq);
      *(float4*)(outh + gb) = o;
    }
    return;
  }

  // ===== input linear via MFMA =====
  {
    const float* xb = X + (size_t)img * (64 * HWT) + hh * 128 + w0 + wv * 16 + lm;
    short8v a[2];
    #pragma unroll
    for (int kc = 0; kc < 2; ++kc) {
      short tmp[8];
      #pragma unroll
      for (int j = 0; j < 8; ++j)
        tmp[j] = f2bs(xb[(size_t)(kc * 32 + quad * 8 + j) * HWT]);
      a[kc] = *(const short8v*)tmp;
    }
    const short* wib = (const short*)Wp + 2 * OFF_WINPB;
    float4v acc[4];
    #pragma unroll
    for (int nt = 0; nt < 4; ++nt) acc[nt] = (float4v){0.f,0.f,0.f,0.f};
    #pragma unroll
    for (int kc = 0; kc < 2; ++kc) {
      #pragma unroll
      for (int nt = 0; nt < 4; ++nt) {
        short8v b = *(const short8v*)(wib + ((nt * 2 + kc) * 64 + ln) * 8);
        acc[nt] = __builtin_amdgcn_mfma_f32_16x16x32_bf16(a[kc], b, acc[nt], 0, 0, 0);
      }
    }
    #pragma unroll
    for (int nt = 0; nt < 4; ++nt) {
      int o = nt * 16 + lm;
      float bias = Wp[OFF_BINP + o];
      #pragma unroll
      for (int ri = 0; ri < 4; ++ri)
        xs[(wv * 16 + quad * 4 + ri) * 72 + o] = f2bs(acc[nt][ri] + bias);
    }
    __syncthreads();
    int row = tid >> 2, c0 = (tid & 3) * 16;
    short8v v0 = *(const short8v*)(xs + row * 72 + c0);
    short8v v1 = *(const short8v*)(xs + row * 72 + c0 + 8);
    short* op = (short*)xl + ((size_t)img * HWT + hh * 128 + w0 + row) * 64 + c0;
    *(short8v*)op = v0;
    *(short8v*)(op + 8) = v1;
  }
}

// ---------------- K5 mega (512 thr, R1-verbatim: erff GELU, branchy scalar gather, 64 VGPR) ----------------
#define LDS_PSA  0         // f32 [8][64]      2048
#define LDS_PSB  2048      // f32 [8][64]      2048
#define LDS_STAT 4096      // f32 [64][2]      512
#define LDS_Y    4608      // bf16 [64][72]    9216  (vls overlays after P2)
#define LDS_OM   13824     // bf16 [64][114]   14592
#define LDS_TOT  28416

__global__ void __launch_bounds__(512) k_mega(
    const float* __restrict__ Wp, const float* __restrict__ hb,
    const bf16* __restrict__ xl, const bf16* __restrict__ womb,
    const bf16* __restrict__ woutb, float* __restrict__ out0) {
  __shared__ char smem[LDS_TOT];
  float* psa  = (float*)(smem + LDS_PSA);
  float* psb  = (float*)(smem + LDS_PSB);
  float* stat = (float*)(smem + LDS_STAT);
  short* yls  = (short*)(smem + LDS_Y);
  short* omls = (short*)(smem + LDS_OM);
  short* vls  = (short*)(smem + LDS_Y);

  int tid = threadIdx.x;
  int bid = blockIdx.x;
  int xcd = bid & 7, slot = bid >> 3;            // slot 0..127
  int img = slot >> 5;                           // 4 imgs
  int rem = slot & 31;                           // 2 w-tiles x 16 h
  int h = xcd * 16 + (rem & 15);
  int w0 = (rem >> 4) * 64;

  int wloc = tid & 63, part = tid >> 6;
  int w = w0 + wloc;
  float yv[8];
  {
    const float* hn = hb + (size_t)img * (32 * HWT);
    #pragma unroll
    for (int i = 0; i < 8; ++i) yv[i] = Wp[OFF_DWB + part*8 + i];
    #pragma unroll
    for (int tap = 0; tap < 9; ++tap) {
      int dy = tap / 3 - 1, dx = tap % 3 - 1;
      int hh = h + dy, ww = w + dx;
      bool ok = ((unsigned)hh < 128u) && ((unsigned)ww < 128u);
      int off = hh * WT + ww;
      #pragma unroll
      for (int j = 0; j < 4; ++j) {
        int cin = part * 4 + j;
        float a = ok ? hn[cin * HWT + off] : 0.f;
        yv[2*j]   += a * Wp[OFF_DWP + tap*64 + part*8 + 2*j];
        yv[2*j+1] += a * Wp[OFF_DWP + tap*64 + part*8 + 2*j+1];
      }
    }
  }
  float lsum = 0.f, lsq = 0.f;
  #pragma unroll
  for (int i = 0; i < 8; ++i) { lsum += yv[i]; lsq += yv[i]*yv[i]; }
  psa[part * 64 + wloc] = lsum;
  psb[part * 64 + wloc] = lsq;
  __syncthreads();
  if (tid < 64) {
    float s = 0.f, q = 0.f;
    #pragma unroll
    for (int p = 0; p < 8; ++p) { s += psa[p*64 + tid]; q += psb[p*64 + tid]; }
    float mu = s * (1.f/64.f);
    float var = q * (1.f/64.f) - mu * mu;
    stat[tid*2] = mu;
    stat[tid*2+1] = rsqrtf(var + 1e-6f);
  }
  __syncthreads();
  {
    float mu = stat[wloc*2], inv = stat[wloc*2+1];
    bf16 tmp[8];
    #pragma unroll
    for (int i = 0; i < 8; ++i) {
      int c = part*8 + i;
      float v = (yv[i] - mu) * inv * Wp[OFF_LNG + c] + Wp[OFF_LNB + c];
      tmp[i] = f2b(0.5f * v * (1.f + erff(v * 0.70710678118654752f)));
    }
    *(short8v*)(yls + wloc*72 + part*8) = *(const short8v*)tmp;
  }
  __syncthreads();

  int wv = tid >> 6, ln = tid & 63, quad = ln >> 4, lm = ln & 15;
  if (wv < 7) {
    const short* wb = (const short*)womb;
    float4v acc[4];
    #pragma unroll
    for (int mt = 0; mt < 4; ++mt) acc[mt] = (float4v){0.f,0.f,0.f,0.f};
    #pragma unroll
    for (int kc = 0; kc < 2; ++kc) {
      short8v b = *(const short8v*)(wb + ((wv * 2 + kc) * 64 + ln) * 8);
      #pragma unroll
      for (int mt = 0; mt < 4; ++mt) {
        short8v a = *(const short8v*)(yls + (mt*16 + lm)*72 + kc*32 + quad*8);
        acc[mt] = __builtin_amdgcn_mfma_f32_16x16x32_bf16(a, b, acc[mt], 0, 0, 0);
      }
    }
    float bias = Wp[OFF_OMB + wv*16 + lm];
    #pragma unroll
    for (int mt = 0; mt < 4; ++mt) {
      #pragma unroll
      for (int ri = 0; ri < 4; ++ri)
        omls[(mt*16 + quad*4 + ri)*114 + wv*16 + lm] = f2bs(acc[mt][ri] + bias);
    }
  }
  __syncthreads();

  {
    int px = tid >> 3, g = (tid >> 1) & 3, half = tid & 1;
    const short* oml = omls + px*114;
    float m[9];
    #pragma unroll
    for (int p = 0; p < 9; ++p) m[p] = bu2f((unsigned short)oml[72 + g*9 + p]);
    float mx = m[0];
    #pragma unroll
    for (int p = 1; p < 9; ++p) mx = fmaxf(mx, m[p]);
    float sum = 0.f;
    #pragma unroll
    for (int p = 0; p < 9; ++p) { m[p] = __expf(m[p] - mx); sum += m[p]; }
    float rs = 1.f / sum;
    int wg = w0 + px;
    const bf16* xn = xl + (size_t)img * (HWT * 64);
    float acc[8];
    #pragma unroll
    for (int i = 0; i < 8; ++i) acc[i] = 0.f;
    for (int p = 0; p < 9; ++p) {
      float bx = (float)(wg + p / 3 - 1);
      float by = (float)(h + p % 3 - 1);
      float ox = bu2f((unsigned short)oml[g*18 + p*2]);
      float oy = bu2f((unsigned short)oml[g*18 + p*2 + 1]);
      float mk = m[p] * rs;
      float pxx = bx + ox, pyy = by + oy;
      float fx = floorf(pxx), fy = floorf(pyy);
      int jx0 = (int)fx, jy0 = (int)fy;
      float wx1 = pxx - fx, wy1 = pyy - fy;
      float wx0 = 1.f - wx1, wy0 = 1.f - wy1;
      int cjx[4] = { jx0, jx0 + 1, jx0, jx0 + 1 };
      int cjy[4] = { jy0, jy0, jy0 + 1, jy0 + 1 };
      float cw[4] = { wx0*wy0, wx1*wy0, wx0*wy1, wx1*wy1 };
      #pragma unroll
      for (int k = 0; k < 4; ++k) {
        if ((unsigned)cjx[k] < 128u && (unsigned)cjy[k] < 128u) {
          float cf = mk * cw[k];
          const bf16* s = xn + (size_t)(cjy[k] * WT + cjx[k]) * 64 + g * 16 + half * 8;
          uint4 u0 = *(const uint4*)(s);
          const unsigned uu[4] = {u0.x,u0.y,u0.z,u0.w};
          #pragma unroll
          for (int q = 0; q < 4; ++q) {
            acc[2*q]     += cf * bu2f((unsigned short)(uu[q] & 0xFFFFu));
            acc[2*q + 1] += cf * bu2f((unsigned short)(uu[q] >> 16));
          }
        }
      }
    }
    bf16 tmp[8];
    #pragma unroll
    for (int i = 0; i < 8; ++i) tmp[i] = f2b(acc[i]);
    *(short8v*)(vls + px*72 + g*16 + half*8) = *(const short8v*)tmp;
  }
  __syncthreads();

  {
    const short* wb = (const short*)woutb;
    #pragma unroll
    for (int s = 0; s < 2; ++s) {
      int tile = wv * 2 + s;
      int nt = tile >> 2, mt = tile & 3;
      float4v acc = (float4v){0.f,0.f,0.f,0.f};
      #pragma unroll
      for (int kc = 0; kc < 2; ++kc) {
        short8v b = *(const short8v*)(wb + ((nt * 2 + kc) * 64 + ln) * 8);
        short8v a = *(const short8v*)(vls + (mt*16 + lm)*72 + kc*32 + quad*8);
        acc = __builtin_amdgcn_mfma_f32_16x16x32_bf16(a, b, acc, 0, 0, 0);
      }
      int ch = nt*16 + lm;
      float bias = Wp[OFF_BOUT + ch];
      float4 v;
      float s0 = acc[0] + bias; v.x = s0 / (1.f + __expf(-s0));
      float s1 = acc[1] + bias; v.y = s1 / (1.f + __expf(-s1));
      float s2 = acc[2] + bias; v.z = s2 / (1.f + __expf(-s2));
      float s3 = acc[3] + bias; v.w = s3 / (1.f + __expf(-s3));
      *(float4*)(out0 + ((size_t)img*64 + ch)*HWT + h*128 + w0 + mt*16 + quad*4) = v;
    }
  }
}

extern "C" void kernel_launch(void* const* d_in, const int* in_sizes, int n_in,
                              void* d_out, int out_size, void* d_ws, size_t ws_size,
                              hipStream_t stream) {
  const float* input_x = (const float*)d_in[0];
  const float* input_y = (const float*)d_in[1];

  float* Wp = (float*)d_ws;
  bf16* WZRB  = (bf16*)((char*)d_ws + B_WZRB);
  bf16* WQB   = (bf16*)((char*)d_ws + B_WQB);
  bf16* WOMB  = (bf16*)((char*)d_ws + B_WOMB);
  bf16* WOUTB = (bf16*)((char*)d_ws + B_WOUTB);
  bf16* HXP   = (bf16*)((char*)d_ws + B_HXP);
  bf16* QINP  = (bf16*)((char*)d_ws + B_QINP);
  bf16* ZBUF  = (bf16*)((char*)d_ws + B_ZBUF);
  bf16* XL    = (bf16*)((char*)d_ws + B_XL);
  float* out0 = (float*)d_out;
  float* outh = (float*)d_out + 4194304;

  k_stage1<<<dim3(NB_PREPB + 1024), dim3(256), 0, stream>>>(
      (const float*)d_in[2], (const float*)d_in[3], (const float*)d_in[4], (const float*)d_in[5],
      (const float*)d_in[6], (const float*)d_in[7], (const float*)d_in[8], (const float*)d_in[9],
      (const float*)d_in[10], (const float*)d_in[11], (const float*)d_in[12], (const float*)d_in[13],
      (const float*)d_in[14], (const float*)d_in[15], (const float*)d_in[16], (const float*)d_in[17],
      (const float*)d_in[18], (const float*)d_in[19], (const float*)d_in[20], (const float*)d_in[21],
      (const float*)d_in[22], (const float*)d_in[23], (const float*)d_in[24], (const float*)d_in[25],
      Wp, WZRB, WQB, WOMB, WOUTB, HXP, QINP, input_x, input_y);
  k_zr<<<dim3(1024), dim3(256), 0, stream>>>(Wp, HXP, WZRB, QINP, ZBUF);
  k_stageB<<<dim3(2048), dim3(256), 0, stream>>>(input_y, Wp, QINP, WQB, ZBUF, outh, input_x, XL);
  k_mega<<<dim3(1024), dim3(512), 0, stream>>>(Wp, outh, XL, WOMB, WOUTB, out0);
}

// Round 9
// 220.163 us; speedup vs baseline: 1.5439x; 1.0108x over previous
//
#include <hip/hip_runtime.h>
#include <hip/hip_bf16.h>

typedef __hip_bfloat16 bf16;
typedef short short8v __attribute__((ext_vector_type(8)));
typedef short short4v __attribute__((ext_vector_type(4)));
typedef float float4v __attribute__((ext_vector_type(4)));

static __device__ __forceinline__ float b2f(bf16 v){ return __bfloat162float(v); }
static __device__ __forceinline__ bf16 f2b(float v){ return __float2bfloat16(v); }
static __device__ __forceinline__ float bu2f(unsigned short u){ return __uint_as_float(((unsigned)u) << 16); }
static __device__ __forceinline__ short f2bs(float v){ bf16 t = __float2bfloat16(v); return *(short*)&t; }
static __device__ __forceinline__ float ftanh(float x){ return 1.f - 2.f / (1.f + __expf(2.f * x)); }

#define WT 128
#define HWT 16384

// ---- packed f32 weights (float offsets inside ws) ----
#define OFF_WINPB 1024     // bf16 fragment-order [nt:4][kc:2][ln:64][j:8] packed 2/float (2048 floats)
#define OFF_BZ    20544    // 32
#define OFF_BR    39008    // 32
#define OFF_BQ    57472    // 32
#define OFF_DWP   57504    // [tap][64]        576
#define OFF_DWB   58080    // 64
#define OFF_LNG   58144    // 64
#define OFF_LNB   58208    // 64
#define OFF_OMB   65184    // 108 (+4 zero pad)
#define OFF_WINP  65296    // [c][64]          4096
#define OFF_BINP  69392    // 64
#define OFF_BOUT  73552    // 64
#define NW_TOTAL  73616
#define NBF_ZR    36864    // bf16 fragment-order [t:4][kc:18][ln:64][j:8]
#define NBF_Q     18432    // bf16 fragment-order [t:2][kc:18][ln:64][j:8]
#define NBF_OM    7168     // bf16 fragment-order [wv:7][kc:2][ln:64][j:8]
#define NBF_OUT   4096     // bf16 fragment-order [nt:4][kc:2][ln:64][j:8]
#define NPREP     (NW_TOTAL + NBF_ZR + NBF_Q + NBF_OM + NBF_OUT)
#define NHALO     2064     // 4 imgs * 516 halo pixels
#define NTOT      (NPREP + NHALO)
#define NB_PREPB  556      // ceil(NTOT/256)

// ---- ws byte offsets ----
#define B_WZRB  294912
#define B_WQB   368640
#define B_WOMB  405504
#define B_WOUTB 419840
#define B_HXP   428544     // bf16 [4][130][130][64]  (dead after k_zr)
#define B_QINP  9081344    // bf16 [4][130][130][64]  (dead after stageB)
#define B_ZBUF  17734144   // bf16 [4][128][32][128]
#define B_XL    428544     // bf16 [4][HWT][64] overlays HXP (fallback: written in stageB part1)
#define B_XL2   21928448   // bf16 [4][HWT][64] NEW region (used iff ws_size allows) -> k_zr can write it
#define WS_NEED (21928448ull + 8388608ull)

// ---------------- K1: stage1 = weight-prep blocks + MFMA encoder blocks ----------------
// NOTE: encoder blocks must read ONLY kernel inputs (enc_w etc.), never Wp —
// prep blocks run in the SAME launch and dispatch order is undefined (R7 race).
__global__ void __launch_bounds__(256) k_stage1(
    const float* __restrict__ enc_w, const float* __restrict__ enc_b,
    const float* __restrict__ bn_g, const float* __restrict__ bn_b,
    const float* __restrict__ bn_m, const float* __restrict__ bn_v,
    const float* __restrict__ gwz, const float* __restrict__ gbz,
    const float* __restrict__ gwr, const float* __restrict__ gbr,
    const float* __restrict__ gwq, const float* __restrict__ gbq,
    const float* __restrict__ dww, const float* __restrict__ dwb,
    const float* __restrict__ lng, const float* __restrict__ lnb,
    const float* __restrict__ offw, const float* __restrict__ offb,
    const float* __restrict__ maskw, const float* __restrict__ maskb,
    const float* __restrict__ inpw, const float* __restrict__ inpb,
    const float* __restrict__ outw, const float* __restrict__ outb,
    float* __restrict__ Wp, bf16* __restrict__ wzrb, bf16* __restrict__ wqb,
    bf16* __restrict__ womb, bf16* __restrict__ woutb,
    bf16* __restrict__ hxp, bf16* __restrict__ qinp,
    const float* __restrict__ X, const float* __restrict__ Y) {
  __shared__ float escl[64];
  __shared__ short ews[2048];   // enc_w in B-fragment order [frag:4][ln:64][j:8]
  __shared__ short es[64 * 40];
  int tid = threadIdx.x;
  int b = blockIdx.x;

  if (b < NB_PREPB) {
    int i = b * 256 + tid;
    if (i >= NTOT) return;
    if (i >= NPREP) {
      int t = i - NPREP;
      int img = t / 516, r = t % 516;
      int ph, pw;
      if (r < 130) { ph = 0; pw = r; }
      else if (r < 260) { ph = 129; pw = r - 130; }
      else if (r < 388) { ph = r - 260 + 1; pw = 0; }
      else { ph = r - 388 + 1; pw = 129; }
      size_t pb = (((size_t)img * 130 + ph) * 130 + pw) * 64;
      uint4 zz = make_uint4(0, 0, 0, 0);
      #pragma unroll
      for (int k = 0; k < 8; ++k) {
        ((uint4*)(hxp + pb))[k] = zz;
        ((uint4*)(qinp + pb))[k] = zz;
      }
      return;
    }
    if (i >= NW_TOTAL) {
      int d = i - NW_TOTAL;
      if (d < NBF_ZR) {
        int t = d / 9216, rem = d % 9216;
        int kc = rem / 512, rem2 = rem % 512;
        int ln = rem2 >> 3, j = rem2 & 7;
        int n = t * 16 + (ln & 15);
        int cin = (kc & 1) * 32 + ((ln >> 4) << 3) + j;
        int tap = kc >> 1;
        float v = (n < 32) ? gwz[(n*64 + cin)*9 + tap] : gwr[((n-32)*64 + cin)*9 + tap];
        wzrb[d] = f2b(v);
      } else if (d < NBF_ZR + NBF_Q) {
        int d2 = d - NBF_ZR;
        int t = d2 / 9216, rem = d2 % 9216;
        int kc = rem / 512, rem2 = rem % 512;
        int ln = rem2 >> 3, j = rem2 & 7;
        int n = t * 16 + (ln & 15);
        int cin = (kc & 1) * 32 + ((ln >> 4) << 3) + j;
        int tap = kc >> 1;
        wqb[d2] = f2b(gwq[(n*64 + cin)*9 + tap]);
      } else if (d < NBF_ZR + NBF_Q + NBF_OM) {
        int d3 = d - NBF_ZR - NBF_Q;
        int wv = d3 / 1024, rem = d3 % 1024;
        int kc = rem / 512, rem2 = rem % 512;
        int ln = rem2 >> 3, j = rem2 & 7;
        int jcol = wv * 16 + (ln & 15);
        int c = kc * 32 + ((ln >> 4) << 3) + j;
        float v = (jcol < 72) ? offw[jcol*64 + c] : ((jcol < 108) ? maskw[(jcol-72)*64 + c] : 0.f);
        womb[d3] = f2b(v);
      } else {
        int d4 = d - NBF_ZR - NBF_Q - NBF_OM;
        int nt = d4 / 1024, rem = d4 % 1024;
        int kc = rem / 512, rem2 = rem % 512;
        int ln = rem2 >> 3, j = rem2 & 7;
        int o = nt * 16 + (ln & 15);
        int c = kc * 32 + ((ln >> 4) << 3) + j;
        woutb[d4] = f2b(outw[o*64 + c]);
      }
      return;
    }
    float v;
    if (i < 20544) {
      if (i >= OFF_WINPB && i < OFF_WINPB + 2048) {
        // bf16 fragment-order inp_w: d = ((nt*2+kc)*64+ln)*8+j, packed 2 bf16 per float
        int d0 = (i - OFF_WINPB) * 2;
        int nt = d0 >> 10, kc = (d0 >> 9) & 1, lnn = (d0 >> 3) & 63, j0 = d0 & 7;
        int o = nt * 16 + (lnn & 15);
        int c = kc * 32 + ((lnn >> 4) << 3) + j0;
        unsigned lo = (unsigned)(unsigned short)f2bs(inpw[o * 64 + c]);
        unsigned hi = (unsigned)(unsigned short)f2bs(inpw[o * 64 + c + 1]);
        v = __uint_as_float(lo | (hi << 16));
      } else v = 0.f;
    }
    else if (i < 20576) { v = gbz[i - OFF_BZ]; }
    else if (i < 39008) { v = 0.f; }
    else if (i < 39040) { v = gbr[i - OFF_BR]; }
    else if (i < 57472) { v = 0.f; }
    else if (i < 57504) { v = gbq[i - OFF_BQ]; }
    else if (i < 58080) { int d = i - OFF_DWP; int tap = d >> 6, o = d & 63; v = dww[o*9 + tap]; }
    else if (i < 58144) { v = dwb[i - OFF_DWB]; }
    else if (i < 58208) { v = lng[i - OFF_LNG]; }
    else if (i < 58272) { v = lnb[i - OFF_LNB]; }
    else if (i < 65184) { v = 0.f; }
    else if (i < 65292) { int j = i - OFF_OMB; v = (j < 72) ? offb[j] : maskb[j-72]; }
    else if (i < 65296) { v = 0.f; }
    else if (i < 69392) { int d = i - OFF_WINP; int c = d >> 6, o = d & 63; v = inpw[o*64 + c]; }
    else if (i < 69456) { v = inpb[i - OFF_BINP]; }
    else if (i < 73552) { v = 0.f; }
    else { v = outb[i - OFF_BOUT]; }
    Wp[i] = v;
    return;
  }

  // ===== encoder blocks (MFMA, XCD h-band aligned with k_zr/stageB/k_mega) =====
  int pb2 = b - NB_PREPB;
  int xcd2 = pb2 & 7, slot2 = pb2 >> 3;
  int img = slot2 >> 5, rem2 = slot2 & 31;
  int h = xcd2 * 16 + (rem2 & 15);
  int w0 = (rem2 >> 4) * 64;
  int px = tid & 63, sect = tid >> 6;
  if (tid < 32) {
    float sc = bn_g[tid] * rsqrtf(bn_v[tid] + 1e-5f);
    escl[tid] = sc;
    escl[32 + tid] = (enc_b[tid] - bn_m[tid]) * sc + bn_b[tid];
  }
  // stage enc_w -> LDS in B-fragment order (from kernel input: no cross-block dep)
  {
    int frag = tid >> 6, lnx = tid & 63;
    int ntw = frag >> 1, kcw = frag & 1;
    int o = ntw * 16 + (lnx & 15);
    int cb = kcw * 32 + ((lnx >> 4) << 3);
    short tmpw[8];
    #pragma unroll
    for (int j = 0; j < 8; ++j) tmpw[j] = f2bs(enc_w[o * 64 + cb + j]);
    *(short8v*)(ews + tid * 8) = *(const short8v*)tmpw;
  }
  int hw = h * WT + w0 + px;
  const float* yp = Y + (size_t)img * (32 * HWT) + hw;
  bf16 yv[8];
  #pragma unroll
  for (int i2 = 0; i2 < 8; ++i2) yv[i2] = f2b(yp[(sect * 8 + i2) * HWT]);
  size_t pbb = (((size_t)img * 130 + h + 1) * 130 + (w0 + px + 1)) * 64;
  *(uint4*)(hxp + pbb + sect * 8) = *(const uint4*)yv;
  // MFMA encoder: M=64px (16/wave), N=32, K=64
  int quad = px >> 4, lm = px & 15;
  const float* xb = X + (size_t)img * (64 * HWT) + h * WT + w0 + sect * 16 + lm;
  short8v af[2];
  #pragma unroll
  for (int kc = 0; kc < 2; ++kc) {
    short tmp[8];
    #pragma unroll
    for (int j = 0; j < 8; ++j)
      tmp[j] = f2bs(xb[(size_t)(kc * 32 + quad * 8 + j) * HWT]);
    af[kc] = *(const short8v*)tmp;
  }
  __syncthreads();
  float4v eacc[2];
  eacc[0] = (float4v){0.f,0.f,0.f,0.f};
  eacc[1] = (float4v){0.f,0.f,0.f,0.f};
  #pragma unroll
  for (int kc = 0; kc < 2; ++kc) {
    #pragma unroll
    for (int nt = 0; nt < 2; ++nt) {
      short8v bb = *(const short8v*)(ews + ((nt * 2 + kc) * 64 + px) * 8);
      eacc[nt] = __builtin_amdgcn_mfma_f32_16x16x32_bf16(af[kc], bb, eacc[nt], 0, 0, 0);
    }
  }
  #pragma unroll
  for (int nt = 0; nt < 2; ++nt) {
    int o = nt * 16 + lm;
    float sc = escl[o], bi = escl[32 + o];
    #pragma unroll
    for (int ri = 0; ri < 4; ++ri) {
      float e = eacc[nt][ri] * sc + bi;
      es[(sect * 16 + quad * 4 + ri) * 40 + o] = f2bs(e / (1.f + __expf(-e)));
    }
  }
  __syncthreads();
  {
    int row = tid >> 2, c0 = (tid & 3) * 8;
    short8v v0 = *(const short8v*)(es + row * 40 + c0);
    size_t ob = (((size_t)img * 130 + h + 1) * 130 + (w0 + row + 1)) * 64 + 32 + c0;
    *(short8v*)((short*)hxp + ob) = v0;
    *(short8v*)((short*)qinp + ob) = v0;
  }
}

// ---------------- K2: z+r implicit-GEMM (+ optional merged input-linear blocks) ----------------
// merged==1: grid 2048, part-interleaved (z+r | input-linear->xl). merged==0: grid 1024, z+r only.
// Input-linear reads only X and Wp (prev launch) and writes xl (exclusive region) — no intra-launch dep.
__global__ void __launch_bounds__(256) k_zr(
    const float* __restrict__ Wp,
    const bf16* __restrict__ hxp, const bf16* __restrict__ wzrb,
    bf16* __restrict__ qinp, bf16* __restrict__ zbuf,
    const float* __restrict__ X, bf16* __restrict__ xl, int merged) {
  __shared__ short shm[4864];   // z+r: zt=shm[0..2303], ryt=shm[2304..4863]; inp: xs=shm[0..4607]
  short* zt  = shm;             // [32][72]
  short* ryt = shm + 2304;      // [64][40]
  short* xs  = shm;             // [64][72]
  int tid = threadIdx.x;
  int bid = blockIdx.x;
  int xcd, slot, part;
  if (merged) { xcd = bid & 7; int u = bid >> 3; part = u & 1; slot = u >> 1; }
  else        { xcd = bid & 7; part = 0; slot = bid >> 3; }
  int img = slot >> 5, rem = slot & 31;
  int h = xcd * 16 + (rem & 15);
  int x0 = (rem >> 4) * 64;
  int wv = tid >> 6, ln = tid & 63;
  int quad = ln >> 4, lm = ln & 15;

  if (part == 0) {
    int p0 = x0 + wv * 16;
    const short* hs = (const short*)hxp;
    const short* ws = (const short*)wzrb;
    size_t rowb = ((size_t)img * 130 + h + 1) * 130;
    const short* ab = hs + (rowb + p0 + lm + 1) * 64 + quad * 8;
    float4v acc[4];
    #pragma unroll
    for (int t = 0; t < 4; ++t) acc[t] = (float4v){0.f, 0.f, 0.f, 0.f};
    #pragma unroll
    for (int kc = 0; kc < 18; ++kc) {
      const int tap = kc >> 1, cin0 = (kc & 1) * 32;
      const int dd = (tap / 3 - 1) * 130 + (tap % 3 - 1);
      short8v a = *(const short8v*)(ab + dd * 64 + cin0);
      #pragma unroll
      for (int t = 0; t < 4; ++t) {
        short8v b = *(const short8v*)(ws + ((t * 18 + kc) * 64 + ln) * 8);
        acc[t] = __builtin_amdgcn_mfma_f32_16x16x32_bf16(a, b, acc[t], 0, 0, 0);
      }
    }
    #pragma unroll
    for (int t = 0; t < 2; ++t) {
      int n = t * 16 + lm;
      float bz = Wp[OFF_BZ + n];
      short zp[4];
      #pragma unroll
      for (int ri = 0; ri < 4; ++ri)
        zp[ri] = f2bs(1.f / (1.f + __expf(-(acc[t][ri] + bz))));
      *(short4v*)(zt + n * 72 + wv * 16 + quad * 4) = *(const short4v*)zp;
    }
    #pragma unroll
    for (int t = 2; t < 4; ++t) {
      int c = (t - 2) * 16 + lm;
      float br = Wp[OFF_BR + c];
      #pragma unroll
      for (int ri = 0; ri < 4; ++ri) {
        int pxl = wv * 16 + quad * 4 + ri;
        float rv = 1.f / (1.f + __expf(-(acc[t][ri] + br)));
        float yy = b2f(hxp[(rowb + x0 + pxl + 1) * 64 + c]);
        ryt[pxl * 40 + c] = f2bs(rv * yy);
      }
    }
    __syncthreads();
    {
      int n2 = tid >> 3, pq = tid & 7;
      short8v z0 = *(const short8v*)(zt + n2 * 72 + pq * 8);
      short* zo = (short*)zbuf + (((size_t)img * 128 + h) * 32 + n2) * 128 + x0 + pq * 8;
      *(short8v*)zo = z0;
    }
    {
      int px = tid >> 2, cq = tid & 3;
      short8v r0 = *(const short8v*)(ryt + px * 40 + cq * 8);
      short* qo = (short*)qinp + (rowb + x0 + px + 1) * 64 + cq * 8;
      *(short8v*)qo = r0;
    }
    return;
  }

  // ===== input linear via MFMA (merged path; writes xl = XL2, no overlap with hxp) =====
  {
    const float* xb = X + (size_t)img * (64 * HWT) + h * 128 + x0 + wv * 16 + lm;
    short8v a[2];
    #pragma unroll
    for (int kc = 0; kc < 2; ++kc) {
      short tmp[8];
      #pragma unroll
      for (int j = 0; j < 8; ++j)
        tmp[j] = f2bs(xb[(size_t)(kc * 32 + quad * 8 + j) * HWT]);
      a[kc] = *(const short8v*)tmp;
    }
    const short* wib = (const short*)Wp + 2 * OFF_WINPB;
    float4v acc[4];
    #pragma unroll
    for (int nt = 0; nt < 4; ++nt) acc[nt] = (float4v){0.f,0.f,0.f,0.f};
    #pragma unroll
    for (int kc = 0; kc < 2; ++kc) {
      #pragma unroll
      for (int nt = 0; nt < 4; ++nt) {
        short8v b = *(const short8v*)(wib + ((nt * 2 + kc) * 64 + ln) * 8);
        acc[nt] = __builtin_amdgcn_mfma_f32_16x16x32_bf16(a[kc], b, acc[nt], 0, 0, 0);
      }
    }
    #pragma unroll
    for (int nt = 0; nt < 4; ++nt) {
      int o = nt * 16 + lm;
      float bias = Wp[OFF_BINP + o];
      #pragma unroll
      for (int ri = 0; ri < 4; ++ri)
        xs[(wv * 16 + quad * 4 + ri) * 72 + o] = f2bs(acc[nt][ri] + bias);
    }
    __syncthreads();
    int row = tid >> 2, c0 = (tid & 3) * 16;
    short8v v0 = *(const short8v*)(xs + row * 72 + c0);
    short8v v1 = *(const short8v*)(xs + row * 72 + c0 + 8);
    short* op = (short*)xl + ((size_t)img * HWT + h * 128 + x0 + row) * 64 + c0;
    *(short8v*)op = v0;
    *(short8v*)(op + 8) = v1;
  }
}

// ---------------- K3: stageB — qonly==1: 1024 q-GEMM blocks; qonly==0: R8's 2048 dual-part ----------------
__global__ void __launch_bounds__(256) k_stageB(
    const float* __restrict__ Y, const float* __restrict__ Wp,
    const bf16* __restrict__ qinp, const bf16* __restrict__ wqb,
    const bf16* __restrict__ zbuf, float* __restrict__ outh,
    const float* __restrict__ X, bf16* __restrict__ xl, int qonly) {
  __shared__ short xs[64 * 72];
  int tid = threadIdx.x;
  int bid = blockIdx.x;
  int xcd, slot, part;
  if (qonly) { xcd = bid & 7; part = 0; slot = bid >> 3; }
  else       { xcd = bid & 7; int u = bid >> 3; part = u & 1; slot = u >> 1; }
  int img = slot >> 5, rem = slot & 31;
  int hh = xcd * 16 + (rem & 15);
  int w0 = (rem >> 4) * 64;
  int wv = tid >> 6, ln = tid & 63, quad = ln >> 4, lm = ln & 15;

  if (part == 0) {
    int p0 = w0 + wv * 16;
    const short* qs = (const short*)qinp;
    const short* ws = (const short*)wqb;
    size_t rowb = ((size_t)img * 130 + hh + 1) * 130;
    const short* ab = qs + (rowb + p0 + lm + 1) * 64 + quad * 8;
    float4v acc0 = (float4v){0.f,0.f,0.f,0.f};
    float4v acc1 = (float4v){0.f,0.f,0.f,0.f};
    #pragma unroll
    for (int kc = 0; kc < 18; ++kc) {
      const int tap = kc >> 1, cin0 = (kc & 1) * 32;
      const int dd = (tap / 3 - 1) * 130 + (tap % 3 - 1);
      short8v a  = *(const short8v*)(ab + dd * 64 + cin0);
      short8v b0 = *(const short8v*)(ws + ((0 * 18 + kc) * 64 + ln) * 8);
      short8v b1 = *(const short8v*)(ws + ((1 * 18 + kc) * 64 + ln) * 8);
      acc0 = __builtin_amdgcn_mfma_f32_16x16x32_bf16(a, b0, acc0, 0, 0, 0);
      acc1 = __builtin_amdgcn_mfma_f32_16x16x32_bf16(a, b1, acc1, 0, 0, 0);
    }
    int px4 = p0 + quad * 4;
    #pragma unroll
    for (int t = 0; t < 2; ++t) {
      float4v acc = t ? acc1 : acc0;
      int n = t * 16 + lm;
      float bq = Wp[OFF_BQ + n];
      size_t gb = ((size_t)img * 32 + n) * HWT + hh * 128 + px4;
      uint2 zz = *(const uint2*)((const short*)zbuf + (((size_t)img * 128 + hh) * 32 + n) * 128 + px4);
      float4 yv = *(const float4*)(Y + gb);
      float z0 = bu2f((unsigned short)(zz.x & 0xFFFFu)), z1 = bu2f((unsigned short)(zz.x >> 16));
      float z2 = bu2f((unsigned short)(zz.y & 0xFFFFu)), z3 = bu2f((unsigned short)(zz.y >> 16));
      float4 o;
      o.x = (1.f - z0) * yv.x + z0 * ftanh(acc[0] + bq);
      o.y = (1.f - z1) * yv.y + z1 * ftanh(acc[1] + bq);
      o.z = (1.f - z2) * yv.z + z2 * ftanh(acc[2] + bq);
      o.w = (1.f - z3) * yv.w + z3 * ftanh(acc[3] + bq);
      *(float4*)(outh + gb) = o;
    }
    return;
  }

  // ===== input linear via MFMA (fallback path when qonly==0) =====
  {
    const float* xb = X + (size_t)img * (64 * HWT) + hh * 128 + w0 + wv * 16 + lm;
    short8v a[2];
    #pragma unroll
    for (int kc = 0; kc < 2; ++kc) {
      short tmp[8];
      #pragma unroll
      for (int j = 0; j < 8; ++j)
        tmp[j] = f2bs(xb[(size_t)(kc * 32 + quad * 8 + j) * HWT]);
      a[kc] = *(const short8v*)tmp;
    }
    const short* wib = (const short*)Wp + 2 * OFF_WINPB;
    float4v acc[4];
    #pragma unroll
    for (int nt = 0; nt < 4; ++nt) acc[nt] = (float4v){0.f,0.f,0.f,0.f};
    #pragma unroll
    for (int kc = 0; kc < 2; ++kc) {
      #pragma unroll
      for (int nt = 0; nt < 4; ++nt) {
        short8v b = *(const short8v*)(wib + ((nt * 2 + kc) * 64 + ln) * 8);
        acc[nt] = __builtin_amdgcn_mfma_f32_16x16x32_bf16(a[kc], b, acc[nt], 0, 0, 0);
      }
    }
    #pragma unroll
    for (int nt = 0; nt < 4; ++nt) {
      int o = nt * 16 + lm;
      float bias = Wp[OFF_BINP + o];
      #pragma unroll
      for (int ri = 0; ri < 4; ++ri)
        xs[(wv * 16 + quad * 4 + ri) * 72 + o] = f2bs(acc[nt][ri] + bias);
    }
    __syncthreads();
    int row = tid >> 2, c0 = (tid & 3) * 16;
    short8v v0 = *(const short8v*)(xs + row * 72 + c0);
    short8v v1 = *(const short8v*)(xs + row * 72 + c0 + 8);
    short* op = (short*)xl + ((size_t)img * HWT + hh * 128 + w0 + row) * 64 + c0;
    *(short8v*)op = v0;
    *(short8v*)(op + 8) = v1;
  }
}

// ---------------- K5 mega (512 thr, R1-verbatim: erff GELU, branchy scalar gather, 64 VGPR) ----------------
#define LDS_PSA  0         // f32 [8][64]      2048
#define LDS_PSB  2048      // f32 [8][64]      2048
#define LDS_STAT 4096      // f32 [64][2]      512
#define LDS_Y    4608      // bf16 [64][72]    9216  (vls overlays after P2)
#define LDS_OM   13824     // bf16 [64][114]   14592
#define LDS_TOT  28416

__global__ void __launch_bounds__(512) k_mega(
    const float* __restrict__ Wp, const float* __restrict__ hb,
    const bf16* __restrict__ xl, const bf16* __restrict__ womb,
    const bf16* __restrict__ woutb, float* __restrict__ out0) {
  __shared__ char smem[LDS_TOT];
  float* psa  = (float*)(smem + LDS_PSA);
  float* psb  = (float*)(smem + LDS_PSB);
  float* stat = (float*)(smem + LDS_STAT);
  short* yls  = (short*)(smem + LDS_Y);
  short* omls = (short*)(smem + LDS_OM);
  short* vls  = (short*)(smem + LDS_Y);

  int tid = threadIdx.x;
  int bid = blockIdx.x;
  int xcd = bid & 7, slot = bid >> 3;            // slot 0..127
  int img = slot >> 5;                           // 4 imgs
  int rem = slot & 31;                           // 2 w-tiles x 16 h
  int h = xcd * 16 + (rem & 15);
  int w0 = (rem >> 4) * 64;

  int wloc = tid & 63, part = tid >> 6;
  int w = w0 + wloc;
  float yv[8];
  {
    const float* hn = hb + (size_t)img * (32 * HWT);
    #pragma unroll
    for (int i = 0; i < 8; ++i) yv[i] = Wp[OFF_DWB + part*8 + i];
    #pragma unroll
    for (int tap = 0; tap < 9; ++tap) {
      int dy = tap / 3 - 1, dx = tap % 3 - 1;
      int hh = h + dy, ww = w + dx;
      bool ok = ((unsigned)hh < 128u) && ((unsigned)ww < 128u);
      int off = hh * WT + ww;
      #pragma unroll
      for (int j = 0; j < 4; ++j) {
        int cin = part * 4 + j;
        float a = ok ? hn[cin * HWT + off] : 0.f;
        yv[2*j]   += a * Wp[OFF_DWP + tap*64 + part*8 + 2*j];
        yv[2*j+1] += a * Wp[OFF_DWP + tap*64 + part*8 + 2*j+1];
      }
    }
  }
  float lsum = 0.f, lsq = 0.f;
  #pragma unroll
  for (int i = 0; i < 8; ++i) { lsum += yv[i]; lsq += yv[i]*yv[i]; }
  psa[part * 64 + wloc] = lsum;
  psb[part * 64 + wloc] = lsq;
  __syncthreads();
  if (tid < 64) {
    float s = 0.f, q = 0.f;
    #pragma unroll
    for (int p = 0; p < 8; ++p) { s += psa[p*64 + tid]; q += psb[p*64 + tid]; }
    float mu = s * (1.f/64.f);
    float var = q * (1.f/64.f) - mu * mu;
    stat[tid*2] = mu;
    stat[tid*2+1] = rsqrtf(var + 1e-6f);
  }
  __syncthreads();
  {
    float mu = stat[wloc*2], inv = stat[wloc*2+1];
    bf16 tmp[8];
    #pragma unroll
    for (int i = 0; i < 8; ++i) {
      int c = part*8 + i;
      float v = (yv[i] - mu) * inv * Wp[OFF_LNG + c] + Wp[OFF_LNB + c];
      tmp[i] = f2b(0.5f * v * (1.f + erff(v * 0.70710678118654752f)));
    }
    *(short8v*)(yls + wloc*72 + part*8) = *(const short8v*)tmp;
  }
  __syncthreads();

  int wv = tid >> 6, ln = tid & 63, quad = ln >> 4, lm = ln & 15;
  if (wv < 7) {
    const short* wb = (const short*)womb;
    float4v acc[4];
    #pragma unroll
    for (int mt = 0; mt < 4; ++mt) acc[mt] = (float4v){0.f,0.f,0.f,0.f};
    #pragma unroll
    for (int kc = 0; kc < 2; ++kc) {
      short8v b = *(const short8v*)(wb + ((wv * 2 + kc) * 64 + ln) * 8);
      #pragma unroll
      for (int mt = 0; mt < 4; ++mt) {
        short8v a = *(const short8v*)(yls + (mt*16 + lm)*72 + kc*32 + quad*8);
        acc[mt] = __builtin_amdgcn_mfma_f32_16x16x32_bf16(a, b, acc[mt], 0, 0, 0);
      }
    }
    float bias = Wp[OFF_OMB + wv*16 + lm];
    #pragma unroll
    for (int mt = 0; mt < 4; ++mt) {
      #pragma unroll
      for (int ri = 0; ri < 4; ++ri)
        omls[(mt*16 + quad*4 + ri)*114 + wv*16 + lm] = f2bs(acc[mt][ri] + bias);
    }
  }
  __syncthreads();

  {
    int px = tid >> 3, g = (tid >> 1) & 3, half = tid & 1;
    const short* oml = omls + px*114;
    float m[9];
    #pragma unroll
    for (int p = 0; p < 9; ++p) m[p] = bu2f((unsigned short)oml[72 + g*9 + p]);
    float mx = m[0];
    #pragma unroll
    for (int p = 1; p < 9; ++p) mx = fmaxf(mx, m[p]);
    float sum = 0.f;
    #pragma unroll
    for (int p = 0; p < 9; ++p) { m[p] = __expf(m[p] - mx); sum += m[p]; }
    float rs = 1.f / sum;
    int wg = w0 + px;
    const bf16* xn = xl + (size_t)img * (HWT * 64);
    float acc[8];
    #pragma unroll
    for (int i = 0; i < 8; ++i) acc[i] = 0.f;
    for (int p = 0; p < 9; ++p) {
      float bx = (float)(wg + p / 3 - 1);
      float by = (float)(h + p % 3 - 1);
      float ox = bu2f((unsigned short)oml[g*18 + p*2]);
      float oy = bu2f((unsigned short)oml[g*18 + p*2 + 1]);
      float mk = m[p] * rs;
      float pxx = bx + ox, pyy = by + oy;
      float fx = floorf(pxx), fy = floorf(pyy);
      int jx0 = (int)fx, jy0 = (int)fy;
      float wx1 = pxx - fx, wy1 = pyy - fy;
      float wx0 = 1.f - wx1, wy0 = 1.f - wy1;
      int cjx[4] = { jx0, jx0 + 1, jx0, jx0 + 1 };
      int cjy[4] = { jy0, jy0, jy0 + 1, jy0 + 1 };
      float cw[4] = { wx0*wy0, wx1*wy0, wx0*wy1, wx1*wy1 };
      #pragma unroll
      for (int k = 0; k < 4; ++k) {
        if ((unsigned)cjx[k] < 128u && (unsigned)cjy[k] < 128u) {
          float cf = mk * cw[k];
          const bf16* s = xn + (size_t)(cjy[k] * WT + cjx[k]) * 64 + g * 16 + half * 8;
          uint4 u0 = *(const uint4*)(s);
          const unsigned uu[4] = {u0.x,u0.y,u0.z,u0.w};
          #pragma unroll
          for (int q = 0; q < 4; ++q) {
            acc[2*q]     += cf * bu2f((unsigned short)(uu[q] & 0xFFFFu));
            acc[2*q + 1] += cf * bu2f((unsigned short)(uu[q] >> 16));
          }
        }
      }
    }
    bf16 tmp[8];
    #pragma unroll
    for (int i = 0; i < 8; ++i) tmp[i] = f2b(acc[i]);
    *(short8v*)(vls + px*72 + g*16 + half*8) = *(const short8v*)tmp;
  }
  __syncthreads();

  {
    const short* wb = (const short*)woutb;
    #pragma unroll
    for (int s = 0; s < 2; ++s) {
      int tile = wv * 2 + s;
      int nt = tile >> 2, mt = tile & 3;
      float4v acc = (float4v){0.f,0.f,0.f,0.f};
      #pragma unroll
      for (int kc = 0; kc < 2; ++kc) {
        short8v b = *(const short8v*)(wb + ((nt * 2 + kc) * 64 + ln) * 8);
        short8v a = *(const short8v*)(vls + (mt*16 + lm)*72 + kc*32 + quad*8);
        acc = __builtin_amdgcn_mfma_f32_16x16x32_bf16(a, b, acc, 0, 0, 0);
      }
      int ch = nt*16 + lm;
      float bias = Wp[OFF_BOUT + ch];
      float4 v;
      float s0 = acc[0] + bias; v.x = s0 / (1.f + __expf(-s0));
      float s1 = acc[1] + bias; v.y = s1 / (1.f + __expf(-s1));
      float s2 = acc[2] + bias; v.z = s2 / (1.f + __expf(-s2));
      float s3 = acc[3] + bias; v.w = s3 / (1.f + __expf(-s3));
      *(float4*)(out0 + ((size_t)img*64 + ch)*HWT + h*128 + w0 + mt*16 + quad*4) = v;
    }
  }
}

extern "C" void kernel_launch(void* const* d_in, const int* in_sizes, int n_in,
                              void* d_out, int out_size, void* d_ws, size_t ws_size,
                              hipStream_t stream) {
  const float* input_x = (const float*)d_in[0];
  const float* input_y = (const float*)d_in[1];

  float* Wp = (float*)d_ws;
  bf16* WZRB  = (bf16*)((char*)d_ws + B_WZRB);
  bf16* WQB   = (bf16*)((char*)d_ws + B_WQB);
  bf16* WOMB  = (bf16*)((char*)d_ws + B_WOMB);
  bf16* WOUTB = (bf16*)((char*)d_ws + B_WOUTB);
  bf16* HXP   = (bf16*)((char*)d_ws + B_HXP);
  bf16* QINP  = (bf16*)((char*)d_ws + B_QINP);
  bf16* ZBUF  = (bf16*)((char*)d_ws + B_ZBUF);
  float* out0 = (float*)d_out;
  float* outh = (float*)d_out + 4194304;

  // runtime-gated overlap: if workspace has +8MB slack, input-linear runs inside
  // the k_zr launch (writes XL2), else falls back to R8's stageB dual-part (XL=HXP overlay).
  int big = ws_size >= (size_t)WS_NEED;
  bf16* XLv = big ? (bf16*)((char*)d_ws + B_XL2) : (bf16*)((char*)d_ws + B_XL);

  k_stage1<<<dim3(NB_PREPB + 1024), dim3(256), 0, stream>>>(
      (const float*)d_in[2], (const float*)d_in[3], (const float*)d_in[4], (const float*)d_in[5],
      (const float*)d_in[6], (const float*)d_in[7], (const float*)d_in[8], (const float*)d_in[9],
      (const float*)d_in[10], (const float*)d_in[11], (const float*)d_in[12], (const float*)d_in[13],
      (const float*)d_in[14], (const float*)d_in[15], (const float*)d_in[16], (const float*)d_in[17],
      (const float*)d_in[18], (const float*)d_in[19], (const float*)d_in[20], (const float*)d_in[21],
      (const float*)d_in[22], (const float*)d_in[23], (const float*)d_in[24], (const float*)d_in[25],
      Wp, WZRB, WQB, WOMB, WOUTB, HXP, QINP, input_x, input_y);
  k_zr<<<dim3(big ? 2048 : 1024), dim3(256), 0, stream>>>(
      Wp, HXP, WZRB, QINP, ZBUF, input_x, XLv, big);
  k_stageB<<<dim3(big ? 1024 : 2048), dim3(256), 0, stream>>>(
      input_y, Wp, QINP, WQB, ZBUF, outh, input_x, XLv, big);
  k_mega<<<dim3(1024), dim3(512), 0, stream>>>(Wp, outh, XLv, WOMB, WOUTB, out0);
}